// Round 1
// baseline (622.730 us; speedup 1.0000x reference)
//
#include <hip/hip_runtime.h>
#include <hip/hip_bf16.h>

#define BATCH 4
#define NPTS  4096
#define KNBR  20
#define INC   32
#define TWC   64   // 2*INC
#define OUTC  32
#define EPSBN 1e-5f

// ---------------- helpers ----------------
__device__ __forceinline__ float rl(float v, int l) {
    return __uint_as_float((unsigned)__builtin_amdgcn_readlane((int)__float_as_uint(v), l));
}

// ---------------- kernel 0a: transpose x -> [B][N][{x,y,z,sq}] ----------------
__global__ __launch_bounds__(256) void k_prep_x(const float* __restrict__ x,
                                                float4* __restrict__ xT4) {
    int i = blockIdx.x * 256 + threadIdx.x;          // over B*N
    if (i >= BATCH * NPTS) return;
    int b = i / NPTS, n = i % NPTS;
    const float* xb = x + (size_t)b * 3 * NPTS;
    float x0 = xb[n], x1 = xb[NPTS + n], x2 = xb[2 * NPTS + n];
    float sq = fmaf(x2, x2, fmaf(x1, x1, x0 * x0));
    xT4[i] = make_float4(x0, x1, x2, sq);
}

// ---------------- kernel 0b: transpose feature -> [B][N][C] ----------------
__global__ __launch_bounds__(256) void k_prep_feat(const float* __restrict__ f,
                                                   float* __restrict__ fT) {
    int i = blockIdx.x * 256 + threadIdx.x;          // over B*C*N
    if (i >= BATCH * INC * NPTS) return;
    int n = i % NPTS; int t = i / NPTS; int c = t % INC; int b = t / INC;
    fT[((size_t)(b * NPTS + n)) * INC + c] = f[i];
}

// ---------------- kernel 1: brute-force KNN top-20 ----------------
// block = 256 threads = 32 points x 8 candidate-splits.
// Each thread keeps a register-resident sorted top-20 (static indexing only).
// Merge is lexicographic (d2, idx) => identical tie-breaking to jax.lax.top_k.
#define PPB   32
#define SPLIT 8
__global__ __launch_bounds__(256) void k_knn(const float4* __restrict__ xT4,
                                             int* __restrict__ neigh) {
    __shared__ float4 cand[1024];                    // 16 KB staging chunk
    __shared__ float  md[PPB * SPLIT * KNBR];        // 20 KB
    __shared__ int    mi[PPB * SPLIT * KNBR];        // 20 KB

    int tid = threadIdx.x;
    int pl  = tid % PPB;          // point-in-block
    int sp  = tid / PPB;          // split
    int gp  = blockIdx.x * PPB + pl;                 // global point in [0, B*N)
    int b   = gp / NPTS;

    float4 me = xT4[gp];
    const float4* base = xT4 + (size_t)b * NPTS;

    float ld[KNBR]; int li[KNBR];
#pragma unroll
    for (int q = 0; q < KNBR; ++q) { ld[q] = 3.4e38f; li[q] = 0x7fffffff; }
    float kth = 3.4e38f;

    for (int ch = 0; ch < NPTS; ch += 1024) {
        __syncthreads();
        for (int s = tid; s < 1024; s += 256) cand[s] = base[ch + s];
        __syncthreads();
        for (int i2 = 0; i2 < 1024 / SPLIT; ++i2) {
            int jl = sp + SPLIT * i2;
            float4 o = cand[jl];
            float dot = fmaf(o.z, me.z, fmaf(o.y, me.y, o.x * me.x));
            float d2  = (me.w + o.w) - 2.0f * dot;
            if (d2 < kth) {
                ld[KNBR - 1] = d2; li[KNBR - 1] = ch + jl;
#pragma unroll
                for (int q = KNBR - 1; q > 0; --q) {
                    bool sw = ld[q] < ld[q - 1];          // strict => stable ties
                    float ta = ld[q - 1]; ld[q - 1] = sw ? ld[q] : ta; ld[q] = sw ? ta : ld[q];
                    int   ia = li[q - 1]; li[q - 1] = sw ? li[q] : ia; li[q] = sw ? ia : li[q];
                }
                kth = ld[KNBR - 1];
            }
        }
    }
    __syncthreads();
#pragma unroll
    for (int q = 0; q < KNBR; ++q) {
        md[(pl * SPLIT + sp) * KNBR + q] = ld[q];
        mi[(pl * SPLIT + sp) * KNBR + q] = li[q];
    }
    __syncthreads();

    if (sp == 0) {
        int ptr[SPLIT];
#pragma unroll
        for (int s = 0; s < SPLIT; ++s) ptr[s] = 0;
        int outbase = gp * KNBR;
        for (int r = 0; r < KNBR; ++r) {
            float bd = 3.5e38f; int bi = 0x7fffffff; int bs = -1;
#pragma unroll
            for (int s = 0; s < SPLIT; ++s) {
                int pq = ptr[s];
                float dv = md[(pl * SPLIT + s) * KNBR + pq];
                int   iv = mi[(pl * SPLIT + s) * KNBR + pq];
                bool better = (dv < bd) || (dv == bd && iv < bi);
                bd = better ? dv : bd; bi = better ? iv : bi; bs = better ? s : bs;
            }
            neigh[outbase + r] = bi;
#pragma unroll
            for (int s = 0; s < SPLIT; ++s) ptr[s] += (bs == s) ? 1 : 0;
        }
    }
}

// ---------------- kernel 2: relative MLP + channel-softmax attention + convs ----------------
// One wave per point; lane = channel d in [0,64). w_att row held in 64 VGPRs.
__global__ __launch_bounds__(256) void k_attn(
    const float4* __restrict__ xT4, const float* __restrict__ featT,
    const int* __restrict__ neigh,
    const float* __restrict__ w_mlp, const float* __restrict__ b_mlp,
    const float* __restrict__ w_att, const float* __restrict__ w_conv,
    const float* __restrict__ b_conv, const float* __restrict__ w_out,
    const float* __restrict__ b_out, float* __restrict__ out) {

    __shared__ float wcT[TWC * OUTC];   // [c][o]  8 KB
    __shared__ float woT[INC * OUTC];   // [c][o]  4 KB

    int tid = threadIdx.x;
    for (int i = tid; i < TWC * OUTC; i += 256) {
        int c = i / OUTC, o = i % OUTC;
        wcT[i] = w_conv[o * TWC + c];
    }
    for (int i = tid; i < INC * OUTC; i += 256) {
        int c = i / OUTC, o = i % OUTC;
        woT[i] = w_out[o * INC + c];
    }
    __syncthreads();

    int lane = tid & 63;
    int wv   = tid >> 6;

    // per-lane attention weight row (64 VGPRs)
    float wrow[TWC];
    const float4* wa4 = (const float4*)w_att;
#pragma unroll
    for (int c4 = 0; c4 < 16; ++c4) {
        float4 v = wa4[lane * 16 + c4];
        wrow[4 * c4 + 0] = v.x; wrow[4 * c4 + 1] = v.y;
        wrow[4 * c4 + 2] = v.z; wrow[4 * c4 + 3] = v.w;
    }
    float wm[7]; float bm = 0.f;
#pragma unroll
    for (int j = 0; j < 7; ++j) wm[j] = 0.f;
    if (lane >= INC) {
        int e = lane - INC;
#pragma unroll
        for (int j = 0; j < 7; ++j) wm[j] = w_mlp[e * 7 + j];
        bm = b_mlp[e];
    }
    float bias = (lane < OUTC) ? (b_conv[lane] + b_out[lane]) : 0.f;

    int gw = blockIdx.x * 4 + wv;      // global wave, 0..4095
    for (int it = 0; it < 4; ++it) {
        int gp = gw * 4 + it;          // point 0..16383
        int b = gp >> 12, p = gp & (NPTS - 1);
        const int* nl = neigh + gp * KNBR;
        int n0 = nl[0];
        float4 c0 = xT4[b * NPTS + n0];              // coords of nearest (== self)
        const float* fb = featT + ((size_t)b * NPTS) * INC;

        float pooled = 0.f;
        for (int k = 0; k < KNBR; ++k) {
            int nk = nl[k];
            float4 nc = xT4[b * NPTS + nk];
            float rx = nc.x - c0.x, ry = nc.y - c0.y, rz = nc.z - c0.z;
            float dis = sqrtf(fmaf(rz, rz, fmaf(ry, ry, rx * rx)));
            float f;
            if (lane < INC) {
                f = fb[(size_t)nk * INC + lane];
            } else {
                f = bm;
                f = fmaf(wm[0], c0.x, f); f = fmaf(wm[1], c0.y, f); f = fmaf(wm[2], c0.z, f);
                f = fmaf(wm[3], rx,  f); f = fmaf(wm[4], ry,  f); f = fmaf(wm[5], rz,  f);
                f = fmaf(wm[6], dis, f);
            }
            // scores[d] = sum_c w_att[d][c] * f[c]   (f[c] via readlane)
            float s0 = 0.f, s1 = 0.f, s2 = 0.f, s3 = 0.f;
#pragma unroll
            for (int c = 0; c < TWC; c += 4) {
                s0 = fmaf(wrow[c + 0], rl(f, c + 0), s0);
                s1 = fmaf(wrow[c + 1], rl(f, c + 1), s1);
                s2 = fmaf(wrow[c + 2], rl(f, c + 2), s2);
                s3 = fmaf(wrow[c + 3], rl(f, c + 3), s3);
            }
            float s = (s0 + s1) + (s2 + s3);
            // softmax over the 64 channels (= the wave)
            float m = s;
#pragma unroll
            for (int off = 32; off >= 1; off >>= 1) m = fmaxf(m, __shfl_xor(m, off, 64));
            float e = __expf(s - m);
            float se = e;
#pragma unroll
            for (int off = 32; off >= 1; off >>= 1) se += __shfl_xor(se, off, 64);
            float a = e / se;
            pooled = fmaf(a, f, pooled);
        }

        // epilogue: lanes 0..31 -> w_conv @ pooled ; lanes 32..63 -> w_out @ feature
        float acc = 0.f;
        if (lane < OUTC) {
#pragma unroll
            for (int c = 0; c < TWC; ++c)
                acc = fmaf(wcT[c * OUTC + lane], rl(pooled, c), acc);
        } else {
            int o2 = lane - OUTC;
            const float* fp = fb + (size_t)p * INC;
#pragma unroll
            for (int c = 0; c < INC; ++c)
                acc = fmaf(woT[c * OUTC + o2], fp[c], acc);
        }
        float tot = acc + __shfl_xor(acc, 32, 64);
        if (lane < OUTC) {
            tot += bias;
            out[((size_t)b * OUTC + lane) * NPTS + p] = tot;
        }
    }
}

// ---------------- kernel 3a: per-channel batch stats ----------------
__global__ __launch_bounds__(256) void k_stats(const float* __restrict__ of,
                                               float* __restrict__ stats) {
    int c = blockIdx.x;                 // 0..31
    int tid = threadIdx.x;
    float s = 0.f, s2 = 0.f;
    for (int i = tid; i < BATCH * NPTS; i += 256) {
        int b = i >> 12, n = i & (NPTS - 1);
        float v = of[((size_t)b * OUTC + c) * NPTS + n];
        s += v; s2 = fmaf(v, v, s2);
    }
#pragma unroll
    for (int off = 32; off >= 1; off >>= 1) {
        s += __shfl_xor(s, off, 64);
        s2 += __shfl_xor(s2, off, 64);
    }
    __shared__ float rs[4], rs2[4];
    if ((tid & 63) == 0) { rs[tid >> 6] = s; rs2[tid >> 6] = s2; }
    __syncthreads();
    if (tid == 0) {
        float S = (rs[0] + rs[1]) + (rs[2] + rs[3]);
        float S2 = (rs2[0] + rs2[1]) + (rs2[2] + rs2[3]);
        const float invn = 1.0f / (BATCH * NPTS);
        float mean = S * invn;
        float var = S2 * invn - mean * mean;
        stats[c] = mean;
        stats[32 + c] = rsqrtf(var + EPSBN);
    }
}

// ---------------- kernel 3b: normalize in place ----------------
__global__ __launch_bounds__(256) void k_norm(float* __restrict__ of,
                                              const float* __restrict__ stats,
                                              const float* __restrict__ gamma,
                                              const float* __restrict__ beta) {
    int i = blockIdx.x * 256 + threadIdx.x;
    if (i >= BATCH * OUTC * NPTS) return;
    int c = (i >> 12) & (OUTC - 1);
    float v = of[i];
    of[i] = (v - stats[c]) * stats[32 + c] * gamma[c] + beta[c];
}

// ---------------- launch ----------------
extern "C" void kernel_launch(void* const* d_in, const int* in_sizes, int n_in,
                              void* d_out, int out_size, void* d_ws, size_t ws_size,
                              hipStream_t stream) {
    const float* x      = (const float*)d_in[0];
    const float* feat   = (const float*)d_in[1];
    const float* w_mlp  = (const float*)d_in[2];
    const float* b_mlp  = (const float*)d_in[3];
    const float* w_att  = (const float*)d_in[4];
    const float* w_conv = (const float*)d_in[5];
    const float* b_conv = (const float*)d_in[6];
    const float* w_out  = (const float*)d_in[7];
    const float* b_out  = (const float*)d_in[8];
    const float* gamma  = (const float*)d_in[9];
    const float* beta   = (const float*)d_in[10];
    float* out = (float*)d_out;

    char* ws = (char*)d_ws;
    float4* xT4  = (float4*)ws;                                    // 262144 B
    float*  featT = (float*)(ws + 262144);                         // 2097152 B
    int*    neigh = (int*)(ws + 262144 + 2097152);                 // 1310720 B
    float*  stats = (float*)(ws + 262144 + 2097152 + 1310720);     // 256 B

    k_prep_x<<<(BATCH * NPTS + 255) / 256, 256, 0, stream>>>(x, xT4);
    k_prep_feat<<<(BATCH * INC * NPTS + 255) / 256, 256, 0, stream>>>(feat, featT);
    k_knn<<<(BATCH * NPTS) / PPB, 256, 0, stream>>>(xT4, neigh);
    k_attn<<<(BATCH * NPTS) / 16, 256, 0, stream>>>(xT4, featT, neigh, w_mlp, b_mlp,
                                                    w_att, w_conv, b_conv, w_out, b_out, out);
    k_stats<<<OUTC, 256, 0, stream>>>(out, stats);
    k_norm<<<(BATCH * OUTC * NPTS + 255) / 256, 256, 0, stream>>>(out, stats, gamma, beta);
}

// Round 2
// 281.211 us; speedup vs baseline: 2.2145x; 2.2145x over previous
//
#include <hip/hip_runtime.h>
#include <hip/hip_bf16.h>

#define BATCH 4
#define NPTS  4096
#define KNBR  20
#define INC   32
#define TWC   64   // 2*INC
#define OUTC  32
#define EPSBN 1e-5f

// ---------------- helpers ----------------
__device__ __forceinline__ float rl(float v, int l) {
    return __uint_as_float((unsigned)__builtin_amdgcn_readlane((int)__float_as_uint(v), l));
}

// ---------------- kernel 0a: transpose x -> [B][N][{x,y,z,sq}] ----------------
__global__ __launch_bounds__(256) void k_prep_x(const float* __restrict__ x,
                                                float4* __restrict__ xT4) {
    int i = blockIdx.x * 256 + threadIdx.x;          // over B*N
    if (i >= BATCH * NPTS) return;
    int b = i / NPTS, n = i % NPTS;
    const float* xb = x + (size_t)b * 3 * NPTS;
    float x0 = xb[n], x1 = xb[NPTS + n], x2 = xb[2 * NPTS + n];
    float sq = fmaf(x2, x2, fmaf(x1, x1, x0 * x0));
    xT4[i] = make_float4(x0, x1, x2, sq);
}

// ---------------- kernel 0b: transpose feature -> [B][N][C] ----------------
__global__ __launch_bounds__(256) void k_prep_feat(const float* __restrict__ f,
                                                   float* __restrict__ fT) {
    int i = blockIdx.x * 256 + threadIdx.x;          // over B*C*N
    if (i >= BATCH * INC * NPTS) return;
    int n = i % NPTS; int t = i / NPTS; int c = t % INC; int b = t / INC;
    fT[((size_t)(b * NPTS + n)) * INC + c] = f[i];
}

// ---------------- kernel 1: KNN, filter-then-select ----------------
// One wave per point (4 waves/block). Phase 1: tau = upper bound on 20th-NN
// distance from a 1024-candidate subset via ballot-bisection on float bits.
// Phase 2: stream all 4096 candidates through LDS, append d2<=tau survivors
// (packed (d2bits<<32)|idx keys -> exact jax.lax.top_k tie-breaking) via
// ballot compaction. Phase 3: 20 rounds of wave-wide extract-min.
#define CAP   256   // survivor capacity per point (mean ~80; P(overflow) ~ e^-121)
#define PPBK  4     // points per block
__global__ __launch_bounds__(256) void k_knn2(const float4* __restrict__ xT4,
                                              int* __restrict__ neigh) {
    __shared__ float4 cand[1024];                       // 16 KB chunk
    __shared__ unsigned long long surv[PPBK][CAP];      // 8 KB
    __shared__ int scnt[PPBK];

    const int tid  = threadIdx.x;
    const int lane = tid & 63;
    const int wv   = tid >> 6;
    const int gp   = blockIdx.x * PPBK + wv;            // global point
    const int b    = gp >> 12;
    const float4* base = xT4 + (size_t)b * NPTS;

    if (tid < PPBK) scnt[tid] = 0;

    float4 me = xT4[gp];

    // stage chunk 0 (candidates 0..1023)
    for (int r = 0; r < 4; ++r)
        cand[tid + 256 * r] = base[tid + 256 * r];
    __syncthreads();

    // ---- phase 1: subset distances (lane + 64j, j<16) kept in regs ----
    unsigned bits[16];
#pragma unroll
    for (int j = 0; j < 16; ++j) {
        float4 o = cand[lane + 64 * j];
        float dot = fmaf(o.z, me.z, fmaf(o.y, me.y, o.x * me.x));
        float d2  = fmaxf((me.w + o.w) - 2.0f * dot, 0.0f);
        bits[j] = __float_as_uint(d2);
    }
    // bisection on float bits: tau >= exact 20th-smallest of the subset
    unsigned lo = 0u, hi = 0xFF000000u;
    for (int it = 0; it < 24; ++it) {
        unsigned mid = lo + ((hi - lo) >> 1);
        int cnt = 0;
#pragma unroll
        for (int j = 0; j < 16; ++j)
            cnt += __popcll(__ballot(bits[j] <= mid));
        if (cnt >= KNBR) hi = mid; else lo = mid + 1;
    }
    const unsigned tau = hi;

    // ---- phase 2: filtered append ----
    auto append = [&](unsigned bb, int idx) {
        bool pass = bb <= tau;
        unsigned long long bal = __ballot(pass);
        if (bal) {
            int lead = __builtin_ctzll(bal);
            int basep = 0;
            if (lane == lead) basep = atomicAdd(&scnt[wv], __popcll(bal));
            basep = __shfl(basep, lead, 64);
            if (pass) {
                int pos = basep + __popcll(bal & ((1ull << lane) - 1ull));
                if (pos < CAP)
                    surv[wv][pos] = ((unsigned long long)bb << 32) | (unsigned)idx;
            }
        }
    };

#pragma unroll
    for (int j = 0; j < 16; ++j) append(bits[j], lane + 64 * j);

    for (int ch = 1; ch < 4; ++ch) {
        __syncthreads();
        for (int r = 0; r < 4; ++r)
            cand[tid + 256 * r] = base[ch * 1024 + tid + 256 * r];
        __syncthreads();
#pragma unroll
        for (int j = 0; j < 16; ++j) {
            float4 o = cand[lane + 64 * j];
            float dot = fmaf(o.z, me.z, fmaf(o.y, me.y, o.x * me.x));
            float d2  = fmaxf((me.w + o.w) - 2.0f * dot, 0.0f);
            append(__float_as_uint(d2), ch * 1024 + lane + 64 * j);
        }
    }
    __syncthreads();

    // ---- phase 3: 20 x wave extract-min over survivors ----
    int cnt = min(scnt[wv], CAP);
    unsigned long long k0 = (lane       < cnt) ? surv[wv][lane      ] : ~0ull;
    unsigned long long k1 = (lane +  64 < cnt) ? surv[wv][lane +  64] : ~0ull;
    unsigned long long k2 = (lane + 128 < cnt) ? surv[wv][lane + 128] : ~0ull;
    unsigned long long k3 = (lane + 192 < cnt) ? surv[wv][lane + 192] : ~0ull;

    const int outb = gp * KNBR;
    for (int r = 0; r < KNBR; ++r) {
        unsigned long long m01 = k0 < k1 ? k0 : k1;
        unsigned long long m23 = k2 < k3 ? k2 : k3;
        unsigned long long mk  = m01 < m23 ? m01 : m23;
#pragma unroll
        for (int off = 32; off >= 1; off >>= 1) {
            unsigned long long o = __shfl_xor(mk, off, 64);
            mk = o < mk ? o : mk;
        }
        if (lane == 0) neigh[outb + r] = (int)(unsigned)(mk & 0xFFFFFFFFull);
        k0 = (k0 == mk) ? ~0ull : k0;
        k1 = (k1 == mk) ? ~0ull : k1;
        k2 = (k2 == mk) ? ~0ull : k2;
        k3 = (k3 == mk) ? ~0ull : k3;
    }
}

// ---------------- kernel 2: relative MLP + channel-softmax attention + convs ----------------
// One wave per point; lane = channel d in [0,64). w_att row held in 64 VGPRs.
__global__ __launch_bounds__(256) void k_attn(
    const float4* __restrict__ xT4, const float* __restrict__ featT,
    const int* __restrict__ neigh,
    const float* __restrict__ w_mlp, const float* __restrict__ b_mlp,
    const float* __restrict__ w_att, const float* __restrict__ w_conv,
    const float* __restrict__ b_conv, const float* __restrict__ w_out,
    const float* __restrict__ b_out, float* __restrict__ out) {

    __shared__ float wcT[TWC * OUTC];   // [c][o]  8 KB
    __shared__ float woT[INC * OUTC];   // [c][o]  4 KB

    int tid = threadIdx.x;
    for (int i = tid; i < TWC * OUTC; i += 256) {
        int c = i / OUTC, o = i % OUTC;
        wcT[i] = w_conv[o * TWC + c];
    }
    for (int i = tid; i < INC * OUTC; i += 256) {
        int c = i / OUTC, o = i % OUTC;
        woT[i] = w_out[o * INC + c];
    }
    __syncthreads();

    int lane = tid & 63;
    int wv   = tid >> 6;

    // per-lane attention weight row (64 VGPRs)
    float wrow[TWC];
    const float4* wa4 = (const float4*)w_att;
#pragma unroll
    for (int c4 = 0; c4 < 16; ++c4) {
        float4 v = wa4[lane * 16 + c4];
        wrow[4 * c4 + 0] = v.x; wrow[4 * c4 + 1] = v.y;
        wrow[4 * c4 + 2] = v.z; wrow[4 * c4 + 3] = v.w;
    }
    float wm[7]; float bm = 0.f;
#pragma unroll
    for (int j = 0; j < 7; ++j) wm[j] = 0.f;
    if (lane >= INC) {
        int e = lane - INC;
#pragma unroll
        for (int j = 0; j < 7; ++j) wm[j] = w_mlp[e * 7 + j];
        bm = b_mlp[e];
    }
    float bias = (lane < OUTC) ? (b_conv[lane] + b_out[lane]) : 0.f;

    int gw = blockIdx.x * 4 + wv;      // global wave, 0..4095
    for (int it = 0; it < 4; ++it) {
        int gp = gw * 4 + it;          // point 0..16383
        int b = gp >> 12, p = gp & (NPTS - 1);
        const int* nl = neigh + gp * KNBR;
        int n0 = nl[0];
        float4 c0 = xT4[b * NPTS + n0];              // coords of nearest (== self)
        const float* fb = featT + ((size_t)b * NPTS) * INC;

        float pooled = 0.f;
        for (int k = 0; k < KNBR; ++k) {
            int nk = nl[k];
            float4 nc = xT4[b * NPTS + nk];
            float rx = nc.x - c0.x, ry = nc.y - c0.y, rz = nc.z - c0.z;
            float dis = sqrtf(fmaf(rz, rz, fmaf(ry, ry, rx * rx)));
            float f;
            if (lane < INC) {
                f = fb[(size_t)nk * INC + lane];
            } else {
                f = bm;
                f = fmaf(wm[0], c0.x, f); f = fmaf(wm[1], c0.y, f); f = fmaf(wm[2], c0.z, f);
                f = fmaf(wm[3], rx,  f); f = fmaf(wm[4], ry,  f); f = fmaf(wm[5], rz,  f);
                f = fmaf(wm[6], dis, f);
            }
            // scores[d] = sum_c w_att[d][c] * f[c]   (f[c] via readlane)
            float s0 = 0.f, s1 = 0.f, s2 = 0.f, s3 = 0.f;
#pragma unroll
            for (int c = 0; c < TWC; c += 4) {
                s0 = fmaf(wrow[c + 0], rl(f, c + 0), s0);
                s1 = fmaf(wrow[c + 1], rl(f, c + 1), s1);
                s2 = fmaf(wrow[c + 2], rl(f, c + 2), s2);
                s3 = fmaf(wrow[c + 3], rl(f, c + 3), s3);
            }
            float s = (s0 + s1) + (s2 + s3);
            // softmax over the 64 channels (= the wave)
            float m = s;
#pragma unroll
            for (int off = 32; off >= 1; off >>= 1) m = fmaxf(m, __shfl_xor(m, off, 64));
            float e = __expf(s - m);
            float se = e;
#pragma unroll
            for (int off = 32; off >= 1; off >>= 1) se += __shfl_xor(se, off, 64);
            float a = e / se;
            pooled = fmaf(a, f, pooled);
        }

        // epilogue: lanes 0..31 -> w_conv @ pooled ; lanes 32..63 -> w_out @ feature
        float acc = 0.f;
        if (lane < OUTC) {
#pragma unroll
            for (int c = 0; c < TWC; ++c)
                acc = fmaf(wcT[c * OUTC + lane], rl(pooled, c), acc);
        } else {
            int o2 = lane - OUTC;
            const float* fp = fb + (size_t)p * INC;
#pragma unroll
            for (int c = 0; c < INC; ++c)
                acc = fmaf(woT[c * OUTC + o2], fp[c], acc);
        }
        float tot = acc + __shfl_xor(acc, 32, 64);
        if (lane < OUTC) {
            tot += bias;
            out[((size_t)b * OUTC + lane) * NPTS + p] = tot;
        }
    }
}

// ---------------- kernel 3a: per-channel batch stats ----------------
__global__ __launch_bounds__(256) void k_stats(const float* __restrict__ of,
                                               float* __restrict__ stats) {
    int c = blockIdx.x;                 // 0..31
    int tid = threadIdx.x;
    float s = 0.f, s2 = 0.f;
    for (int i = tid; i < BATCH * NPTS; i += 256) {
        int b = i >> 12, n = i & (NPTS - 1);
        float v = of[((size_t)b * OUTC + c) * NPTS + n];
        s += v; s2 = fmaf(v, v, s2);
    }
#pragma unroll
    for (int off = 32; off >= 1; off >>= 1) {
        s += __shfl_xor(s, off, 64);
        s2 += __shfl_xor(s2, off, 64);
    }
    __shared__ float rs[4], rs2[4];
    if ((tid & 63) == 0) { rs[tid >> 6] = s; rs2[tid >> 6] = s2; }
    __syncthreads();
    if (tid == 0) {
        float S = (rs[0] + rs[1]) + (rs[2] + rs[3]);
        float S2 = (rs2[0] + rs2[1]) + (rs2[2] + rs2[3]);
        const float invn = 1.0f / (BATCH * NPTS);
        float mean = S * invn;
        float var = S2 * invn - mean * mean;
        stats[c] = mean;
        stats[32 + c] = rsqrtf(var + EPSBN);
    }
}

// ---------------- kernel 3b: normalize in place ----------------
__global__ __launch_bounds__(256) void k_norm(float* __restrict__ of,
                                              const float* __restrict__ stats,
                                              const float* __restrict__ gamma,
                                              const float* __restrict__ beta) {
    int i = blockIdx.x * 256 + threadIdx.x;
    if (i >= BATCH * OUTC * NPTS) return;
    int c = (i >> 12) & (OUTC - 1);
    float v = of[i];
    of[i] = (v - stats[c]) * stats[32 + c] * gamma[c] + beta[c];
}

// ---------------- launch ----------------
extern "C" void kernel_launch(void* const* d_in, const int* in_sizes, int n_in,
                              void* d_out, int out_size, void* d_ws, size_t ws_size,
                              hipStream_t stream) {
    const float* x      = (const float*)d_in[0];
    const float* feat   = (const float*)d_in[1];
    const float* w_mlp  = (const float*)d_in[2];
    const float* b_mlp  = (const float*)d_in[3];
    const float* w_att  = (const float*)d_in[4];
    const float* w_conv = (const float*)d_in[5];
    const float* b_conv = (const float*)d_in[6];
    const float* w_out  = (const float*)d_in[7];
    const float* b_out  = (const float*)d_in[8];
    const float* gamma  = (const float*)d_in[9];
    const float* beta   = (const float*)d_in[10];
    float* out = (float*)d_out;

    char* ws = (char*)d_ws;
    float4* xT4  = (float4*)ws;                                    // 262144 B
    float*  featT = (float*)(ws + 262144);                         // 2097152 B
    int*    neigh = (int*)(ws + 262144 + 2097152);                 // 1310720 B
    float*  stats = (float*)(ws + 262144 + 2097152 + 1310720);     // 256 B

    k_prep_x<<<(BATCH * NPTS + 255) / 256, 256, 0, stream>>>(x, xT4);
    k_prep_feat<<<(BATCH * INC * NPTS + 255) / 256, 256, 0, stream>>>(feat, featT);
    k_knn2<<<(BATCH * NPTS) / PPBK, 256, 0, stream>>>(xT4, neigh);
    k_attn<<<(BATCH * NPTS) / 16, 256, 0, stream>>>(xT4, featT, neigh, w_mlp, b_mlp,
                                                    w_att, w_conv, b_conv, w_out, b_out, out);
    k_stats<<<OUTC, 256, 0, stream>>>(out, stats);
    k_norm<<<(BATCH * OUTC * NPTS + 255) / 256, 256, 0, stream>>>(out, stats, gamma, beta);
}

// Round 3
// 189.134 us; speedup vs baseline: 3.2925x; 1.4868x over previous
//
#include <hip/hip_runtime.h>
#include <hip/hip_bf16.h>

#define BATCH 4
#define NPTS  4096
#define KNBR  20
#define INC   32
#define TWC   64   // 2*INC
#define OUTC  32
#define EPSBN 1e-5f

typedef short short8 __attribute__((ext_vector_type(8)));
typedef float f32x16 __attribute__((ext_vector_type(16)));

// ---------------- helpers ----------------
__device__ __forceinline__ float rlf(float v, int l) {
    return __uint_as_float((unsigned)__builtin_amdgcn_readlane((int)__float_as_uint(v), l));
}
__device__ __forceinline__ ushort f2bf(float x) {        // fp32 -> bf16 bits (RNE)
    unsigned u = __float_as_uint(x);
    unsigned r = u + 0x7FFFu + ((u >> 16) & 1u);
    return (ushort)(r >> 16);
}
__device__ __forceinline__ float bf2f(ushort h) {
    return __uint_as_float(((unsigned)h) << 16);
}

// ---------------- kernel 0a: transpose x -> [B][N][{x,y,z,sq}] ----------------
__global__ __launch_bounds__(256) void k_prep_x(const float* __restrict__ x,
                                                float4* __restrict__ xT4) {
    int i = blockIdx.x * 256 + threadIdx.x;
    if (i >= BATCH * NPTS) return;
    int b = i / NPTS, n = i % NPTS;
    const float* xb = x + (size_t)b * 3 * NPTS;
    float x0 = xb[n], x1 = xb[NPTS + n], x2 = xb[2 * NPTS + n];
    float sq = fmaf(x2, x2, fmaf(x1, x1, x0 * x0));
    xT4[i] = make_float4(x0, x1, x2, sq);
}

// ---------------- kernel 0b: transpose feature -> [B][N][C] ----------------
__global__ __launch_bounds__(256) void k_prep_feat(const float* __restrict__ f,
                                                   float* __restrict__ fT) {
    int i = blockIdx.x * 256 + threadIdx.x;
    if (i >= BATCH * INC * NPTS) return;
    int n = i % NPTS; int t = i / NPTS; int c = t % INC; int b = t / INC;
    fT[((size_t)(b * NPTS + n)) * INC + c] = f[i];
}

// ---------------- kernel 1: KNN, filter-then-select (unchanged from R2) ----------------
#define CAP   256
#define PPBK  4
__global__ __launch_bounds__(256) void k_knn2(const float4* __restrict__ xT4,
                                              int* __restrict__ neigh) {
    __shared__ float4 cand[1024];
    __shared__ unsigned long long surv[PPBK][CAP];
    __shared__ int scnt[PPBK];

    const int tid  = threadIdx.x;
    const int lane = tid & 63;
    const int wv   = tid >> 6;
    const int gp   = blockIdx.x * PPBK + wv;
    const int b    = gp >> 12;
    const float4* base = xT4 + (size_t)b * NPTS;

    if (tid < PPBK) scnt[tid] = 0;

    float4 me = xT4[gp];

    for (int r = 0; r < 4; ++r)
        cand[tid + 256 * r] = base[tid + 256 * r];
    __syncthreads();

    unsigned bits[16];
#pragma unroll
    for (int j = 0; j < 16; ++j) {
        float4 o = cand[lane + 64 * j];
        float dot = fmaf(o.z, me.z, fmaf(o.y, me.y, o.x * me.x));
        float d2  = fmaxf((me.w + o.w) - 2.0f * dot, 0.0f);
        bits[j] = __float_as_uint(d2);
    }
    unsigned lo = 0u, hi2 = 0xFF000000u;
    for (int it = 0; it < 24; ++it) {
        unsigned mid = lo + ((hi2 - lo) >> 1);
        int cnt = 0;
#pragma unroll
        for (int j = 0; j < 16; ++j)
            cnt += __popcll(__ballot(bits[j] <= mid));
        if (cnt >= KNBR) hi2 = mid; else lo = mid + 1;
    }
    const unsigned tau = hi2;

    auto append = [&](unsigned bb, int idx) {
        bool pass = bb <= tau;
        unsigned long long bal = __ballot(pass);
        if (bal) {
            int lead = __builtin_ctzll(bal);
            int basep = 0;
            if (lane == lead) basep = atomicAdd(&scnt[wv], __popcll(bal));
            basep = __shfl(basep, lead, 64);
            if (pass) {
                int pos = basep + __popcll(bal & ((1ull << lane) - 1ull));
                if (pos < CAP)
                    surv[wv][pos] = ((unsigned long long)bb << 32) | (unsigned)idx;
            }
        }
    };

#pragma unroll
    for (int j = 0; j < 16; ++j) append(bits[j], lane + 64 * j);

    for (int ch = 1; ch < 4; ++ch) {
        __syncthreads();
        for (int r = 0; r < 4; ++r)
            cand[tid + 256 * r] = base[ch * 1024 + tid + 256 * r];
        __syncthreads();
#pragma unroll
        for (int j = 0; j < 16; ++j) {
            float4 o = cand[lane + 64 * j];
            float dot = fmaf(o.z, me.z, fmaf(o.y, me.y, o.x * me.x));
            float d2  = fmaxf((me.w + o.w) - 2.0f * dot, 0.0f);
            append(__float_as_uint(d2), ch * 1024 + lane + 64 * j);
        }
    }
    __syncthreads();

    int cnt = min(scnt[wv], CAP);
    unsigned long long k0 = (lane       < cnt) ? surv[wv][lane      ] : ~0ull;
    unsigned long long k1 = (lane +  64 < cnt) ? surv[wv][lane +  64] : ~0ull;
    unsigned long long k2 = (lane + 128 < cnt) ? surv[wv][lane + 128] : ~0ull;
    unsigned long long k3 = (lane + 192 < cnt) ? surv[wv][lane + 192] : ~0ull;

    const int outb = gp * KNBR;
    for (int r = 0; r < KNBR; ++r) {
        unsigned long long m01 = k0 < k1 ? k0 : k1;
        unsigned long long m23 = k2 < k3 ? k2 : k3;
        unsigned long long mk  = m01 < m23 ? m01 : m23;
#pragma unroll
        for (int off = 32; off >= 1; off >>= 1) {
            unsigned long long o = __shfl_xor(mk, off, 64);
            mk = o < mk ? o : mk;
        }
        if (lane == 0) neigh[outb + r] = (int)(unsigned)(mk & 0xFFFFFFFFull);
        k0 = (k0 == mk) ? ~0ull : k0;
        k1 = (k1 == mk) ? ~0ull : k1;
        k2 = (k2 == mk) ? ~0ull : k2;
        k3 = (k3 == mk) ? ~0ull : k3;
    }
}

// ---------------- kernel 2: MFMA attention ----------------
// One wave per point-group (QPW points). Per point:
//   stage F^T (bf16 [32 j][64 c], XOR-swizzled) in per-wave LDS,
//   S^T = F^T @ W_att^T via 8x mfma_f32_32x32x16_bf16,
//   C layout: row j=(r&3)+8(r>>2)+4hi, col d=nt*32+(lane&31).
//   valid j<20 rows: hi=0 -> r0..11, hi=1 -> r0..7; r12..15 never valid.
//   softmax over d = 2-reg local + 5-step butterfly per row; pooled = lane-local row sum.
// Epilogue (per wave, batched over QPW points, biases dropped -- BN cancels them):
//   out = W_conv @ pooled + W_out @ feat via 6 more mfma.
#define QPW 4
__global__ __launch_bounds__(256) void k_attn2(
    const float4* __restrict__ xT4, const float* __restrict__ featT,
    const int* __restrict__ neigh,
    const float* __restrict__ w_mlp, const float* __restrict__ b_mlp,
    const float* __restrict__ w_att, const float* __restrict__ w_conv,
    const float* __restrict__ w_out, float* __restrict__ out) {

    __shared__ __align__(16) ushort Fb[4][32 * 64];     // per-wave F^T bf16, 4 KB each
    __shared__ __align__(16) ushort pool[4][QPW * 64];  // per-wave pooled bf16

    const int tid  = threadIdx.x;
    const int lane = tid & 63;
    const int wv   = tid >> 6;
    const int hi   = lane >> 5;
    const int l31  = lane & 31;

    // W_att as B-fragments: Wb[nt][kt]: lane holds W^T[c0..c0+7][d], d=nt*32+l31, c0=kt*16+8*hi
    short8 Wb[2][4];
#pragma unroll
    for (int nt = 0; nt < 2; ++nt)
#pragma unroll
        for (int kt = 0; kt < 4; ++kt) {
            const float* src = w_att + (nt * 32 + l31) * 64 + kt * 16 + 8 * hi;
            short8 v;
#pragma unroll
            for (int i = 0; i < 8; ++i) v[i] = (short)f2bf(src[i]);
            Wb[nt][kt] = v;
        }

    // MLP weights for lanes >= 32 (channel e = l31)
    float wm[7]; float bm = 0.f;
#pragma unroll
    for (int j = 0; j < 7; ++j) wm[j] = 0.f;
    if (hi) {
#pragma unroll
        for (int j = 0; j < 7; ++j) wm[j] = w_mlp[l31 * 7 + j];
        bm = b_mlp[l31];
    }

    const int gw  = blockIdx.x * 4 + wv;
    const int gp0 = gw * QPW;
    const int b   = gp0 >> 12;
    const int nb  = gp0 & (NPTS - 1);
    const float4* xb    = xT4 + (size_t)b * NPTS;
    const float*  fbase = featT + (size_t)b * NPTS * INC;

    for (int pi = 0; pi < QPW; ++pi) {
        const int gp = gp0 + pi;
        int nv = 0;
        if (!hi && l31 < KNBR) nv = neigh[gp * KNBR + l31];
        float4 ncl = xb[nv];                      // lanes 0..19 hold their neighbor's coords

        // prefetch gathered features (channel = l31; lanes>=32 read duplicate lines)
        float fv[KNBR];
#pragma unroll
        for (int k = 0; k < KNBR; ++k) {
            int snk = __builtin_amdgcn_readlane(nv, k);
            fv[k] = fbase[(size_t)snk * INC + l31];
        }
        const float c0x = rlf(ncl.x, 0), c0y = rlf(ncl.y, 0), c0z = rlf(ncl.z, 0);

#pragma unroll
        for (int k = 0; k < KNBR; ++k) {
            float rx = rlf(ncl.x, k) - c0x;
            float ry = rlf(ncl.y, k) - c0y;
            float rz = rlf(ncl.z, k) - c0z;
            float dis = sqrtf(fmaf(rz, rz, fmaf(ry, ry, rx * rx)));
            float f;
            if (!hi) {
                f = fv[k];
            } else {
                f = bm;
                f = fmaf(wm[0], c0x, f); f = fmaf(wm[1], c0y, f); f = fmaf(wm[2], c0z, f);
                f = fmaf(wm[3], rx, f);  f = fmaf(wm[4], ry, f);  f = fmaf(wm[5], rz, f);
                f = fmaf(wm[6], dis, f);
            }
            Fb[wv][k * 64 + (lane ^ ((k & 7) << 3))] = f2bf(f);
        }

        // A-fragments: row j=l31, c-run c0=kt*16+8*hi (swizzle keeps 8-runs contiguous)
        short8 Af[4];
#pragma unroll
        for (int kt = 0; kt < 4; ++kt) {
            int c0 = kt * 16 + 8 * hi;
            Af[kt] = *(const short8*)&Fb[wv][l31 * 64 + (c0 ^ ((l31 & 7) << 3))];
        }
        f32x16 acc0, acc1;
#pragma unroll
        for (int i = 0; i < 16; ++i) { acc0[i] = 0.f; acc1[i] = 0.f; }
#pragma unroll
        for (int kt = 0; kt < 4; ++kt) {
            acc0 = __builtin_amdgcn_mfma_f32_32x32x16_bf16(Af[kt], Wb[0][kt], acc0, 0, 0, 0);
            acc1 = __builtin_amdgcn_mfma_f32_32x32x16_bf16(Af[kt], Wb[1][kt], acc1, 0, 0, 0);
        }

        float pooled0 = 0.f, pooled1 = 0.f;
#pragma unroll
        for (int r = 0; r < 12; ++r) {
            float s0 = acc0[r], s1 = acc1[r];
            float m = fmaxf(s0, s1);
#pragma unroll
            for (int off = 16; off >= 1; off >>= 1) m = fmaxf(m, __shfl_xor(m, off, 64));
            float e0 = __expf(s0 - m), e1 = __expf(s1 - m);
            float se = e0 + e1;
#pragma unroll
            for (int off = 16; off >= 1; off >>= 1) se += __shfl_xor(se, off, 64);
            float inv = 1.0f / se;
            int j = ((r & 3) + 8 * (r >> 2)) + 4 * hi;
            float f0 = bf2f(Fb[wv][j * 64 + (l31 ^ ((j & 7) << 3))]);
            float f1 = bf2f(Fb[wv][j * 64 + ((32 + l31) ^ ((j & 7) << 3))]);
            float p0 = e0 * inv * f0;
            float p1 = e1 * inv * f1;
            if (r >= 8) { p0 = hi ? 0.f : p0; p1 = hi ? 0.f : p1; }  // j>=20 rows on hi=1
            pooled0 += p0; pooled1 += p1;
        }
        pooled0 += __shfl_xor(pooled0, 32, 64);
        pooled1 += __shfl_xor(pooled1, 32, 64);
        if (!hi) {
            pool[wv][pi * 64 + l31]      = f2bf(pooled0);
            pool[wv][pi * 64 + 32 + l31] = f2bf(pooled1);
        }
    }

    // ---- batched epilogue over QPW points ----
    f32x16 oa;
#pragma unroll
    for (int i = 0; i < 16; ++i) oa[i] = 0.f;
    const int pcl = l31 & (QPW - 1);
#pragma unroll
    for (int kt = 0; kt < 4; ++kt) {                      // W_conv(32x64) @ pooled(64xQPW)
        const float* src = w_conv + l31 * 64 + kt * 16 + 8 * hi;
        short8 a;
#pragma unroll
        for (int i = 0; i < 8; ++i) a[i] = (short)f2bf(src[i]);
        short8 bb = *(const short8*)&pool[wv][pcl * 64 + kt * 16 + 8 * hi];
        oa = __builtin_amdgcn_mfma_f32_32x32x16_bf16(a, bb, oa, 0, 0, 0);
    }
#pragma unroll
    for (int kt = 0; kt < 2; ++kt) {                      // W_out(32x32) @ feat(32xQPW)
        const float* srcA = w_out + l31 * 32 + kt * 16 + 8 * hi;
        short8 a;
#pragma unroll
        for (int i = 0; i < 8; ++i) a[i] = (short)f2bf(srcA[i]);
        const float* srcB = fbase + (size_t)(nb + pcl) * INC + kt * 16 + 8 * hi;
        short8 bb;
#pragma unroll
        for (int i = 0; i < 8; ++i) bb[i] = (short)f2bf(srcB[i]);
        oa = __builtin_amdgcn_mfma_f32_32x32x16_bf16(a, bb, oa, 0, 0, 0);
    }
#pragma unroll
    for (int r = 0; r < 16; ++r) {
        int o = (r & 3) + 8 * (r >> 2) + 4 * hi;
        if (l31 < QPW) out[((size_t)(b * OUTC + o)) * NPTS + nb + l31] = oa[r];
    }
}

// ---------------- kernel 3a: per-channel batch stats ----------------
__global__ __launch_bounds__(256) void k_stats(const float* __restrict__ of,
                                               float* __restrict__ stats) {
    int c = blockIdx.x;
    int tid = threadIdx.x;
    float s = 0.f, s2 = 0.f;
    for (int i = tid; i < BATCH * NPTS; i += 256) {
        int b = i >> 12, n = i & (NPTS - 1);
        float v = of[((size_t)b * OUTC + c) * NPTS + n];
        s += v; s2 = fmaf(v, v, s2);
    }
#pragma unroll
    for (int off = 32; off >= 1; off >>= 1) {
        s += __shfl_xor(s, off, 64);
        s2 += __shfl_xor(s2, off, 64);
    }
    __shared__ float rs[4], rs2[4];
    if ((tid & 63) == 0) { rs[tid >> 6] = s; rs2[tid >> 6] = s2; }
    __syncthreads();
    if (tid == 0) {
        float S = (rs[0] + rs[1]) + (rs[2] + rs[3]);
        float S2 = (rs2[0] + rs2[1]) + (rs2[2] + rs2[3]);
        const float invn = 1.0f / (BATCH * NPTS);
        float mean = S * invn;
        float var = S2 * invn - mean * mean;
        stats[c] = mean;
        stats[32 + c] = rsqrtf(var + EPSBN);
    }
}

// ---------------- kernel 3b: normalize in place ----------------
__global__ __launch_bounds__(256) void k_norm(float* __restrict__ of,
                                              const float* __restrict__ stats,
                                              const float* __restrict__ gamma,
                                              const float* __restrict__ beta) {
    int i = blockIdx.x * 256 + threadIdx.x;
    if (i >= BATCH * OUTC * NPTS) return;
    int c = (i >> 12) & (OUTC - 1);
    float v = of[i];
    of[i] = (v - stats[c]) * stats[32 + c] * gamma[c] + beta[c];
}

// ---------------- launch ----------------
extern "C" void kernel_launch(void* const* d_in, const int* in_sizes, int n_in,
                              void* d_out, int out_size, void* d_ws, size_t ws_size,
                              hipStream_t stream) {
    const float* x      = (const float*)d_in[0];
    const float* feat   = (const float*)d_in[1];
    const float* w_mlp  = (const float*)d_in[2];
    const float* b_mlp  = (const float*)d_in[3];
    const float* w_att  = (const float*)d_in[4];
    const float* w_conv = (const float*)d_in[5];
    const float* w_out  = (const float*)d_in[7];
    const float* gamma  = (const float*)d_in[9];
    const float* beta   = (const float*)d_in[10];
    float* out = (float*)d_out;

    char* ws = (char*)d_ws;
    float4* xT4   = (float4*)ws;                                   // 262144 B
    float*  featT = (float*)(ws + 262144);                         // 2097152 B
    int*    neigh = (int*)(ws + 262144 + 2097152);                 // 1310720 B
    float*  stats = (float*)(ws + 262144 + 2097152 + 1310720);     // 256 B

    k_prep_x<<<(BATCH * NPTS + 255) / 256, 256, 0, stream>>>(x, xT4);
    k_prep_feat<<<(BATCH * INC * NPTS + 255) / 256, 256, 0, stream>>>(feat, featT);
    k_knn2<<<(BATCH * NPTS) / PPBK, 256, 0, stream>>>(xT4, neigh);
    k_attn2<<<(BATCH * NPTS) / (QPW * 4), 256, 0, stream>>>(xT4, featT, neigh, w_mlp, b_mlp,
                                                            w_att, w_conv, w_out, out);
    k_stats<<<OUTC, 256, 0, stream>>>(out, stats);
    k_norm<<<(BATCH * OUTC * NPTS + 255) / 256, 256, 0, stream>>>(out, stats, gamma, beta);
}

// Round 4
// 159.443 us; speedup vs baseline: 3.9057x; 1.1862x over previous
//
#include <hip/hip_runtime.h>
#include <hip/hip_bf16.h>

#define BATCH 4
#define NPTS  4096
#define KNBR  20
#define INC   32
#define TWC   64   // 2*INC
#define OUTC  32
#define EPSBN 1e-5f

typedef short short8 __attribute__((ext_vector_type(8)));
typedef float f32x16 __attribute__((ext_vector_type(16)));

// ---------------- helpers ----------------
__device__ __forceinline__ float rlf(float v, int l) {
    return __uint_as_float((unsigned)__builtin_amdgcn_readlane((int)__float_as_uint(v), l));
}
__device__ __forceinline__ ushort f2bf(float x) {        // fp32 -> bf16 bits (RNE)
    unsigned u = __float_as_uint(x);
    unsigned r = u + 0x7FFFu + ((u >> 16) & 1u);
    return (ushort)(r >> 16);
}
__device__ __forceinline__ float bf2f(ushort h) {
    return __uint_as_float(((unsigned)h) << 16);
}
__device__ __forceinline__ void gll16(const float4* g, float4* l) {
    __builtin_amdgcn_global_load_lds((const __attribute__((address_space(1))) void*)g,
                                     (__attribute__((address_space(3))) void*)l, 16, 0, 0);
}

// ---------------- kernel 0a: transpose x -> [B][N][{x,y,z,sq}] ----------------
__global__ __launch_bounds__(256) void k_prep_x(const float* __restrict__ x,
                                                float4* __restrict__ xT4) {
    int i = blockIdx.x * 256 + threadIdx.x;
    if (i >= BATCH * NPTS) return;
    int b = i / NPTS, n = i % NPTS;
    const float* xb = x + (size_t)b * 3 * NPTS;
    float x0 = xb[n], x1 = xb[NPTS + n], x2 = xb[2 * NPTS + n];
    float sq = fmaf(x2, x2, fmaf(x1, x1, x0 * x0));
    xT4[i] = make_float4(x0, x1, x2, sq);
}

// ---------------- kernel 0b: transpose feature -> [B][N][C] ----------------
__global__ __launch_bounds__(256) void k_prep_feat(const float* __restrict__ f,
                                                   float* __restrict__ fT) {
    int i = blockIdx.x * 256 + threadIdx.x;
    if (i >= BATCH * INC * NPTS) return;
    int n = i % NPTS; int t = i / NPTS; int c = t % INC; int b = t / INC;
    fT[((size_t)(b * NPTS + n)) * INC + c] = f[i];
}

// ---------------- kernel 1: KNN, filter + exact-set select ----------------
// One wave per point (4/block). Output contract: neigh[gp*20+0] = min key
// (self); slots 1..19 = rest of exact top-20 SET in arbitrary order (the
// downstream pooled-sum is permutation-invariant over k>=1).
// Phase 1: tau (upper bound on 20th d2) by 16-iter ballot-bisection over a
//   1024-candidate register subset.
// Phase 2: stream candidates (global_load_lds double-buffered 8 KB chunks),
//   per-lane atomic append of d2<=tau survivors as (d2bits<<32|idx) keys.
// Phase 3: exact 20th-d2 via 32-iter bisection over survivor regs; idx
//   tie-break sub-bisection (rare, uniform branch); unordered emit.
#define CAP   256
#define PPBK  4
__global__ __launch_bounds__(256) void k_knn3(const float4* __restrict__ xT4,
                                              int* __restrict__ neigh) {
    __shared__ float4 cand[2][512];                     // 2 x 8 KB
    __shared__ unsigned long long surv[PPBK][CAP];      // 8 KB
    __shared__ int scnt[PPBK];
    __shared__ int slot[PPBK];

    const int tid  = threadIdx.x;
    const int lane = tid & 63;
    const int wv   = tid >> 6;
    const int gp   = blockIdx.x * PPBK + wv;
    const int b    = gp >> 12;
    const float4* base = xT4 + (size_t)b * NPTS;

    if (lane == 0) { scnt[wv] = 0; slot[wv] = 1; }

    float4 me = xT4[gp];

    auto stage = [&](int c) {
        const float4* src = base + c * 512 + wv * 64 + lane;
        float4* dst = &cand[c & 1][wv * 64];            // wave-uniform base; HW adds lane*16
        gll16(src, dst);
        gll16(src + 256, dst + 256);
    };

    stage(0); stage(1);
    __syncthreads();

    // ---- phase 1: subset distances in regs ----
    unsigned bits[16];
#pragma unroll
    for (int j = 0; j < 8; ++j) {
        float4 o = cand[0][lane + 64 * j];
        float dot = fmaf(o.z, me.z, fmaf(o.y, me.y, o.x * me.x));
        bits[j] = __float_as_uint(fmaxf((me.w + o.w) - 2.0f * dot, 0.0f));
    }
#pragma unroll
    for (int j = 0; j < 8; ++j) {
        float4 o = cand[1][lane + 64 * j];
        float dot = fmaf(o.z, me.z, fmaf(o.y, me.y, o.x * me.x));
        bits[8 + j] = __float_as_uint(fmaxf((me.w + o.w) - 2.0f * dot, 0.0f));
    }
    __syncthreads();          // all waves done reading buf0/buf1
    stage(2);                 // prefetch chunk 2 into buf0 (overlaps bisection)

    unsigned lo = 0u, hi = 0xFF000000u;
    for (int it = 0; it < 16; ++it) {
        unsigned mid = lo + ((hi - lo) >> 1);
        int c = 0;
#pragma unroll
        for (int j = 0; j < 16; ++j) c += __popcll(__ballot(bits[j] <= mid));
        if (c >= KNBR) hi = mid; else lo = mid + 1;
    }
    const unsigned tau = hi;

    // ---- phase 2: append (subset candidates: idx = lane + 64j for j<16) ----
#pragma unroll
    for (int j = 0; j < 16; ++j) {
        if (bits[j] <= tau) {
            int pos = atomicAdd(&scnt[wv], 1);
            if (pos < CAP)
                surv[wv][pos] = ((unsigned long long)bits[j] << 32) | (unsigned)(lane + 64 * j);
        }
    }
    __syncthreads();          // chunk 2 staged

    for (int ch = 2; ch < 8; ++ch) {
        if (ch < 7) stage(ch + 1);
        const float4* cb = cand[ch & 1];
        const int ib = ch * 512 + lane;
#pragma unroll
        for (int j = 0; j < 8; ++j) {
            float4 o = cb[lane + 64 * j];
            float dot = fmaf(o.z, me.z, fmaf(o.y, me.y, o.x * me.x));
            unsigned bb = __float_as_uint(fmaxf((me.w + o.w) - 2.0f * dot, 0.0f));
            if (bb <= tau) {
                int pos = atomicAdd(&scnt[wv], 1);
                if (pos < CAP)
                    surv[wv][pos] = ((unsigned long long)bb << 32) | (unsigned)(ib + 64 * j);
            }
        }
        __syncthreads();
    }

    // ---- phase 3: exact top-20 set ----
    int cnt = scnt[wv]; if (cnt > CAP) cnt = CAP;
    unsigned long long k0 = (lane       < cnt) ? surv[wv][lane      ] : ~0ull;
    unsigned long long k1 = (lane +  64 < cnt) ? surv[wv][lane +  64] : ~0ull;
    unsigned long long k2 = (lane + 128 < cnt) ? surv[wv][lane + 128] : ~0ull;
    unsigned long long k3 = (lane + 192 < cnt) ? surv[wv][lane + 192] : ~0ull;
    unsigned d0 = (unsigned)(k0 >> 32), d1 = (unsigned)(k1 >> 32);
    unsigned d2 = (unsigned)(k2 >> 32), d3 = (unsigned)(k3 >> 32);
    unsigned i0 = (unsigned)k0, i1 = (unsigned)k1, i2 = (unsigned)k2, i3 = (unsigned)k3;

    // exact 20th-smallest d2 (32 iters fully collapse [0,tau])
    unsigned l2 = 0u, h2 = tau;
    for (int it = 0; it < 32; ++it) {
        unsigned mid = l2 + ((h2 - l2) >> 1);
        int c = __popcll(__ballot(d0 <= mid)) + __popcll(__ballot(d1 <= mid))
              + __popcll(__ballot(d2 <= mid)) + __popcll(__ballot(d3 <= mid));
        if (c >= KNBR) h2 = mid; else l2 = mid + 1;
    }
    const unsigned th = h2;
    int cless = __popcll(__ballot(d0 < th)) + __popcll(__ballot(d1 < th))
              + __popcll(__ballot(d2 < th)) + __popcll(__ballot(d3 < th));
    int need = KNBR - cless;
    bool t0 = (d0 == th), t1 = (d1 == th), t2 = (d2 == th), t3 = (d3 == th);
    int tcnt = __popcll(__ballot(t0)) + __popcll(__ballot(t1))
             + __popcll(__ballot(t2)) + __popcll(__ballot(t3));
    unsigned idxthr = 0xFFFFFFFFu;
    if (tcnt != need) {       // rare exact-d2-tie path (uniform branch)
        unsigned la = 0u, ha = 0xFFFFFFFFu;
        for (int it = 0; it < 32; ++it) {
            unsigned mid = la + ((ha - la) >> 1);
            int c = __popcll(__ballot(t0 && i0 <= mid)) + __popcll(__ballot(t1 && i1 <= mid))
                  + __popcll(__ballot(t2 && i2 <= mid)) + __popcll(__ballot(t3 && i3 <= mid));
            if (c >= need) ha = mid; else la = mid + 1;
        }
        idxthr = ha;
    }
    bool s0 = (d0 < th) || (t0 && i0 <= idxthr);
    bool s1 = (d1 < th) || (t1 && i1 <= idxthr);
    bool s2 = (d2 < th) || (t2 && i2 <= idxthr);
    bool s3 = (d3 < th) || (t3 && i3 <= idxthr);

    // global min key -> slot 0 (self)
    unsigned long long m01 = k0 < k1 ? k0 : k1;
    unsigned long long m23 = k2 < k3 ? k2 : k3;
    unsigned long long mk  = m01 < m23 ? m01 : m23;
#pragma unroll
    for (int off = 32; off >= 1; off >>= 1) {
        unsigned long long o = __shfl_xor(mk, off, 64);
        mk = o < mk ? o : mk;
    }
    const int ob = gp * KNBR;
    if (s0) { if (k0 == mk) neigh[ob] = (int)i0; else { int p = atomicAdd(&slot[wv], 1); neigh[ob + p] = (int)i0; } }
    if (s1) { if (k1 == mk) neigh[ob] = (int)i1; else { int p = atomicAdd(&slot[wv], 1); neigh[ob + p] = (int)i1; } }
    if (s2) { if (k2 == mk) neigh[ob] = (int)i2; else { int p = atomicAdd(&slot[wv], 1); neigh[ob + p] = (int)i2; } }
    if (s3) { if (k3 == mk) neigh[ob] = (int)i3; else { int p = atomicAdd(&slot[wv], 1); neigh[ob + p] = (int)i3; } }
}

// ---------------- kernel 2: MFMA attention (unchanged from R3) ----------------
#define QPW 4
__global__ __launch_bounds__(256) void k_attn2(
    const float4* __restrict__ xT4, const float* __restrict__ featT,
    const int* __restrict__ neigh,
    const float* __restrict__ w_mlp, const float* __restrict__ b_mlp,
    const float* __restrict__ w_att, const float* __restrict__ w_conv,
    const float* __restrict__ w_out, float* __restrict__ out) {

    __shared__ __align__(16) ushort Fb[4][32 * 64];
    __shared__ __align__(16) ushort pool[4][QPW * 64];

    const int tid  = threadIdx.x;
    const int lane = tid & 63;
    const int wv   = tid >> 6;
    const int hi   = lane >> 5;
    const int l31  = lane & 31;

    short8 Wb[2][4];
#pragma unroll
    for (int nt = 0; nt < 2; ++nt)
#pragma unroll
        for (int kt = 0; kt < 4; ++kt) {
            const float* src = w_att + (nt * 32 + l31) * 64 + kt * 16 + 8 * hi;
            short8 v;
#pragma unroll
            for (int i = 0; i < 8; ++i) v[i] = (short)f2bf(src[i]);
            Wb[nt][kt] = v;
        }

    float wm[7]; float bm = 0.f;
#pragma unroll
    for (int j = 0; j < 7; ++j) wm[j] = 0.f;
    if (hi) {
#pragma unroll
        for (int j = 0; j < 7; ++j) wm[j] = w_mlp[l31 * 7 + j];
        bm = b_mlp[l31];
    }

    const int gw  = blockIdx.x * 4 + wv;
    const int gp0 = gw * QPW;
    const int b   = gp0 >> 12;
    const int nb  = gp0 & (NPTS - 1);
    const float4* xb    = xT4 + (size_t)b * NPTS;
    const float*  fbase = featT + (size_t)b * NPTS * INC;

    for (int pi = 0; pi < QPW; ++pi) {
        const int gp = gp0 + pi;
        int nv = 0;
        if (!hi && l31 < KNBR) nv = neigh[gp * KNBR + l31];
        float4 ncl = xb[nv];

        float fv[KNBR];
#pragma unroll
        for (int k = 0; k < KNBR; ++k) {
            int snk = __builtin_amdgcn_readlane(nv, k);
            fv[k] = fbase[(size_t)snk * INC + l31];
        }
        const float c0x = rlf(ncl.x, 0), c0y = rlf(ncl.y, 0), c0z = rlf(ncl.z, 0);

#pragma unroll
        for (int k = 0; k < KNBR; ++k) {
            float rx = rlf(ncl.x, k) - c0x;
            float ry = rlf(ncl.y, k) - c0y;
            float rz = rlf(ncl.z, k) - c0z;
            float dis = sqrtf(fmaf(rz, rz, fmaf(ry, ry, rx * rx)));
            float f;
            if (!hi) {
                f = fv[k];
            } else {
                f = bm;
                f = fmaf(wm[0], c0x, f); f = fmaf(wm[1], c0y, f); f = fmaf(wm[2], c0z, f);
                f = fmaf(wm[3], rx, f);  f = fmaf(wm[4], ry, f);  f = fmaf(wm[5], rz, f);
                f = fmaf(wm[6], dis, f);
            }
            Fb[wv][k * 64 + (lane ^ ((k & 7) << 3))] = f2bf(f);
        }

        short8 Af[4];
#pragma unroll
        for (int kt = 0; kt < 4; ++kt) {
            int c0 = kt * 16 + 8 * hi;
            Af[kt] = *(const short8*)&Fb[wv][l31 * 64 + (c0 ^ ((l31 & 7) << 3))];
        }
        f32x16 acc0, acc1;
#pragma unroll
        for (int i = 0; i < 16; ++i) { acc0[i] = 0.f; acc1[i] = 0.f; }
#pragma unroll
        for (int kt = 0; kt < 4; ++kt) {
            acc0 = __builtin_amdgcn_mfma_f32_32x32x16_bf16(Af[kt], Wb[0][kt], acc0, 0, 0, 0);
            acc1 = __builtin_amdgcn_mfma_f32_32x32x16_bf16(Af[kt], Wb[1][kt], acc1, 0, 0, 0);
        }

        float pooled0 = 0.f, pooled1 = 0.f;
#pragma unroll
        for (int r = 0; r < 12; ++r) {
            float s0 = acc0[r], s1 = acc1[r];
            float m = fmaxf(s0, s1);
#pragma unroll
            for (int off = 16; off >= 1; off >>= 1) m = fmaxf(m, __shfl_xor(m, off, 64));
            float e0 = __expf(s0 - m), e1 = __expf(s1 - m);
            float se = e0 + e1;
#pragma unroll
            for (int off = 16; off >= 1; off >>= 1) se += __shfl_xor(se, off, 64);
            float inv = 1.0f / se;
            int j = ((r & 3) + 8 * (r >> 2)) + 4 * hi;
            float f0 = bf2f(Fb[wv][j * 64 + (l31 ^ ((j & 7) << 3))]);
            float f1 = bf2f(Fb[wv][j * 64 + ((32 + l31) ^ ((j & 7) << 3))]);
            float p0 = e0 * inv * f0;
            float p1 = e1 * inv * f1;
            if (r >= 8) { p0 = hi ? 0.f : p0; p1 = hi ? 0.f : p1; }
            pooled0 += p0; pooled1 += p1;
        }
        pooled0 += __shfl_xor(pooled0, 32, 64);
        pooled1 += __shfl_xor(pooled1, 32, 64);
        if (!hi) {
            pool[wv][pi * 64 + l31]      = f2bf(pooled0);
            pool[wv][pi * 64 + 32 + l31] = f2bf(pooled1);
        }
    }

    f32x16 oa;
#pragma unroll
    for (int i = 0; i < 16; ++i) oa[i] = 0.f;
    const int pcl = l31 & (QPW - 1);
#pragma unroll
    for (int kt = 0; kt < 4; ++kt) {
        const float* src = w_conv + l31 * 64 + kt * 16 + 8 * hi;
        short8 a;
#pragma unroll
        for (int i = 0; i < 8; ++i) a[i] = (short)f2bf(src[i]);
        short8 bb = *(const short8*)&pool[wv][pcl * 64 + kt * 16 + 8 * hi];
        oa = __builtin_amdgcn_mfma_f32_32x32x16_bf16(a, bb, oa, 0, 0, 0);
    }
#pragma unroll
    for (int kt = 0; kt < 2; ++kt) {
        const float* srcA = w_out + l31 * 32 + kt * 16 + 8 * hi;
        short8 a;
#pragma unroll
        for (int i = 0; i < 8; ++i) a[i] = (short)f2bf(srcA[i]);
        const float* srcB = fbase + (size_t)(nb + pcl) * INC + kt * 16 + 8 * hi;
        short8 bb;
#pragma unroll
        for (int i = 0; i < 8; ++i) bb[i] = (short)f2bf(srcB[i]);
        oa = __builtin_amdgcn_mfma_f32_32x32x16_bf16(a, bb, oa, 0, 0, 0);
    }
#pragma unroll
    for (int r = 0; r < 16; ++r) {
        int o = (r & 3) + 8 * (r >> 2) + 4 * hi;
        if (l31 < QPW) out[((size_t)(b * OUTC + o)) * NPTS + nb + l31] = oa[r];
    }
}

// ---------------- kernel 3a: per-channel batch stats ----------------
__global__ __launch_bounds__(256) void k_stats(const float* __restrict__ of,
                                               float* __restrict__ stats) {
    int c = blockIdx.x;
    int tid = threadIdx.x;
    float s = 0.f, s2 = 0.f;
    for (int i = tid; i < BATCH * NPTS; i += 256) {
        int b = i >> 12, n = i & (NPTS - 1);
        float v = of[((size_t)b * OUTC + c) * NPTS + n];
        s += v; s2 = fmaf(v, v, s2);
    }
#pragma unroll
    for (int off = 32; off >= 1; off >>= 1) {
        s += __shfl_xor(s, off, 64);
        s2 += __shfl_xor(s2, off, 64);
    }
    __shared__ float rs[4], rs2[4];
    if ((tid & 63) == 0) { rs[tid >> 6] = s; rs2[tid >> 6] = s2; }
    __syncthreads();
    if (tid == 0) {
        float S = (rs[0] + rs[1]) + (rs[2] + rs[3]);
        float S2 = (rs2[0] + rs2[1]) + (rs2[2] + rs2[3]);
        const float invn = 1.0f / (BATCH * NPTS);
        float mean = S * invn;
        float var = S2 * invn - mean * mean;
        stats[c] = mean;
        stats[32 + c] = rsqrtf(var + EPSBN);
    }
}

// ---------------- kernel 3b: normalize in place ----------------
__global__ __launch_bounds__(256) void k_norm(float* __restrict__ of,
                                              const float* __restrict__ stats,
                                              const float* __restrict__ gamma,
                                              const float* __restrict__ beta) {
    int i = blockIdx.x * 256 + threadIdx.x;
    if (i >= BATCH * OUTC * NPTS) return;
    int c = (i >> 12) & (OUTC - 1);
    float v = of[i];
    of[i] = (v - stats[c]) * stats[32 + c] * gamma[c] + beta[c];
}

// ---------------- launch ----------------
extern "C" void kernel_launch(void* const* d_in, const int* in_sizes, int n_in,
                              void* d_out, int out_size, void* d_ws, size_t ws_size,
                              hipStream_t stream) {
    const float* x      = (const float*)d_in[0];
    const float* feat   = (const float*)d_in[1];
    const float* w_mlp  = (const float*)d_in[2];
    const float* b_mlp  = (const float*)d_in[3];
    const float* w_att  = (const float*)d_in[4];
    const float* w_conv = (const float*)d_in[5];
    const float* w_out  = (const float*)d_in[7];
    const float* gamma  = (const float*)d_in[9];
    const float* beta   = (const float*)d_in[10];
    float* out = (float*)d_out;

    char* ws = (char*)d_ws;
    float4* xT4   = (float4*)ws;                                   // 262144 B
    float*  featT = (float*)(ws + 262144);                         // 2097152 B
    int*    neigh = (int*)(ws + 262144 + 2097152);                 // 1310720 B
    float*  stats = (float*)(ws + 262144 + 2097152 + 1310720);     // 256 B

    k_prep_x<<<(BATCH * NPTS + 255) / 256, 256, 0, stream>>>(x, xT4);
    k_prep_feat<<<(BATCH * INC * NPTS + 255) / 256, 256, 0, stream>>>(feat, featT);
    k_knn3<<<(BATCH * NPTS) / PPBK, 256, 0, stream>>>(xT4, neigh);
    k_attn2<<<(BATCH * NPTS) / (QPW * 4), 256, 0, stream>>>(xT4, featT, neigh, w_mlp, b_mlp,
                                                            w_att, w_conv, w_out, out);
    k_stats<<<OUTC, 256, 0, stream>>>(out, stats);
    k_norm<<<(BATCH * OUTC * NPTS + 255) / 256, 256, 0, stream>>>(out, stats, gamma, beta);
}

// Round 5
// 151.445 us; speedup vs baseline: 4.1119x; 1.0528x over previous
//
#include <hip/hip_runtime.h>
#include <hip/hip_bf16.h>

#define BATCH 4
#define NPTS  4096
#define KNBR  20
#define INC   32
#define TWC   64   // 2*INC
#define OUTC  32
#define EPSBN 1e-5f

typedef short short8 __attribute__((ext_vector_type(8)));
typedef float f32x16 __attribute__((ext_vector_type(16)));

// ---------------- helpers ----------------
__device__ __forceinline__ float rlf(float v, int l) {
    return __uint_as_float((unsigned)__builtin_amdgcn_readlane((int)__float_as_uint(v), l));
}
__device__ __forceinline__ ushort f2bf(float x) {        // fp32 -> bf16 bits (RNE)
    unsigned u = __float_as_uint(x);
    unsigned r = u + 0x7FFFu + ((u >> 16) & 1u);
    return (ushort)(r >> 16);
}
__device__ __forceinline__ float bf2f(ushort h) {
    return __uint_as_float(((unsigned)h) << 16);
}
__device__ __forceinline__ void gll16(const float4* g, float4* l) {
    __builtin_amdgcn_global_load_lds((const __attribute__((address_space(1))) void*)g,
                                     (__attribute__((address_space(3))) void*)l, 16, 0, 0);
}

// ---------------- kernel 0: fused transposes ----------------
// i < B*C*N: feature -> [B][N][C]. i < B*N (subset): x -> [B][N][{x,y,z,sq}].
__global__ __launch_bounds__(256) void k_prep(const float* __restrict__ x,
                                              const float* __restrict__ f,
                                              float4* __restrict__ xT4,
                                              float* __restrict__ fT) {
    int i = blockIdx.x * 256 + threadIdx.x;
    if (i < BATCH * NPTS) {
        int b = i / NPTS, n = i % NPTS;
        const float* xb = x + (size_t)b * 3 * NPTS;
        float x0 = xb[n], x1 = xb[NPTS + n], x2 = xb[2 * NPTS + n];
        float sq = fmaf(x2, x2, fmaf(x1, x1, x0 * x0));
        xT4[i] = make_float4(x0, x1, x2, sq);
    }
    if (i < BATCH * INC * NPTS) {
        int n = i % NPTS; int t = i / NPTS; int c = t % INC; int b = t / INC;
        fT[((size_t)(b * NPTS + n)) * INC + c] = f[i];
    }
}

// ---------------- kernel 1: KNN, filter + exact-set select ----------------
// 512-thread blocks, 8 waves = 8 points; staged chunks shared by all 8.
// Output contract: slot 0 = min key (self); slots 1..19 = rest of the exact
// top-20 SET, arbitrary order (downstream pooling is k-permutation-invariant).
#define CAP   256
#define PPBK  8
__global__ __launch_bounds__(512) void k_knn3(const float4* __restrict__ xT4,
                                              int* __restrict__ neigh) {
    __shared__ float4 cand[2][512];                     // 2 x 8 KB
    __shared__ unsigned long long surv[PPBK][CAP];      // 16 KB
    __shared__ int scnt[PPBK];
    __shared__ int slot[PPBK];

    const int tid  = threadIdx.x;
    const int lane = tid & 63;
    const int wv   = tid >> 6;
    const int gp   = blockIdx.x * PPBK + wv;
    const int b    = gp >> 12;
    const float4* base = xT4 + (size_t)b * NPTS;

    if (lane == 0) { scnt[wv] = 0; slot[wv] = 1; }

    float4 me = xT4[gp];

    auto stage = [&](int c) {
        const float4* src = base + c * 512 + wv * 64 + lane;
        float4* dst = &cand[c & 1][wv * 64];            // wave-uniform base; HW adds lane*16
        gll16(src, dst);
    };

    stage(0); stage(1);
    __syncthreads();

    // ---- phase 1: subset distances (candidates 0..1023) in regs ----
    unsigned bits[16];
#pragma unroll
    for (int j = 0; j < 8; ++j) {
        float4 o = cand[0][lane + 64 * j];
        float dot = fmaf(o.z, me.z, fmaf(o.y, me.y, o.x * me.x));
        bits[j] = __float_as_uint(fmaxf((me.w + o.w) - 2.0f * dot, 0.0f));
    }
#pragma unroll
    for (int j = 0; j < 8; ++j) {
        float4 o = cand[1][lane + 64 * j];
        float dot = fmaf(o.z, me.z, fmaf(o.y, me.y, o.x * me.x));
        bits[8 + j] = __float_as_uint(fmaxf((me.w + o.w) - 2.0f * dot, 0.0f));
    }
    __syncthreads();          // all waves done reading buf0/buf1
    stage(2);                 // prefetch chunk 2 into buf0 (overlaps bisection)

    unsigned lo = 0u, hi = 0xFF000000u;
    for (int it = 0; it < 16; ++it) {
        unsigned mid = lo + ((hi - lo) >> 1);
        int c = 0;
#pragma unroll
        for (int j = 0; j < 16; ++j) c += __popcll(__ballot(bits[j] <= mid));
        if (c >= KNBR) hi = mid; else lo = mid + 1;
    }
    const unsigned tau = hi;

    // ---- phase 2: append survivors ----
#pragma unroll
    for (int j = 0; j < 16; ++j) {
        if (bits[j] <= tau) {
            int pos = atomicAdd(&scnt[wv], 1);
            if (pos < CAP)
                surv[wv][pos] = ((unsigned long long)bits[j] << 32) | (unsigned)(lane + 64 * j);
        }
    }
    __syncthreads();          // chunk 2 staged

    for (int ch = 2; ch < 8; ++ch) {
        if (ch < 7) stage(ch + 1);
        const float4* cb = cand[ch & 1];
        const int ib = ch * 512 + lane;
#pragma unroll
        for (int j = 0; j < 8; ++j) {
            float4 o = cb[lane + 64 * j];
            float dot = fmaf(o.z, me.z, fmaf(o.y, me.y, o.x * me.x));
            unsigned bb = __float_as_uint(fmaxf((me.w + o.w) - 2.0f * dot, 0.0f));
            if (bb <= tau) {
                int pos = atomicAdd(&scnt[wv], 1);
                if (pos < CAP)
                    surv[wv][pos] = ((unsigned long long)bb << 32) | (unsigned)(ib + 64 * j);
            }
        }
        __syncthreads();
    }

    // ---- phase 3: exact top-20 set ----
    int cnt = scnt[wv]; if (cnt > CAP) cnt = CAP;
    unsigned long long k0 = (lane       < cnt) ? surv[wv][lane      ] : ~0ull;
    unsigned long long k1 = (lane +  64 < cnt) ? surv[wv][lane +  64] : ~0ull;
    unsigned long long k2 = (lane + 128 < cnt) ? surv[wv][lane + 128] : ~0ull;
    unsigned long long k3 = (lane + 192 < cnt) ? surv[wv][lane + 192] : ~0ull;
    unsigned d0 = (unsigned)(k0 >> 32), d1 = (unsigned)(k1 >> 32);
    unsigned d2 = (unsigned)(k2 >> 32), d3 = (unsigned)(k3 >> 32);
    unsigned i0 = (unsigned)k0, i1 = (unsigned)k1, i2 = (unsigned)k2, i3 = (unsigned)k3;

    unsigned l2 = 0u, h2 = tau;
    for (int it = 0; it < 32; ++it) {
        unsigned mid = l2 + ((h2 - l2) >> 1);
        int c = __popcll(__ballot(d0 <= mid)) + __popcll(__ballot(d1 <= mid))
              + __popcll(__ballot(d2 <= mid)) + __popcll(__ballot(d3 <= mid));
        if (c >= KNBR) h2 = mid; else l2 = mid + 1;
    }
    const unsigned th = h2;
    int cless = __popcll(__ballot(d0 < th)) + __popcll(__ballot(d1 < th))
              + __popcll(__ballot(d2 < th)) + __popcll(__ballot(d3 < th));
    int need = KNBR - cless;
    bool t0 = (d0 == th), t1 = (d1 == th), t2 = (d2 == th), t3 = (d3 == th);
    int tcnt = __popcll(__ballot(t0)) + __popcll(__ballot(t1))
             + __popcll(__ballot(t2)) + __popcll(__ballot(t3));
    unsigned idxthr = 0xFFFFFFFFu;
    if (tcnt != need) {       // rare exact-d2-tie path (uniform branch)
        unsigned la = 0u, ha = 0xFFFFFFFFu;
        for (int it = 0; it < 32; ++it) {
            unsigned mid = la + ((ha - la) >> 1);
            int c = __popcll(__ballot(t0 && i0 <= mid)) + __popcll(__ballot(t1 && i1 <= mid))
                  + __popcll(__ballot(t2 && i2 <= mid)) + __popcll(__ballot(t3 && i3 <= mid));
            if (c >= need) ha = mid; else la = mid + 1;
        }
        idxthr = ha;
    }
    bool s0 = (d0 < th) || (t0 && i0 <= idxthr);
    bool s1 = (d1 < th) || (t1 && i1 <= idxthr);
    bool s2 = (d2 < th) || (t2 && i2 <= idxthr);
    bool s3 = (d3 < th) || (t3 && i3 <= idxthr);

    unsigned long long m01 = k0 < k1 ? k0 : k1;
    unsigned long long m23 = k2 < k3 ? k2 : k3;
    unsigned long long mk  = m01 < m23 ? m01 : m23;
#pragma unroll
    for (int off = 32; off >= 1; off >>= 1) {
        unsigned long long o = __shfl_xor(mk, off, 64);
        mk = o < mk ? o : mk;
    }
    const int ob = gp * KNBR;
    if (s0) { if (k0 == mk) neigh[ob] = (int)i0; else { int p = atomicAdd(&slot[wv], 1); neigh[ob + p] = (int)i0; } }
    if (s1) { if (k1 == mk) neigh[ob] = (int)i1; else { int p = atomicAdd(&slot[wv], 1); neigh[ob + p] = (int)i1; } }
    if (s2) { if (k2 == mk) neigh[ob] = (int)i2; else { int p = atomicAdd(&slot[wv], 1); neigh[ob + p] = (int)i2; } }
    if (s3) { if (k3 == mk) neigh[ob] = (int)i3; else { int p = atomicAdd(&slot[wv], 1); neigh[ob + p] = (int)i3; } }
}

// ---------------- kernel 2: MFMA attention (QPW=2 -> 2048 blocks, full occupancy) ----------------
#define QPW 2
__global__ __launch_bounds__(256) void k_attn2(
    const float4* __restrict__ xT4, const float* __restrict__ featT,
    const int* __restrict__ neigh,
    const float* __restrict__ w_mlp, const float* __restrict__ b_mlp,
    const float* __restrict__ w_att, const float* __restrict__ w_conv,
    const float* __restrict__ w_out, float* __restrict__ out) {

    __shared__ __align__(16) ushort Fb[4][32 * 64];     // 16 KB
    __shared__ __align__(16) ushort pool[4][QPW * 64];  // 1 KB

    const int tid  = threadIdx.x;
    const int lane = tid & 63;
    const int wv   = tid >> 6;
    const int hi   = lane >> 5;
    const int l31  = lane & 31;

    short8 Wb[2][4];
#pragma unroll
    for (int nt = 0; nt < 2; ++nt)
#pragma unroll
        for (int kt = 0; kt < 4; ++kt) {
            const float* src = w_att + (nt * 32 + l31) * 64 + kt * 16 + 8 * hi;
            short8 v;
#pragma unroll
            for (int i = 0; i < 8; ++i) v[i] = (short)f2bf(src[i]);
            Wb[nt][kt] = v;
        }

    float wm[7]; float bm = 0.f;
#pragma unroll
    for (int j = 0; j < 7; ++j) wm[j] = 0.f;
    if (hi) {
#pragma unroll
        for (int j = 0; j < 7; ++j) wm[j] = w_mlp[l31 * 7 + j];
        bm = b_mlp[l31];
    }

    const int gw  = blockIdx.x * 4 + wv;
    const int gp0 = gw * QPW;
    const int b   = gp0 >> 12;
    const int nb  = gp0 & (NPTS - 1);
    const float4* xb    = xT4 + (size_t)b * NPTS;
    const float*  fbase = featT + (size_t)b * NPTS * INC;

    for (int pi = 0; pi < QPW; ++pi) {
        const int gp = gp0 + pi;
        int nv = 0;
        if (!hi && l31 < KNBR) nv = neigh[gp * KNBR + l31];
        float4 ncl = xb[nv];

        float fv[KNBR];
#pragma unroll
        for (int k = 0; k < KNBR; ++k) {
            int snk = __builtin_amdgcn_readlane(nv, k);
            fv[k] = fbase[(size_t)snk * INC + l31];
        }
        const float c0x = rlf(ncl.x, 0), c0y = rlf(ncl.y, 0), c0z = rlf(ncl.z, 0);

#pragma unroll
        for (int k = 0; k < KNBR; ++k) {
            float rx = rlf(ncl.x, k) - c0x;
            float ry = rlf(ncl.y, k) - c0y;
            float rz = rlf(ncl.z, k) - c0z;
            float dis = sqrtf(fmaf(rz, rz, fmaf(ry, ry, rx * rx)));
            float f;
            if (!hi) {
                f = fv[k];
            } else {
                f = bm;
                f = fmaf(wm[0], c0x, f); f = fmaf(wm[1], c0y, f); f = fmaf(wm[2], c0z, f);
                f = fmaf(wm[3], rx, f);  f = fmaf(wm[4], ry, f);  f = fmaf(wm[5], rz, f);
                f = fmaf(wm[6], dis, f);
            }
            Fb[wv][k * 64 + (lane ^ ((k & 7) << 3))] = f2bf(f);
        }

        short8 Af[4];
#pragma unroll
        for (int kt = 0; kt < 4; ++kt) {
            int c0 = kt * 16 + 8 * hi;
            Af[kt] = *(const short8*)&Fb[wv][l31 * 64 + (c0 ^ ((l31 & 7) << 3))];
        }
        f32x16 acc0, acc1;
#pragma unroll
        for (int i = 0; i < 16; ++i) { acc0[i] = 0.f; acc1[i] = 0.f; }
#pragma unroll
        for (int kt = 0; kt < 4; ++kt) {
            acc0 = __builtin_amdgcn_mfma_f32_32x32x16_bf16(Af[kt], Wb[0][kt], acc0, 0, 0, 0);
            acc1 = __builtin_amdgcn_mfma_f32_32x32x16_bf16(Af[kt], Wb[1][kt], acc1, 0, 0, 0);
        }

        float pooled0 = 0.f, pooled1 = 0.f;
#pragma unroll
        for (int r = 0; r < 12; ++r) {
            float s0 = acc0[r], s1 = acc1[r];
            float m = fmaxf(s0, s1);
#pragma unroll
            for (int off = 16; off >= 1; off >>= 1) m = fmaxf(m, __shfl_xor(m, off, 64));
            float e0 = __expf(s0 - m), e1 = __expf(s1 - m);
            float se = e0 + e1;
#pragma unroll
            for (int off = 16; off >= 1; off >>= 1) se += __shfl_xor(se, off, 64);
            float inv = 1.0f / se;
            int j = ((r & 3) + 8 * (r >> 2)) + 4 * hi;
            float f0 = bf2f(Fb[wv][j * 64 + (l31 ^ ((j & 7) << 3))]);
            float f1 = bf2f(Fb[wv][j * 64 + ((32 + l31) ^ ((j & 7) << 3))]);
            float p0 = e0 * inv * f0;
            float p1 = e1 * inv * f1;
            if (r >= 8) { p0 = hi ? 0.f : p0; p1 = hi ? 0.f : p1; }
            pooled0 += p0; pooled1 += p1;
        }
        pooled0 += __shfl_xor(pooled0, 32, 64);
        pooled1 += __shfl_xor(pooled1, 32, 64);
        if (!hi) {
            pool[wv][pi * 64 + l31]      = f2bf(pooled0);
            pool[wv][pi * 64 + 32 + l31] = f2bf(pooled1);
        }
    }

    f32x16 oa;
#pragma unroll
    for (int i = 0; i < 16; ++i) oa[i] = 0.f;
    const int pcl = l31 & (QPW - 1);
#pragma unroll
    for (int kt = 0; kt < 4; ++kt) {
        const float* src = w_conv + l31 * 64 + kt * 16 + 8 * hi;
        short8 a;
#pragma unroll
        for (int i = 0; i < 8; ++i) a[i] = (short)f2bf(src[i]);
        short8 bb = *(const short8*)&pool[wv][pcl * 64 + kt * 16 + 8 * hi];
        oa = __builtin_amdgcn_mfma_f32_32x32x16_bf16(a, bb, oa, 0, 0, 0);
    }
#pragma unroll
    for (int kt = 0; kt < 2; ++kt) {
        const float* srcA = w_out + l31 * 32 + kt * 16 + 8 * hi;
        short8 a;
#pragma unroll
        for (int i = 0; i < 8; ++i) a[i] = (short)f2bf(srcA[i]);
        const float* srcB = fbase + (size_t)(nb + pcl) * INC + kt * 16 + 8 * hi;
        short8 bb;
#pragma unroll
        for (int i = 0; i < 8; ++i) bb[i] = (short)f2bf(srcB[i]);
        oa = __builtin_amdgcn_mfma_f32_32x32x16_bf16(a, bb, oa, 0, 0, 0);
    }
#pragma unroll
    for (int r = 0; r < 16; ++r) {
        int o = (r & 3) + 8 * (r >> 2) + 4 * hi;
        if (l31 < QPW) out[((size_t)(b * OUTC + o)) * NPTS + nb + l31] = oa[r];
    }
}

// ---------------- kernel 3a: per-channel batch stats ----------------
__global__ __launch_bounds__(256) void k_stats(const float* __restrict__ of,
                                               float* __restrict__ stats) {
    int c = blockIdx.x;
    int tid = threadIdx.x;
    float s = 0.f, s2 = 0.f;
    for (int i = tid; i < BATCH * NPTS; i += 256) {
        int b = i >> 12, n = i & (NPTS - 1);
        float v = of[((size_t)b * OUTC + c) * NPTS + n];
        s += v; s2 = fmaf(v, v, s2);
    }
#pragma unroll
    for (int off = 32; off >= 1; off >>= 1) {
        s += __shfl_xor(s, off, 64);
        s2 += __shfl_xor(s2, off, 64);
    }
    __shared__ float rs[4], rs2[4];
    if ((tid & 63) == 0) { rs[tid >> 6] = s; rs2[tid >> 6] = s2; }
    __syncthreads();
    if (tid == 0) {
        float S = (rs[0] + rs[1]) + (rs[2] + rs[3]);
        float S2 = (rs2[0] + rs2[1]) + (rs2[2] + rs2[3]);
        const float invn = 1.0f / (BATCH * NPTS);
        float mean = S * invn;
        float var = S2 * invn - mean * mean;
        stats[c] = mean;
        stats[32 + c] = rsqrtf(var + EPSBN);
    }
}

// ---------------- kernel 3b: normalize in place ----------------
__global__ __launch_bounds__(256) void k_norm(float* __restrict__ of,
                                              const float* __restrict__ stats,
                                              const float* __restrict__ gamma,
                                              const float* __restrict__ beta) {
    int i = blockIdx.x * 256 + threadIdx.x;
    if (i >= BATCH * OUTC * NPTS) return;
    int c = (i >> 12) & (OUTC - 1);
    float v = of[i];
    of[i] = (v - stats[c]) * stats[32 + c] * gamma[c] + beta[c];
}

// ---------------- launch ----------------
extern "C" void kernel_launch(void* const* d_in, const int* in_sizes, int n_in,
                              void* d_out, int out_size, void* d_ws, size_t ws_size,
                              hipStream_t stream) {
    const float* x      = (const float*)d_in[0];
    const float* feat   = (const float*)d_in[1];
    const float* w_mlp  = (const float*)d_in[2];
    const float* b_mlp  = (const float*)d_in[3];
    const float* w_att  = (const float*)d_in[4];
    const float* w_conv = (const float*)d_in[5];
    const float* w_out  = (const float*)d_in[7];
    const float* gamma  = (const float*)d_in[9];
    const float* beta   = (const float*)d_in[10];
    float* out = (float*)d_out;

    char* ws = (char*)d_ws;
    float4* xT4   = (float4*)ws;                                   // 262144 B
    float*  featT = (float*)(ws + 262144);                         // 2097152 B
    int*    neigh = (int*)(ws + 262144 + 2097152);                 // 1310720 B
    float*  stats = (float*)(ws + 262144 + 2097152 + 1310720);     // 256 B

    k_prep<<<(BATCH * INC * NPTS + 255) / 256, 256, 0, stream>>>(x, feat, xT4, featT);
    k_knn3<<<(BATCH * NPTS) / PPBK, 512, 0, stream>>>(xT4, neigh);
    k_attn2<<<(BATCH * NPTS) / (QPW * 4), 256, 0, stream>>>(xT4, featT, neigh, w_mlp, b_mlp,
                                                            w_att, w_conv, w_out, out);
    k_stats<<<OUTC, 256, 0, stream>>>(out, stats);
    k_norm<<<(BATCH * OUTC * NPTS + 255) / 256, 256, 0, stream>>>(out, stats, gamma, beta);
}

// Round 6
// 141.480 us; speedup vs baseline: 4.4015x; 1.0704x over previous
//
#include <hip/hip_runtime.h>
#include <hip/hip_bf16.h>

#define BATCH 4
#define NPTS  4096
#define KNBR  20
#define INC   32
#define TWC   64   // 2*INC
#define OUTC  32
#define EPSBN 1e-5f

typedef short short8 __attribute__((ext_vector_type(8)));
typedef float f32x16 __attribute__((ext_vector_type(16)));

// ---------------- helpers ----------------
__device__ __forceinline__ float rlf(float v, int l) {
    return __uint_as_float((unsigned)__builtin_amdgcn_readlane((int)__float_as_uint(v), l));
}
__device__ __forceinline__ ushort f2bf(float x) {        // fp32 -> bf16 bits (RNE)
    unsigned u = __float_as_uint(x);
    unsigned r = u + 0x7FFFu + ((u >> 16) & 1u);
    return (ushort)(r >> 16);
}
__device__ __forceinline__ float bf2f(ushort h) {
    return __uint_as_float(((unsigned)h) << 16);
}
__device__ __forceinline__ void gll16(const float4* g, float4* l) {
    __builtin_amdgcn_global_load_lds((const __attribute__((address_space(1))) void*)g,
                                     (__attribute__((address_space(3))) void*)l, 16, 0, 0);
}

// ---------------- kernel 0: fused transposes + weight prepack ----------------
// i < B*N: x -> [B][N][{x,y,z,sq}].  i < B*C*N: feature -> [B][N][C] (bf16).
// Last block: pack w_att/w_conv/w_out into MFMA fragment order (bf16) and
// w_mlp+b_mlp into [e][8].
__global__ __launch_bounds__(256) void k_prep(const float* __restrict__ x,
                                              const float* __restrict__ f,
                                              float4* __restrict__ xT4,
                                              ushort* __restrict__ fT,
                                              const float* __restrict__ w_att,
                                              const float* __restrict__ w_conv,
                                              const float* __restrict__ w_out,
                                              const float* __restrict__ w_mlp,
                                              const float* __restrict__ b_mlp,
                                              short8* __restrict__ wattF,
                                              short8* __restrict__ wconvF,
                                              short8* __restrict__ woutF,
                                              float* __restrict__ wmlp8) {
    int i = blockIdx.x * 256 + threadIdx.x;
    if (i < BATCH * NPTS) {
        int b = i / NPTS, n = i % NPTS;
        const float* xb = x + (size_t)b * 3 * NPTS;
        float x0 = xb[n], x1 = xb[NPTS + n], x2 = xb[2 * NPTS + n];
        float sq = fmaf(x2, x2, fmaf(x1, x1, x0 * x0));
        xT4[i] = make_float4(x0, x1, x2, sq);
    }
    if (i < BATCH * INC * NPTS) {
        int n = i % NPTS; int t = i / NPTS; int c = t % INC; int b = t / INC;
        fT[((size_t)(b * NPTS + n)) * INC + c] = f2bf(f[i]);
    }
    if (blockIdx.x == gridDim.x - 1) {
        int t = threadIdx.x;
        for (int idx = t; idx < 14 * 64; idx += 256) {
            int fr = idx >> 6, ln = idx & 63, l31 = ln & 31, h8 = (ln >> 5) * 8;
            short8 v;
            if (fr < 8) {
                int nt = fr >> 2, kt = fr & 3;
                const float* s = w_att + (nt * 32 + l31) * 64 + kt * 16 + h8;
#pragma unroll
                for (int j = 0; j < 8; ++j) v[j] = (short)f2bf(s[j]);
                wattF[fr * 64 + ln] = v;
            } else if (fr < 12) {
                int kt = fr - 8;
                const float* s = w_conv + l31 * 64 + kt * 16 + h8;
#pragma unroll
                for (int j = 0; j < 8; ++j) v[j] = (short)f2bf(s[j]);
                wconvF[kt * 64 + ln] = v;
            } else {
                int kt = fr - 12;
                const float* s = w_out + l31 * 32 + kt * 16 + h8;
#pragma unroll
                for (int j = 0; j < 8; ++j) v[j] = (short)f2bf(s[j]);
                woutF[kt * 64 + ln] = v;
            }
        }
        for (int idx = t; idx < 512; idx += 256) {
            int e = idx >> 3, j = idx & 7;
            wmlp8[idx] = (j < 7) ? w_mlp[e * 7 + j] : b_mlp[e];
        }
    }
}

// ---------------- kernel 1: KNN, filter + exact-set select (unchanged R5) ----------------
#define CAP   256
#define PPBK  8
__global__ __launch_bounds__(512) void k_knn3(const float4* __restrict__ xT4,
                                              int* __restrict__ neigh) {
    __shared__ float4 cand[2][512];
    __shared__ unsigned long long surv[PPBK][CAP];
    __shared__ int scnt[PPBK];
    __shared__ int slot[PPBK];

    const int tid  = threadIdx.x;
    const int lane = tid & 63;
    const int wv   = tid >> 6;
    const int gp   = blockIdx.x * PPBK + wv;
    const int b    = gp >> 12;
    const float4* base = xT4 + (size_t)b * NPTS;

    if (lane == 0) { scnt[wv] = 0; slot[wv] = 1; }

    float4 me = xT4[gp];

    auto stage = [&](int c) {
        const float4* src = base + c * 512 + wv * 64 + lane;
        float4* dst = &cand[c & 1][wv * 64];
        gll16(src, dst);
    };

    stage(0); stage(1);
    __syncthreads();

    unsigned bits[16];
#pragma unroll
    for (int j = 0; j < 8; ++j) {
        float4 o = cand[0][lane + 64 * j];
        float dot = fmaf(o.z, me.z, fmaf(o.y, me.y, o.x * me.x));
        bits[j] = __float_as_uint(fmaxf((me.w + o.w) - 2.0f * dot, 0.0f));
    }
#pragma unroll
    for (int j = 0; j < 8; ++j) {
        float4 o = cand[1][lane + 64 * j];
        float dot = fmaf(o.z, me.z, fmaf(o.y, me.y, o.x * me.x));
        bits[8 + j] = __float_as_uint(fmaxf((me.w + o.w) - 2.0f * dot, 0.0f));
    }
    __syncthreads();
    stage(2);

    unsigned lo = 0u, hi = 0xFF000000u;
    for (int it = 0; it < 16; ++it) {
        unsigned mid = lo + ((hi - lo) >> 1);
        int c = 0;
#pragma unroll
        for (int j = 0; j < 16; ++j) c += __popcll(__ballot(bits[j] <= mid));
        if (c >= KNBR) hi = mid; else lo = mid + 1;
    }
    const unsigned tau = hi;

#pragma unroll
    for (int j = 0; j < 16; ++j) {
        if (bits[j] <= tau) {
            int pos = atomicAdd(&scnt[wv], 1);
            if (pos < CAP)
                surv[wv][pos] = ((unsigned long long)bits[j] << 32) | (unsigned)(lane + 64 * j);
        }
    }
    __syncthreads();

    for (int ch = 2; ch < 8; ++ch) {
        if (ch < 7) stage(ch + 1);
        const float4* cb = cand[ch & 1];
        const int ib = ch * 512 + lane;
#pragma unroll
        for (int j = 0; j < 8; ++j) {
            float4 o = cb[lane + 64 * j];
            float dot = fmaf(o.z, me.z, fmaf(o.y, me.y, o.x * me.x));
            unsigned bb = __float_as_uint(fmaxf((me.w + o.w) - 2.0f * dot, 0.0f));
            if (bb <= tau) {
                int pos = atomicAdd(&scnt[wv], 1);
                if (pos < CAP)
                    surv[wv][pos] = ((unsigned long long)bb << 32) | (unsigned)(ib + 64 * j);
            }
        }
        __syncthreads();
    }

    int cnt = scnt[wv]; if (cnt > CAP) cnt = CAP;
    unsigned long long k0 = (lane       < cnt) ? surv[wv][lane      ] : ~0ull;
    unsigned long long k1 = (lane +  64 < cnt) ? surv[wv][lane +  64] : ~0ull;
    unsigned long long k2 = (lane + 128 < cnt) ? surv[wv][lane + 128] : ~0ull;
    unsigned long long k3 = (lane + 192 < cnt) ? surv[wv][lane + 192] : ~0ull;
    unsigned d0 = (unsigned)(k0 >> 32), d1 = (unsigned)(k1 >> 32);
    unsigned d2 = (unsigned)(k2 >> 32), d3 = (unsigned)(k3 >> 32);
    unsigned i0 = (unsigned)k0, i1 = (unsigned)k1, i2 = (unsigned)k2, i3 = (unsigned)k3;

    unsigned l2 = 0u, h2 = tau;
    for (int it = 0; it < 32; ++it) {
        unsigned mid = l2 + ((h2 - l2) >> 1);
        int c = __popcll(__ballot(d0 <= mid)) + __popcll(__ballot(d1 <= mid))
              + __popcll(__ballot(d2 <= mid)) + __popcll(__ballot(d3 <= mid));
        if (c >= KNBR) h2 = mid; else l2 = mid + 1;
    }
    const unsigned th = h2;
    int cless = __popcll(__ballot(d0 < th)) + __popcll(__ballot(d1 < th))
              + __popcll(__ballot(d2 < th)) + __popcll(__ballot(d3 < th));
    int need = KNBR - cless;
    bool t0 = (d0 == th), t1 = (d1 == th), t2 = (d2 == th), t3 = (d3 == th);
    int tcnt = __popcll(__ballot(t0)) + __popcll(__ballot(t1))
             + __popcll(__ballot(t2)) + __popcll(__ballot(t3));
    unsigned idxthr = 0xFFFFFFFFu;
    if (tcnt != need) {
        unsigned la = 0u, ha = 0xFFFFFFFFu;
        for (int it = 0; it < 32; ++it) {
            unsigned mid = la + ((ha - la) >> 1);
            int c = __popcll(__ballot(t0 && i0 <= mid)) + __popcll(__ballot(t1 && i1 <= mid))
                  + __popcll(__ballot(t2 && i2 <= mid)) + __popcll(__ballot(t3 && i3 <= mid));
            if (c >= need) ha = mid; else la = mid + 1;
        }
        idxthr = ha;
    }
    bool s0 = (d0 < th) || (t0 && i0 <= idxthr);
    bool s1 = (d1 < th) || (t1 && i1 <= idxthr);
    bool s2 = (d2 < th) || (t2 && i2 <= idxthr);
    bool s3 = (d3 < th) || (t3 && i3 <= idxthr);

    unsigned long long m01 = k0 < k1 ? k0 : k1;
    unsigned long long m23 = k2 < k3 ? k2 : k3;
    unsigned long long mk  = m01 < m23 ? m01 : m23;
#pragma unroll
    for (int off = 32; off >= 1; off >>= 1) {
        unsigned long long o = __shfl_xor(mk, off, 64);
        mk = o < mk ? o : mk;
    }
    const int ob = gp * KNBR;
    if (s0) { if (k0 == mk) neigh[ob] = (int)i0; else { int p = atomicAdd(&slot[wv], 1); neigh[ob + p] = (int)i0; } }
    if (s1) { if (k1 == mk) neigh[ob] = (int)i1; else { int p = atomicAdd(&slot[wv], 1); neigh[ob + p] = (int)i1; } }
    if (s2) { if (k2 == mk) neigh[ob] = (int)i2; else { int p = atomicAdd(&slot[wv], 1); neigh[ob + p] = (int)i2; } }
    if (s3) { if (k3 == mk) neigh[ob] = (int)i3; else { int p = atomicAdd(&slot[wv], 1); neigh[ob + p] = (int)i3; } }
}

// ---------------- kernel 2: dual-orientation MFMA attention, 1 point/wave ----------------
// Flipped mfma (A=W_att rows d, B=F-frags) puts the full d-column in lane k ->
// lane-local softmax stats (m, 1/Z) with one xor32 shuffle each, broadcast via
// 24B of LDS. Original-orientation accs then pool with lane-local k-sums.
__global__ __launch_bounds__(256, 8) void k_attn3(
    const float4* __restrict__ xT4, const ushort* __restrict__ fbT,
    const int* __restrict__ neigh, const float* __restrict__ wmlp8,
    const short8* __restrict__ wattF, const short8* __restrict__ wconvF,
    const short8* __restrict__ woutF, float* __restrict__ out) {

    __shared__ __align__(16) ushort Fb[4][32 * 64];   // 16 KB
    __shared__ __align__(16) float4 f4buf[4][32];     // 2 KB
    __shared__ __align__(8)  float2 mzb[4][32];       // 1 KB
    __shared__ __align__(16) ushort pool[4][64];      // 512 B

    const int tid  = threadIdx.x;
    const int lane = tid & 63;
    const int wv   = tid >> 6;
    const int hi   = lane >> 5;
    const int l31  = lane & 31;

    const int gp = blockIdx.x * 4 + wv;               // one point per wave
    const int b  = gp >> 12;
    const int nb = gp & (NPTS - 1);
    const float4* xb = xT4 + (size_t)b * NPTS;
    const ushort* fb = fbT + (size_t)b * NPTS * INC;

    int nv = 0;
    if (l31 < KNBR) nv = neigh[gp * KNBR + l31];      // both halves hold k=l31's idx
    float4 ncl = xb[nv];
    if (!hi && l31 < KNBR) f4buf[wv][l31] = ncl;

    float wm[8];
    {
        const float4* w8 = (const float4*)(wmlp8 + l31 * 8);
        float4 a = w8[0], bq = w8[1];
        wm[0] = a.x; wm[1] = a.y; wm[2] = a.z; wm[3] = a.w;
        wm[4] = bq.x; wm[5] = bq.y; wm[6] = bq.z; wm[7] = bq.w;
    }
    const float c0x = rlf(ncl.x, 0), c0y = rlf(ncl.y, 0), c0z = rlf(ncl.z, 0);

    // ---- staging: predicated, column = lane ----
#pragma unroll
    for (int k = 0; k < KNBR; ++k) {
        int snk = __builtin_amdgcn_readlane(nv, k);
        ushort fraw = fb[(size_t)snk * INC + l31];    // c<32 path (lanes>=32 dup read)
        float4 nk4 = f4buf[wv][k];                    // wave-uniform broadcast
        float rx = nk4.x - c0x, ry = nk4.y - c0y, rz = nk4.z - c0z;
        float dis = sqrtf(fmaf(rz, rz, fmaf(ry, ry, rx * rx)));
        float fm = wm[7];
        fm = fmaf(wm[0], c0x, fm); fm = fmaf(wm[1], c0y, fm); fm = fmaf(wm[2], c0z, fm);
        fm = fmaf(wm[3], rx, fm);  fm = fmaf(wm[4], ry, fm);  fm = fmaf(wm[5], rz, fm);
        fm = fmaf(wm[6], dis, fm);
        ushort fbits = hi ? f2bf(fm) : fraw;
        Fb[wv][k * 64 + (lane ^ ((k & 7) << 3))] = fbits;
    }

    // ---- fragments (row l31): serve as A (orig) AND B (flip) ----
    short8 Af[4];
#pragma unroll
    for (int kt = 0; kt < 4; ++kt) {
        int c0 = kt * 16 + 8 * hi;
        Af[kt] = *(const short8*)&Fb[wv][l31 * 64 + (c0 ^ ((l31 & 7) << 3))];
    }

    // ---- flipped orientation: lane k holds d-column -> lane-local stats ----
    float mloc, zloc;
    {
        f32x16 af;
#pragma unroll
        for (int i = 0; i < 16; ++i) af[i] = 0.f;
#pragma unroll
        for (int kt = 0; kt < 4; ++kt)
            af = __builtin_amdgcn_mfma_f32_32x32x16_bf16(wattF[kt * 64 + lane], Af[kt], af, 0, 0, 0);
        float m0 = af[0];
#pragma unroll
        for (int i = 1; i < 16; ++i) m0 = fmaxf(m0, af[i]);
        float z0 = 0.f;
#pragma unroll
        for (int i = 0; i < 16; ++i) z0 += __expf(af[i] - m0);
        mloc = m0; zloc = z0;
    }
    {
        f32x16 af;
#pragma unroll
        for (int i = 0; i < 16; ++i) af[i] = 0.f;
#pragma unroll
        for (int kt = 0; kt < 4; ++kt)
            af = __builtin_amdgcn_mfma_f32_32x32x16_bf16(wattF[(4 + kt) * 64 + lane], Af[kt], af, 0, 0, 0);
        float m1 = af[0];
#pragma unroll
        for (int i = 1; i < 16; ++i) m1 = fmaxf(m1, af[i]);
        float z1 = 0.f;
#pragma unroll
        for (int i = 0; i < 16; ++i) z1 += __expf(af[i] - m1);
        float mn = fmaxf(mloc, m1);
        zloc = zloc * __expf(mloc - mn) + z1 * __expf(m1 - mn);
        mloc = mn;
    }
    float mo = fmaxf(mloc, __shfl_xor(mloc, 32, 64));
    float zs = zloc * __expf(mloc - mo);
    float Zk = zs + __shfl_xor(zs, 32, 64);
    if (!hi && l31 < KNBR) mzb[wv][l31] = make_float2(mo, 1.0f / Zk);

    // ---- original orientation + pooling, half at a time ----
    float pooled0 = 0.f, pooled1 = 0.f;
    {
        f32x16 acc;
#pragma unroll
        for (int i = 0; i < 16; ++i) acc[i] = 0.f;
#pragma unroll
        for (int kt = 0; kt < 4; ++kt)
            acc = __builtin_amdgcn_mfma_f32_32x32x16_bf16(Af[kt], wattF[kt * 64 + lane], acc, 0, 0, 0);
#pragma unroll
        for (int r = 0; r < 12; ++r) {
            int j = (r & 3) + 8 * (r >> 2) + 4 * hi;
            float2 mz = mzb[wv][j];                   // 2-address broadcast read
            float a0 = __expf(acc[r] - mz.x) * mz.y;
            float f0 = bf2f(Fb[wv][j * 64 + (l31 ^ ((j & 7) << 3))]);
            float p0 = a0 * f0;
            if (r >= 8) p0 = hi ? 0.f : p0;           // j>=20 rows invalid
            pooled0 += p0;
        }
    }
    {
        f32x16 acc;
#pragma unroll
        for (int i = 0; i < 16; ++i) acc[i] = 0.f;
#pragma unroll
        for (int kt = 0; kt < 4; ++kt)
            acc = __builtin_amdgcn_mfma_f32_32x32x16_bf16(Af[kt], wattF[(4 + kt) * 64 + lane], acc, 0, 0, 0);
#pragma unroll
        for (int r = 0; r < 12; ++r) {
            int j = (r & 3) + 8 * (r >> 2) + 4 * hi;
            float2 mz = mzb[wv][j];
            float a1 = __expf(acc[r] - mz.x) * mz.y;
            float f1 = bf2f(Fb[wv][j * 64 + ((32 + l31) ^ ((j & 7) << 3))]);
            float p1 = a1 * f1;
            if (r >= 8) p1 = hi ? 0.f : p1;
            pooled1 += p1;
        }
    }
    pooled0 += __shfl_xor(pooled0, 32, 64);
    pooled1 += __shfl_xor(pooled1, 32, 64);
    if (!hi) {
        pool[wv][l31]      = f2bf(pooled0);
        pool[wv][32 + l31] = f2bf(pooled1);
    }

    // ---- epilogue: out = W_conv@pooled + W_out@feat (biases cancel in BN) ----
    f32x16 oa;
#pragma unroll
    for (int i = 0; i < 16; ++i) oa[i] = 0.f;
#pragma unroll
    for (int kt = 0; kt < 4; ++kt) {
        short8 bb = *(const short8*)&pool[wv][kt * 16 + 8 * hi];
        oa = __builtin_amdgcn_mfma_f32_32x32x16_bf16(wconvF[kt * 64 + lane], bb, oa, 0, 0, 0);
    }
#pragma unroll
    for (int kt = 0; kt < 2; ++kt) {
        short8 bb = *(const short8*)(fb + (size_t)nb * INC + kt * 16 + 8 * hi);
        oa = __builtin_amdgcn_mfma_f32_32x32x16_bf16(woutF[kt * 64 + lane], bb, oa, 0, 0, 0);
    }
#pragma unroll
    for (int r = 0; r < 16; ++r) {
        int o = (r & 3) + 8 * (r >> 2) + 4 * hi;
        if (l31 == 0) out[((size_t)(b * OUTC + o)) * NPTS + nb] = oa[r];
    }
}

// ---------------- kernel 3a: per-channel batch stats ----------------
__global__ __launch_bounds__(256) void k_stats(const float* __restrict__ of,
                                               float* __restrict__ stats) {
    int c = blockIdx.x;
    int tid = threadIdx.x;
    float s = 0.f, s2 = 0.f;
    for (int i = tid; i < BATCH * NPTS; i += 256) {
        int b = i >> 12, n = i & (NPTS - 1);
        float v = of[((size_t)b * OUTC + c) * NPTS + n];
        s += v; s2 = fmaf(v, v, s2);
    }
#pragma unroll
    for (int off = 32; off >= 1; off >>= 1) {
        s += __shfl_xor(s, off, 64);
        s2 += __shfl_xor(s2, off, 64);
    }
    __shared__ float rs[4], rs2[4];
    if ((tid & 63) == 0) { rs[tid >> 6] = s; rs2[tid >> 6] = s2; }
    __syncthreads();
    if (tid == 0) {
        float S = (rs[0] + rs[1]) + (rs[2] + rs[3]);
        float S2 = (rs2[0] + rs2[1]) + (rs2[2] + rs2[3]);
        const float invn = 1.0f / (BATCH * NPTS);
        float mean = S * invn;
        float var = S2 * invn - mean * mean;
        stats[c] = mean;
        stats[32 + c] = rsqrtf(var + EPSBN);
    }
}

// ---------------- kernel 3b: normalize in place ----------------
__global__ __launch_bounds__(256) void k_norm(float* __restrict__ of,
                                              const float* __restrict__ stats,
                                              const float* __restrict__ gamma,
                                              const float* __restrict__ beta) {
    int i = blockIdx.x * 256 + threadIdx.x;
    if (i >= BATCH * OUTC * NPTS) return;
    int c = (i >> 12) & (OUTC - 1);
    float v = of[i];
    of[i] = (v - stats[c]) * stats[32 + c] * gamma[c] + beta[c];
}

// ---------------- launch ----------------
extern "C" void kernel_launch(void* const* d_in, const int* in_sizes, int n_in,
                              void* d_out, int out_size, void* d_ws, size_t ws_size,
                              hipStream_t stream) {
    const float* x      = (const float*)d_in[0];
    const float* feat   = (const float*)d_in[1];
    const float* w_mlp  = (const float*)d_in[2];
    const float* b_mlp  = (const float*)d_in[3];
    const float* w_att  = (const float*)d_in[4];
    const float* w_conv = (const float*)d_in[5];
    const float* w_out  = (const float*)d_in[7];
    const float* gamma  = (const float*)d_in[9];
    const float* beta   = (const float*)d_in[10];
    float* out = (float*)d_out;

    char* ws = (char*)d_ws;
    float4* xT4    = (float4*)ws;                          // 262144 B
    ushort* fbT    = (ushort*)(ws + 262144);               // 1048576 B
    int*    neigh  = (int*)(ws + 1310720);                 // 1310720 B
    float*  stats  = (float*)(ws + 2621440);               // 256 B
    short8* wattF  = (short8*)(ws + 2621696);              // 8192 B
    short8* wconvF = (short8*)(ws + 2629888);              // 4096 B
    short8* woutF  = (short8*)(ws + 2633984);              // 2048 B
    float*  wmlp8  = (float*)(ws + 2636032);               // 2048 B

    k_prep<<<(BATCH * INC * NPTS + 255) / 256 + 1, 256, 0, stream>>>(
        x, feat, xT4, fbT, w_att, w_conv, w_out, w_mlp, b_mlp,
        wattF, wconvF, woutF, wmlp8);
    k_knn3<<<(BATCH * NPTS) / PPBK, 512, 0, stream>>>(xT4, neigh);
    k_attn3<<<(BATCH * NPTS) / 4, 256, 0, stream>>>(xT4, fbT, neigh, wmlp8,
                                                    wattF, wconvF, woutF, out);
    k_stats<<<OUTC, 256, 0, stream>>>(out, stats);
    k_norm<<<(BATCH * OUTC * NPTS + 255) / 256, 256, 0, stream>>>(out, stats, gamma, beta);
}

// Round 7
// 132.928 us; speedup vs baseline: 4.6847x; 1.0643x over previous
//
#include <hip/hip_runtime.h>
#include <hip/hip_bf16.h>

#define BATCH 4
#define NPTS  4096
#define KNBR  20
#define INC   32
#define TWC   64   // 2*INC
#define OUTC  32
#define EPSBN 1e-5f

typedef short short8 __attribute__((ext_vector_type(8)));
typedef float f32x16 __attribute__((ext_vector_type(16)));

// ---------------- helpers ----------------
__device__ __forceinline__ float rlf(float v, int l) {
    return __uint_as_float((unsigned)__builtin_amdgcn_readlane((int)__float_as_uint(v), l));
}
__device__ __forceinline__ ushort f2bf(float x) {        // fp32 -> bf16 bits (RNE)
    unsigned u = __float_as_uint(x);
    unsigned r = u + 0x7FFFu + ((u >> 16) & 1u);
    return (ushort)(r >> 16);
}
__device__ __forceinline__ float bf2f(ushort h) {
    return __uint_as_float(((unsigned)h) << 16);
}
__device__ __forceinline__ void gll16(const float4* g, float4* l) {
    __builtin_amdgcn_global_load_lds((const __attribute__((address_space(1))) void*)g,
                                     (__attribute__((address_space(3))) void*)l, 16, 0, 0);
}

// ---------------- kernel 0: fused transposes + weight prepack ----------------
__global__ __launch_bounds__(256) void k_prep(const float* __restrict__ x,
                                              const float* __restrict__ f,
                                              float4* __restrict__ xT4,
                                              ushort* __restrict__ fT,
                                              const float* __restrict__ w_att,
                                              const float* __restrict__ w_conv,
                                              const float* __restrict__ w_out,
                                              const float* __restrict__ w_mlp,
                                              const float* __restrict__ b_mlp,
                                              short8* __restrict__ wattF,
                                              short8* __restrict__ wconvF,
                                              short8* __restrict__ woutF,
                                              float* __restrict__ wmlp8) {
    int i = blockIdx.x * 256 + threadIdx.x;
    if (i < BATCH * NPTS) {
        int b = i / NPTS, n = i % NPTS;
        const float* xb = x + (size_t)b * 3 * NPTS;
        float x0 = xb[n], x1 = xb[NPTS + n], x2 = xb[2 * NPTS + n];
        float sq = fmaf(x2, x2, fmaf(x1, x1, x0 * x0));
        xT4[i] = make_float4(x0, x1, x2, sq);
    }
    if (i < BATCH * INC * NPTS) {
        int n = i % NPTS; int t = i / NPTS; int c = t % INC; int b = t / INC;
        fT[((size_t)(b * NPTS + n)) * INC + c] = f2bf(f[i]);
    }
    if (blockIdx.x == gridDim.x - 1) {
        int t = threadIdx.x;
        for (int idx = t; idx < 14 * 64; idx += 256) {
            int fr = idx >> 6, ln = idx & 63, l31 = ln & 31, h8 = (ln >> 5) * 8;
            short8 v;
            if (fr < 8) {
                int nt = fr >> 2, kt = fr & 3;
                const float* s = w_att + (nt * 32 + l31) * 64 + kt * 16 + h8;
#pragma unroll
                for (int j = 0; j < 8; ++j) v[j] = (short)f2bf(s[j]);
                wattF[fr * 64 + ln] = v;
            } else if (fr < 12) {
                int kt = fr - 8;
                const float* s = w_conv + l31 * 64 + kt * 16 + h8;
#pragma unroll
                for (int j = 0; j < 8; ++j) v[j] = (short)f2bf(s[j]);
                wconvF[kt * 64 + ln] = v;
            } else {
                int kt = fr - 12;
                const float* s = w_out + l31 * 32 + kt * 16 + h8;
#pragma unroll
                for (int j = 0; j < 8; ++j) v[j] = (short)f2bf(s[j]);
                woutF[kt * 64 + ln] = v;
            }
        }
        for (int idx = t; idx < 512; idx += 256) {
            int e = idx >> 3, j = idx & 7;
            wmlp8[idx] = (j < 7) ? w_mlp[e * 7 + j] : b_mlp[e];
        }
    }
}

// ---------------- kernel 1: FUSED knn + attention ----------------
// 512 threads = 8 waves = 8 points. Phase A: filter+exact-set KNN (R5
// algorithm) with results kept in LDS. Phase B (after one barrier): dual-
// orientation MFMA attention per wave (R6 algorithm). Fb (32 KB) exactly
// aliases cand(16K)+surv(16K) -- lifetimes disjoint across the barrier.
#define CAP   256
#define PPBK  8
__global__ __launch_bounds__(512, 8) void k_fused(const float4* __restrict__ xT4,
                                                  const ushort* __restrict__ fbT,
                                                  const float* __restrict__ wmlp8,
                                                  const short8* __restrict__ wattF,
                                                  const short8* __restrict__ wconvF,
                                                  const short8* __restrict__ woutF,
                                                  float* __restrict__ out) {
    __shared__ __align__(16) char smA[32768];       // cand[2][512]f4 + surv[8][256]u64 / Fb[8][2048]u16
    float4*             candB = (float4*)smA;
    unsigned long long* survB = (unsigned long long*)(smA + 16384);
    ushort*             FbB   = (ushort*)smA;
    __shared__ int scnt[PPBK], slot[PPBK];
    __shared__ int neighL[PPBK][KNBR];              // 640 B
    __shared__ __align__(16) float4 f4buf[PPBK][KNBR];  // 2560 B
    __shared__ float2 mzb[PPBK][32];                // 2048 B (rows>=20 garbage-read, select-zeroed)
    __shared__ __align__(16) ushort pool[PPBK][64]; // 1024 B

    const int tid  = threadIdx.x;
    const int lane = tid & 63;
    const int wv   = tid >> 6;
    const int hi   = lane >> 5;
    const int l31  = lane & 31;
    const int gp   = blockIdx.x * PPBK + wv;
    const int b    = gp >> 12;
    const int nb   = gp & (NPTS - 1);
    const float4* base = xT4 + (size_t)b * NPTS;

    if (lane == 0) { scnt[wv] = 0; slot[wv] = 1; }

    float4 me = xT4[gp];

    auto stage = [&](int c) {
        const float4* src = base + c * 512 + wv * 64 + lane;
        float4* dst = candB + (c & 1) * 512 + wv * 64;   // wave-uniform base; HW adds lane*16
        gll16(src, dst);
    };

    stage(0); stage(1);
    __syncthreads();

    // ---- phase A1: subset distances (candidates 0..1023) in regs ----
    unsigned bits[16];
#pragma unroll
    for (int j = 0; j < 8; ++j) {
        float4 o = candB[lane + 64 * j];
        float dot = fmaf(o.z, me.z, fmaf(o.y, me.y, o.x * me.x));
        bits[j] = __float_as_uint(fmaxf((me.w + o.w) - 2.0f * dot, 0.0f));
    }
#pragma unroll
    for (int j = 0; j < 8; ++j) {
        float4 o = candB[512 + lane + 64 * j];
        float dot = fmaf(o.z, me.z, fmaf(o.y, me.y, o.x * me.x));
        bits[8 + j] = __float_as_uint(fmaxf((me.w + o.w) - 2.0f * dot, 0.0f));
    }
    __syncthreads();
    stage(2);

    unsigned lo = 0u, hi2 = 0xFF000000u;
    for (int it = 0; it < 16; ++it) {
        unsigned mid = lo + ((hi2 - lo) >> 1);
        int c = 0;
#pragma unroll
        for (int j = 0; j < 16; ++j) c += __popcll(__ballot(bits[j] <= mid));
        if (c >= KNBR) hi2 = mid; else lo = mid + 1;
    }
    const unsigned tau = hi2;

    // ---- phase A2: append survivors ----
#pragma unroll
    for (int j = 0; j < 16; ++j) {
        if (bits[j] <= tau) {
            int pos = atomicAdd(&scnt[wv], 1);
            if (pos < CAP)
                survB[wv * CAP + pos] = ((unsigned long long)bits[j] << 32) | (unsigned)(lane + 64 * j);
        }
    }
    __syncthreads();

    for (int ch = 2; ch < 8; ++ch) {
        if (ch < 7) stage(ch + 1);
        const float4* cb = candB + (ch & 1) * 512;
        const int ib = ch * 512 + lane;
#pragma unroll
        for (int j = 0; j < 8; ++j) {
            float4 o = cb[lane + 64 * j];
            float dot = fmaf(o.z, me.z, fmaf(o.y, me.y, o.x * me.x));
            unsigned bb = __float_as_uint(fmaxf((me.w + o.w) - 2.0f * dot, 0.0f));
            if (bb <= tau) {
                int pos = atomicAdd(&scnt[wv], 1);
                if (pos < CAP)
                    survB[wv * CAP + pos] = ((unsigned long long)bb << 32) | (unsigned)(ib + 64 * j);
            }
        }
        __syncthreads();
    }

    // ---- phase A3: exact top-20 set ----
    int cnt = scnt[wv]; if (cnt > CAP) cnt = CAP;
    unsigned long long k0 = (lane       < cnt) ? survB[wv * CAP + lane      ] : ~0ull;
    unsigned long long k1 = (lane +  64 < cnt) ? survB[wv * CAP + lane +  64] : ~0ull;
    unsigned long long k2 = (lane + 128 < cnt) ? survB[wv * CAP + lane + 128] : ~0ull;
    unsigned long long k3 = (lane + 192 < cnt) ? survB[wv * CAP + lane + 192] : ~0ull;
    unsigned d0 = (unsigned)(k0 >> 32), d1 = (unsigned)(k1 >> 32);
    unsigned d2 = (unsigned)(k2 >> 32), d3 = (unsigned)(k3 >> 32);
    unsigned i0 = (unsigned)k0, i1 = (unsigned)k1, i2 = (unsigned)k2, i3 = (unsigned)k3;

    unsigned l2 = 0u, h2 = tau;
    for (int it = 0; it < 32; ++it) {
        unsigned mid = l2 + ((h2 - l2) >> 1);
        int c = __popcll(__ballot(d0 <= mid)) + __popcll(__ballot(d1 <= mid))
              + __popcll(__ballot(d2 <= mid)) + __popcll(__ballot(d3 <= mid));
        if (c >= KNBR) h2 = mid; else l2 = mid + 1;
    }
    const unsigned th = h2;
    int cless = __popcll(__ballot(d0 < th)) + __popcll(__ballot(d1 < th))
              + __popcll(__ballot(d2 < th)) + __popcll(__ballot(d3 < th));
    int need = KNBR - cless;
    bool t0 = (d0 == th), t1 = (d1 == th), t2 = (d2 == th), t3 = (d3 == th);
    int tcnt = __popcll(__ballot(t0)) + __popcll(__ballot(t1))
             + __popcll(__ballot(t2)) + __popcll(__ballot(t3));
    unsigned idxthr = 0xFFFFFFFFu;
    if (tcnt != need) {       // rare exact-d2-tie path (uniform branch)
        unsigned la = 0u, ha = 0xFFFFFFFFu;
        for (int it = 0; it < 32; ++it) {
            unsigned mid = la + ((ha - la) >> 1);
            int c = __popcll(__ballot(t0 && i0 <= mid)) + __popcll(__ballot(t1 && i1 <= mid))
                  + __popcll(__ballot(t2 && i2 <= mid)) + __popcll(__ballot(t3 && i3 <= mid));
            if (c >= need) ha = mid; else la = mid + 1;
        }
        idxthr = ha;
    }
    bool s0 = (d0 < th) || (t0 && i0 <= idxthr);
    bool s1 = (d1 < th) || (t1 && i1 <= idxthr);
    bool s2 = (d2 < th) || (t2 && i2 <= idxthr);
    bool s3 = (d3 < th) || (t3 && i3 <= idxthr);

    unsigned long long m01 = k0 < k1 ? k0 : k1;
    unsigned long long m23 = k2 < k3 ? k2 : k3;
    unsigned long long mk  = m01 < m23 ? m01 : m23;
#pragma unroll
    for (int off = 32; off >= 1; off >>= 1) {
        unsigned long long o = __shfl_xor(mk, off, 64);
        mk = o < mk ? o : mk;
    }
    if (s0) { if (k0 == mk) neighL[wv][0] = (int)i0; else { int p = atomicAdd(&slot[wv], 1); neighL[wv][p] = (int)i0; } }
    if (s1) { if (k1 == mk) neighL[wv][0] = (int)i1; else { int p = atomicAdd(&slot[wv], 1); neighL[wv][p] = (int)i1; } }
    if (s2) { if (k2 == mk) neighL[wv][0] = (int)i2; else { int p = atomicAdd(&slot[wv], 1); neighL[wv][p] = (int)i2; } }
    if (s3) { if (k3 == mk) neighL[wv][0] = (int)i3; else { int p = atomicAdd(&slot[wv], 1); neighL[wv][p] = (int)i3; } }

    __syncthreads();   // last surv/cand use above; Fb (aliased) written below

    // ================= phase B: attention =================
    const ushort* fb = fbT + (size_t)b * NPTS * INC;
    ushort* Fw = FbB + wv * 2048;

    int nv = 0;
    if (l31 < KNBR) nv = neighL[wv][l31];
    float4 ncl = base[nv];
    if (!hi && l31 < KNBR) f4buf[wv][l31] = ncl;

    float wm[8];
    {
        const float4* w8 = (const float4*)(wmlp8 + l31 * 8);
        float4 a = w8[0], bq = w8[1];
        wm[0] = a.x; wm[1] = a.y; wm[2] = a.z; wm[3] = a.w;
        wm[4] = bq.x; wm[5] = bq.y; wm[6] = bq.z; wm[7] = bq.w;
    }
    const float c0x = rlf(ncl.x, 0), c0y = rlf(ncl.y, 0), c0z = rlf(ncl.z, 0);

#pragma unroll
    for (int k = 0; k < KNBR; ++k) {
        int snk = __builtin_amdgcn_readlane(nv, k);
        ushort fraw = fb[(size_t)snk * INC + l31];
        float4 nk4 = f4buf[wv][k];
        float rx = nk4.x - c0x, ry = nk4.y - c0y, rz = nk4.z - c0z;
        float dis = sqrtf(fmaf(rz, rz, fmaf(ry, ry, rx * rx)));
        float fm = wm[7];
        fm = fmaf(wm[0], c0x, fm); fm = fmaf(wm[1], c0y, fm); fm = fmaf(wm[2], c0z, fm);
        fm = fmaf(wm[3], rx, fm);  fm = fmaf(wm[4], ry, fm);  fm = fmaf(wm[5], rz, fm);
        fm = fmaf(wm[6], dis, fm);
        ushort fbits = hi ? f2bf(fm) : fraw;
        Fw[k * 64 + (lane ^ ((k & 7) << 3))] = fbits;
    }

    short8 Af[4];
#pragma unroll
    for (int kt = 0; kt < 4; ++kt) {
        int c0 = kt * 16 + 8 * hi;
        Af[kt] = *(const short8*)&Fw[l31 * 64 + (c0 ^ ((l31 & 7) << 3))];
    }

    // flipped orientation: lane k holds d-column -> lane-local softmax stats
    float mloc, zloc;
    {
        f32x16 af;
#pragma unroll
        for (int i = 0; i < 16; ++i) af[i] = 0.f;
#pragma unroll
        for (int kt = 0; kt < 4; ++kt)
            af = __builtin_amdgcn_mfma_f32_32x32x16_bf16(wattF[kt * 64 + lane], Af[kt], af, 0, 0, 0);
        float m0 = af[0];
#pragma unroll
        for (int i = 1; i < 16; ++i) m0 = fmaxf(m0, af[i]);
        float z0 = 0.f;
#pragma unroll
        for (int i = 0; i < 16; ++i) z0 += __expf(af[i] - m0);
        mloc = m0; zloc = z0;
    }
    {
        f32x16 af;
#pragma unroll
        for (int i = 0; i < 16; ++i) af[i] = 0.f;
#pragma unroll
        for (int kt = 0; kt < 4; ++kt)
            af = __builtin_amdgcn_mfma_f32_32x32x16_bf16(wattF[(4 + kt) * 64 + lane], Af[kt], af, 0, 0, 0);
        float m1 = af[0];
#pragma unroll
        for (int i = 1; i < 16; ++i) m1 = fmaxf(m1, af[i]);
        float z1 = 0.f;
#pragma unroll
        for (int i = 0; i < 16; ++i) z1 += __expf(af[i] - m1);
        float mn = fmaxf(mloc, m1);
        zloc = zloc * __expf(mloc - mn) + z1 * __expf(m1 - mn);
        mloc = mn;
    }
    float mo = fmaxf(mloc, __shfl_xor(mloc, 32, 64));
    float zs = zloc * __expf(mloc - mo);
    float Zk = zs + __shfl_xor(zs, 32, 64);
    if (!hi && l31 < KNBR) mzb[wv][l31] = make_float2(mo, 1.0f / Zk);

    // original orientation + pooling, half at a time
    float pooled0 = 0.f, pooled1 = 0.f;
    {
        f32x16 acc;
#pragma unroll
        for (int i = 0; i < 16; ++i) acc[i] = 0.f;
#pragma unroll
        for (int kt = 0; kt < 4; ++kt)
            acc = __builtin_amdgcn_mfma_f32_32x32x16_bf16(Af[kt], wattF[kt * 64 + lane], acc, 0, 0, 0);
#pragma unroll
        for (int r = 0; r < 12; ++r) {
            int j = (r & 3) + 8 * (r >> 2) + 4 * hi;
            float2 mz = mzb[wv][j];
            float a0 = __expf(acc[r] - mz.x) * mz.y;
            float f0 = bf2f(Fw[j * 64 + (l31 ^ ((j & 7) << 3))]);
            float p0 = a0 * f0;
            if (r >= 8) p0 = hi ? 0.f : p0;
            pooled0 += p0;
        }
    }
    {
        f32x16 acc;
#pragma unroll
        for (int i = 0; i < 16; ++i) acc[i] = 0.f;
#pragma unroll
        for (int kt = 0; kt < 4; ++kt)
            acc = __builtin_amdgcn_mfma_f32_32x32x16_bf16(Af[kt], wattF[(4 + kt) * 64 + lane], acc, 0, 0, 0);
#pragma unroll
        for (int r = 0; r < 12; ++r) {
            int j = (r & 3) + 8 * (r >> 2) + 4 * hi;
            float2 mz = mzb[wv][j];
            float a1 = __expf(acc[r] - mz.x) * mz.y;
            float f1 = bf2f(Fw[j * 64 + ((32 + l31) ^ ((j & 7) << 3))]);
            float p1 = a1 * f1;
            if (r >= 8) p1 = hi ? 0.f : p1;
            pooled1 += p1;
        }
    }
    pooled0 += __shfl_xor(pooled0, 32, 64);
    pooled1 += __shfl_xor(pooled1, 32, 64);
    if (!hi) {
        pool[wv][l31]      = f2bf(pooled0);
        pool[wv][32 + l31] = f2bf(pooled1);
    }

    // epilogue: out = W_conv@pooled + W_out@feat (biases cancel in BN)
    f32x16 oa;
#pragma unroll
    for (int i = 0; i < 16; ++i) oa[i] = 0.f;
#pragma unroll
    for (int kt = 0; kt < 4; ++kt) {
        short8 bb = *(const short8*)&pool[wv][kt * 16 + 8 * hi];
        oa = __builtin_amdgcn_mfma_f32_32x32x16_bf16(wconvF[kt * 64 + lane], bb, oa, 0, 0, 0);
    }
#pragma unroll
    for (int kt = 0; kt < 2; ++kt) {
        short8 bb = *(const short8*)(fb + (size_t)nb * INC + kt * 16 + 8 * hi);
        oa = __builtin_amdgcn_mfma_f32_32x32x16_bf16(woutF[kt * 64 + lane], bb, oa, 0, 0, 0);
    }
#pragma unroll
    for (int r = 0; r < 16; ++r) {
        int o = (r & 3) + 8 * (r >> 2) + 4 * hi;
        if (l31 == 0) out[((size_t)(b * OUTC + o)) * NPTS + nb] = oa[r];
    }
}

// ---------------- kernel 3a: per-channel batch stats ----------------
__global__ __launch_bounds__(256) void k_stats(const float* __restrict__ of,
                                               float* __restrict__ stats) {
    int c = blockIdx.x;
    int tid = threadIdx.x;
    float s = 0.f, s2 = 0.f;
    for (int i = tid; i < BATCH * NPTS; i += 256) {
        int b = i >> 12, n = i & (NPTS - 1);
        float v = of[((size_t)b * OUTC + c) * NPTS + n];
        s += v; s2 = fmaf(v, v, s2);
    }
#pragma unroll
    for (int off = 32; off >= 1; off >>= 1) {
        s += __shfl_xor(s, off, 64);
        s2 += __shfl_xor(s2, off, 64);
    }
    __shared__ float rs[4], rs2[4];
    if ((tid & 63) == 0) { rs[tid >> 6] = s; rs2[tid >> 6] = s2; }
    __syncthreads();
    if (tid == 0) {
        float S = (rs[0] + rs[1]) + (rs[2] + rs[3]);
        float S2 = (rs2[0] + rs2[1]) + (rs2[2] + rs2[3]);
        const float invn = 1.0f / (BATCH * NPTS);
        float mean = S * invn;
        float var = S2 * invn - mean * mean;
        stats[c] = mean;
        stats[32 + c] = rsqrtf(var + EPSBN);
    }
}

// ---------------- kernel 3b: normalize in place ----------------
__global__ __launch_bounds__(256) void k_norm(float* __restrict__ of,
                                              const float* __restrict__ stats,
                                              const float* __restrict__ gamma,
                                              const float* __restrict__ beta) {
    int i = blockIdx.x * 256 + threadIdx.x;
    if (i >= BATCH * OUTC * NPTS) return;
    int c = (i >> 12) & (OUTC - 1);
    float v = of[i];
    of[i] = (v - stats[c]) * stats[32 + c] * gamma[c] + beta[c];
}

// ---------------- launch ----------------
extern "C" void kernel_launch(void* const* d_in, const int* in_sizes, int n_in,
                              void* d_out, int out_size, void* d_ws, size_t ws_size,
                              hipStream_t stream) {
    const float* x      = (const float*)d_in[0];
    const float* feat   = (const float*)d_in[1];
    const float* w_mlp  = (const float*)d_in[2];
    const float* b_mlp  = (const float*)d_in[3];
    const float* w_att  = (const float*)d_in[4];
    const float* w_conv = (const float*)d_in[5];
    const float* w_out  = (const float*)d_in[7];
    const float* gamma  = (const float*)d_in[9];
    const float* beta   = (const float*)d_in[10];
    float* out = (float*)d_out;

    char* ws = (char*)d_ws;
    float4* xT4    = (float4*)ws;                          // 262144 B
    ushort* fbT    = (ushort*)(ws + 262144);               // 1048576 B
    float*  stats  = (float*)(ws + 1310720);               // 256 B
    short8* wattF  = (short8*)(ws + 1310976);              // 8192 B
    short8* wconvF = (short8*)(ws + 1319168);              // 4096 B
    short8* woutF  = (short8*)(ws + 1323264);              // 2048 B
    float*  wmlp8  = (float*)(ws + 1325312);               // 2048 B

    k_prep<<<(BATCH * INC * NPTS + 255) / 256 + 1, 256, 0, stream>>>(
        x, feat, xT4, fbT, w_att, w_conv, w_out, w_mlp, b_mlp,
        wattF, wconvF, woutF, wmlp8);
    k_fused<<<(BATCH * NPTS) / PPBK, 512, 0, stream>>>(xT4, fbT, wmlp8,
                                                       wattF, wconvF, woutF, out);
    k_stats<<<OUTC, 256, 0, stream>>>(out, stats);
    k_norm<<<(BATCH * OUTC * NPTS + 255) / 256, 256, 0, stream>>>(out, stats, gamma, beta);
}

// Round 8
// 120.971 us; speedup vs baseline: 5.1478x; 1.0988x over previous
//
#include <hip/hip_runtime.h>
#include <hip/hip_bf16.h>

#define BATCH 4
#define NPTS  4096
#define KNBR  20
#define INC   32
#define TWC   64   // 2*INC
#define OUTC  32
#define EPSBN 1e-5f

typedef short short8 __attribute__((ext_vector_type(8)));
typedef float f32x16 __attribute__((ext_vector_type(16)));

// ---------------- helpers ----------------
__device__ __forceinline__ float rlf(float v, int l) {
    return __uint_as_float((unsigned)__builtin_amdgcn_readlane((int)__float_as_uint(v), l));
}
__device__ __forceinline__ ushort f2bf(float x) {        // fp32 -> bf16 bits (RNE)
    unsigned u = __float_as_uint(x);
    unsigned r = u + 0x7FFFu + ((u >> 16) & 1u);
    return (ushort)(r >> 16);
}
__device__ __forceinline__ float bf2f(ushort h) {
    return __uint_as_float(((unsigned)h) << 16);
}
__device__ __forceinline__ void gll16(const float4* g, float4* l) {
    __builtin_amdgcn_global_load_lds((const __attribute__((address_space(1))) void*)g,
                                     (__attribute__((address_space(3))) void*)l, 16, 0, 0);
}

// ---------------- kernel 0: fused transposes + weight prepack ----------------
__global__ __launch_bounds__(256) void k_prep(const float* __restrict__ x,
                                              const float* __restrict__ f,
                                              float4* __restrict__ xT4,
                                              ushort* __restrict__ fT,
                                              const float* __restrict__ w_att,
                                              const float* __restrict__ w_conv,
                                              const float* __restrict__ w_out,
                                              const float* __restrict__ w_mlp,
                                              const float* __restrict__ b_mlp,
                                              short8* __restrict__ wattF,
                                              short8* __restrict__ wconvF,
                                              short8* __restrict__ woutF,
                                              float* __restrict__ wmlp8) {
    int i = blockIdx.x * 256 + threadIdx.x;
    if (i < BATCH * NPTS) {
        int b = i / NPTS, n = i % NPTS;
        const float* xb = x + (size_t)b * 3 * NPTS;
        float x0 = xb[n], x1 = xb[NPTS + n], x2 = xb[2 * NPTS + n];
        float sq = fmaf(x2, x2, fmaf(x1, x1, x0 * x0));
        xT4[i] = make_float4(x0, x1, x2, sq);
    }
    if (i < BATCH * INC * NPTS) {
        int n = i % NPTS; int t = i / NPTS; int c = t % INC; int b = t / INC;
        fT[((size_t)(b * NPTS + n)) * INC + c] = f2bf(f[i]);
    }
    if (blockIdx.x == gridDim.x - 1) {
        int t = threadIdx.x;
        for (int idx = t; idx < 14 * 64; idx += 256) {
            int fr = idx >> 6, ln = idx & 63, l31 = ln & 31, h8 = (ln >> 5) * 8;
            short8 v;
            if (fr < 8) {
                int nt = fr >> 2, kt = fr & 3;
                const float* s = w_att + (nt * 32 + l31) * 64 + kt * 16 + h8;
#pragma unroll
                for (int j = 0; j < 8; ++j) v[j] = (short)f2bf(s[j]);
                wattF[fr * 64 + ln] = v;
            } else if (fr < 12) {
                int kt = fr - 8;
                const float* s = w_conv + l31 * 64 + kt * 16 + h8;
#pragma unroll
                for (int j = 0; j < 8; ++j) v[j] = (short)f2bf(s[j]);
                wconvF[kt * 64 + ln] = v;
            } else {
                int kt = fr - 12;
                const float* s = w_out + l31 * 32 + kt * 16 + h8;
#pragma unroll
                for (int j = 0; j < 8; ++j) v[j] = (short)f2bf(s[j]);
                woutF[kt * 64 + ln] = v;
            }
        }
        for (int idx = t; idx < 512; idx += 256) {
            int e = idx >> 3, j = idx & 7;
            wmlp8[idx] = (j < 7) ? w_mlp[e * 7 + j] : b_mlp[e];
        }
    }
}

// ---------------- kernel 1: FUSED knn + attention ----------------
// 512 threads = 8 waves = 8 points. Phase A: filter+exact-set KNN with
// results in LDS. Phase B (after one barrier): dual-orientation MFMA
// attention per wave. Fb (32 KB) aliases cand(16K)+surv(16K).
// launch_bounds(512,6): 85-reg unified budget -- phase B needs ~85; the
// R7 (512,8)=64-reg bound forced ~180 MB/dispatch of scratch spills.
#define CAP   256
#define PPBK  8
__global__ __launch_bounds__(512, 6) void k_fused(const float4* __restrict__ xT4,
                                                  const ushort* __restrict__ fbT,
                                                  const float* __restrict__ wmlp8,
                                                  const short8* __restrict__ wattF,
                                                  const short8* __restrict__ wconvF,
                                                  const short8* __restrict__ woutF,
                                                  float* __restrict__ out) {
    __shared__ __align__(16) char smA[32768];       // cand[2][512]f4 + surv[8][256]u64 / Fb[8][2048]u16
    float4*             candB = (float4*)smA;
    unsigned long long* survB = (unsigned long long*)(smA + 16384);
    ushort*             FbB   = (ushort*)smA;
    __shared__ int scnt[PPBK], slot[PPBK];
    __shared__ int neighL[PPBK][KNBR];              // 640 B
    __shared__ __align__(16) float4 f4buf[PPBK][KNBR];  // 2560 B
    __shared__ float2 mzb[PPBK][32];                // 2048 B (rows>=20 garbage-read, select-zeroed)
    __shared__ __align__(16) ushort pool[PPBK][64]; // 1024 B

    const int tid  = threadIdx.x;
    const int lane = tid & 63;
    const int wv   = tid >> 6;
    const int hi   = lane >> 5;
    const int l31  = lane & 31;
    const int gp   = blockIdx.x * PPBK + wv;
    const int b    = gp >> 12;
    const int nb   = gp & (NPTS - 1);
    const float4* base = xT4 + (size_t)b * NPTS;

    if (lane == 0) { scnt[wv] = 0; slot[wv] = 1; }

    float4 me = xT4[gp];

    auto stage = [&](int c) {
        const float4* src = base + c * 512 + wv * 64 + lane;
        float4* dst = candB + (c & 1) * 512 + wv * 64;   // wave-uniform base; HW adds lane*16
        gll16(src, dst);
    };

    stage(0); stage(1);
    __syncthreads();

    // ---- phase A1: subset distances (candidates 0..1023) in regs ----
    unsigned bits[16];
#pragma unroll
    for (int j = 0; j < 8; ++j) {
        float4 o = candB[lane + 64 * j];
        float dot = fmaf(o.z, me.z, fmaf(o.y, me.y, o.x * me.x));
        bits[j] = __float_as_uint(fmaxf((me.w + o.w) - 2.0f * dot, 0.0f));
    }
#pragma unroll
    for (int j = 0; j < 8; ++j) {
        float4 o = candB[512 + lane + 64 * j];
        float dot = fmaf(o.z, me.z, fmaf(o.y, me.y, o.x * me.x));
        bits[8 + j] = __float_as_uint(fmaxf((me.w + o.w) - 2.0f * dot, 0.0f));
    }
    __syncthreads();
    stage(2);

    unsigned lo = 0u, hi2 = 0xFF000000u;
    for (int it = 0; it < 16; ++it) {
        unsigned mid = lo + ((hi2 - lo) >> 1);
        int c = 0;
#pragma unroll
        for (int j = 0; j < 16; ++j) c += __popcll(__ballot(bits[j] <= mid));
        if (c >= KNBR) hi2 = mid; else lo = mid + 1;
    }
    const unsigned tau = hi2;

    // ---- phase A2: append survivors ----
#pragma unroll
    for (int j = 0; j < 16; ++j) {
        if (bits[j] <= tau) {
            int pos = atomicAdd(&scnt[wv], 1);
            if (pos < CAP)
                survB[wv * CAP + pos] = ((unsigned long long)bits[j] << 32) | (unsigned)(lane + 64 * j);
        }
    }
    __syncthreads();

    for (int ch = 2; ch < 8; ++ch) {
        if (ch < 7) stage(ch + 1);
        const float4* cb = candB + (ch & 1) * 512;
        const int ib = ch * 512 + lane;
#pragma unroll
        for (int j = 0; j < 8; ++j) {
            float4 o = cb[lane + 64 * j];
            float dot = fmaf(o.z, me.z, fmaf(o.y, me.y, o.x * me.x));
            unsigned bb = __float_as_uint(fmaxf((me.w + o.w) - 2.0f * dot, 0.0f));
            if (bb <= tau) {
                int pos = atomicAdd(&scnt[wv], 1);
                if (pos < CAP)
                    survB[wv * CAP + pos] = ((unsigned long long)bb << 32) | (unsigned)(ib + 64 * j);
            }
        }
        __syncthreads();
    }

    // ---- phase A3: exact top-20 set ----
    int cnt = scnt[wv]; if (cnt > CAP) cnt = CAP;
    unsigned long long k0 = (lane       < cnt) ? survB[wv * CAP + lane      ] : ~0ull;
    unsigned long long k1 = (lane +  64 < cnt) ? survB[wv * CAP + lane +  64] : ~0ull;
    unsigned long long k2 = (lane + 128 < cnt) ? survB[wv * CAP + lane + 128] : ~0ull;
    unsigned long long k3 = (lane + 192 < cnt) ? survB[wv * CAP + lane + 192] : ~0ull;
    unsigned d0 = (unsigned)(k0 >> 32), d1 = (unsigned)(k1 >> 32);
    unsigned d2 = (unsigned)(k2 >> 32), d3 = (unsigned)(k3 >> 32);
    unsigned i0 = (unsigned)k0, i1 = (unsigned)k1, i2 = (unsigned)k2, i3 = (unsigned)k3;

    unsigned l2 = 0u, h2 = tau;
    for (int it = 0; it < 32; ++it) {
        unsigned mid = l2 + ((h2 - l2) >> 1);
        int c = __popcll(__ballot(d0 <= mid)) + __popcll(__ballot(d1 <= mid))
              + __popcll(__ballot(d2 <= mid)) + __popcll(__ballot(d3 <= mid));
        if (c >= KNBR) h2 = mid; else l2 = mid + 1;
    }
    const unsigned th = h2;
    int cless = __popcll(__ballot(d0 < th)) + __popcll(__ballot(d1 < th))
              + __popcll(__ballot(d2 < th)) + __popcll(__ballot(d3 < th));
    int need = KNBR - cless;
    bool t0 = (d0 == th), t1 = (d1 == th), t2 = (d2 == th), t3 = (d3 == th);
    int tcnt = __popcll(__ballot(t0)) + __popcll(__ballot(t1))
             + __popcll(__ballot(t2)) + __popcll(__ballot(t3));
    unsigned idxthr = 0xFFFFFFFFu;
    if (tcnt != need) {       // rare exact-d2-tie path (uniform branch)
        unsigned la = 0u, ha = 0xFFFFFFFFu;
        for (int it = 0; it < 32; ++it) {
            unsigned mid = la + ((ha - la) >> 1);
            int c = __popcll(__ballot(t0 && i0 <= mid)) + __popcll(__ballot(t1 && i1 <= mid))
                  + __popcll(__ballot(t2 && i2 <= mid)) + __popcll(__ballot(t3 && i3 <= mid));
            if (c >= need) ha = mid; else la = mid + 1;
        }
        idxthr = ha;
    }
    bool s0 = (d0 < th) || (t0 && i0 <= idxthr);
    bool s1 = (d1 < th) || (t1 && i1 <= idxthr);
    bool s2 = (d2 < th) || (t2 && i2 <= idxthr);
    bool s3 = (d3 < th) || (t3 && i3 <= idxthr);

    unsigned long long m01 = k0 < k1 ? k0 : k1;
    unsigned long long m23 = k2 < k3 ? k2 : k3;
    unsigned long long mk  = m01 < m23 ? m01 : m23;
#pragma unroll
    for (int off = 32; off >= 1; off >>= 1) {
        unsigned long long o = __shfl_xor(mk, off, 64);
        mk = o < mk ? o : mk;
    }
    if (s0) { if (k0 == mk) neighL[wv][0] = (int)i0; else { int p = atomicAdd(&slot[wv], 1); neighL[wv][p] = (int)i0; } }
    if (s1) { if (k1 == mk) neighL[wv][0] = (int)i1; else { int p = atomicAdd(&slot[wv], 1); neighL[wv][p] = (int)i1; } }
    if (s2) { if (k2 == mk) neighL[wv][0] = (int)i2; else { int p = atomicAdd(&slot[wv], 1); neighL[wv][p] = (int)i2; } }
    if (s3) { if (k3 == mk) neighL[wv][0] = (int)i3; else { int p = atomicAdd(&slot[wv], 1); neighL[wv][p] = (int)i3; } }

    __syncthreads();   // last surv/cand use above; Fb (aliased) written below

    // ================= phase B: attention =================
    const ushort* fb = fbT + (size_t)b * NPTS * INC;
    ushort* Fw = FbB + wv * 2048;

    int nv = 0;
    if (l31 < KNBR) nv = neighL[wv][l31];
    float4 ncl = base[nv];
    if (!hi && l31 < KNBR) f4buf[wv][l31] = ncl;

    float wm[8];
    {
        const float4* w8 = (const float4*)(wmlp8 + l31 * 8);
        float4 a = w8[0], bq = w8[1];
        wm[0] = a.x; wm[1] = a.y; wm[2] = a.z; wm[3] = a.w;
        wm[4] = bq.x; wm[5] = bq.y; wm[6] = bq.z; wm[7] = bq.w;
    }
    const float c0x = rlf(ncl.x, 0), c0y = rlf(ncl.y, 0), c0z = rlf(ncl.z, 0);

#pragma unroll
    for (int k = 0; k < KNBR; ++k) {
        int snk = __builtin_amdgcn_readlane(nv, k);
        ushort fraw = fb[(size_t)snk * INC + l31];
        float4 nk4 = f4buf[wv][k];
        float rx = nk4.x - c0x, ry = nk4.y - c0y, rz = nk4.z - c0z;
        float dis = sqrtf(fmaf(rz, rz, fmaf(ry, ry, rx * rx)));
        float fm = wm[7];
        fm = fmaf(wm[0], c0x, fm); fm = fmaf(wm[1], c0y, fm); fm = fmaf(wm[2], c0z, fm);
        fm = fmaf(wm[3], rx, fm);  fm = fmaf(wm[4], ry, fm);  fm = fmaf(wm[5], rz, fm);
        fm = fmaf(wm[6], dis, fm);
        ushort fbits = hi ? f2bf(fm) : fraw;
        Fw[k * 64 + (lane ^ ((k & 7) << 3))] = fbits;
    }

    short8 Af[4];
#pragma unroll
    for (int kt = 0; kt < 4; ++kt) {
        int c0 = kt * 16 + 8 * hi;
        Af[kt] = *(const short8*)&Fw[l31 * 64 + (c0 ^ ((l31 & 7) << 3))];
    }

    // flipped orientation: lane k holds d-column -> lane-local softmax stats
    float mloc, zloc;
    {
        f32x16 af;
#pragma unroll
        for (int i = 0; i < 16; ++i) af[i] = 0.f;
#pragma unroll
        for (int kt = 0; kt < 4; ++kt)
            af = __builtin_amdgcn_mfma_f32_32x32x16_bf16(wattF[kt * 64 + lane], Af[kt], af, 0, 0, 0);
        float m0 = af[0];
#pragma unroll
        for (int i = 1; i < 16; ++i) m0 = fmaxf(m0, af[i]);
        float z0 = 0.f;
#pragma unroll
        for (int i = 0; i < 16; ++i) z0 += __expf(af[i] - m0);
        mloc = m0; zloc = z0;
    }
    {
        f32x16 af;
#pragma unroll
        for (int i = 0; i < 16; ++i) af[i] = 0.f;
#pragma unroll
        for (int kt = 0; kt < 4; ++kt)
            af = __builtin_amdgcn_mfma_f32_32x32x16_bf16(wattF[(4 + kt) * 64 + lane], Af[kt], af, 0, 0, 0);
        float m1 = af[0];
#pragma unroll
        for (int i = 1; i < 16; ++i) m1 = fmaxf(m1, af[i]);
        float z1 = 0.f;
#pragma unroll
        for (int i = 0; i < 16; ++i) z1 += __expf(af[i] - m1);
        float mn = fmaxf(mloc, m1);
        zloc = zloc * __expf(mloc - mn) + z1 * __expf(m1 - mn);
        mloc = mn;
    }
    float mo = fmaxf(mloc, __shfl_xor(mloc, 32, 64));
    float zs = zloc * __expf(mloc - mo);
    float Zk = zs + __shfl_xor(zs, 32, 64);
    if (!hi && l31 < KNBR) mzb[wv][l31] = make_float2(mo, 1.0f / Zk);

    // original orientation + pooling, half at a time
    float pooled0 = 0.f, pooled1 = 0.f;
    {
        f32x16 acc;
#pragma unroll
        for (int i = 0; i < 16; ++i) acc[i] = 0.f;
#pragma unroll
        for (int kt = 0; kt < 4; ++kt)
            acc = __builtin_amdgcn_mfma_f32_32x32x16_bf16(Af[kt], wattF[kt * 64 + lane], acc, 0, 0, 0);
#pragma unroll
        for (int r = 0; r < 12; ++r) {
            int j = (r & 3) + 8 * (r >> 2) + 4 * hi;
            float2 mz = mzb[wv][j];
            float a0 = __expf(acc[r] - mz.x) * mz.y;
            float f0 = bf2f(Fw[j * 64 + (l31 ^ ((j & 7) << 3))]);
            float p0 = a0 * f0;
            if (r >= 8) p0 = hi ? 0.f : p0;
            pooled0 += p0;
        }
    }
    {
        f32x16 acc;
#pragma unroll
        for (int i = 0; i < 16; ++i) acc[i] = 0.f;
#pragma unroll
        for (int kt = 0; kt < 4; ++kt)
            acc = __builtin_amdgcn_mfma_f32_32x32x16_bf16(Af[kt], wattF[(4 + kt) * 64 + lane], acc, 0, 0, 0);
#pragma unroll
        for (int r = 0; r < 12; ++r) {
            int j = (r & 3) + 8 * (r >> 2) + 4 * hi;
            float2 mz = mzb[wv][j];
            float a1 = __expf(acc[r] - mz.x) * mz.y;
            float f1 = bf2f(Fw[j * 64 + ((32 + l31) ^ ((j & 7) << 3))]);
            float p1 = a1 * f1;
            if (r >= 8) p1 = hi ? 0.f : p1;
            pooled1 += p1;
        }
    }
    pooled0 += __shfl_xor(pooled0, 32, 64);
    pooled1 += __shfl_xor(pooled1, 32, 64);
    if (!hi) {
        pool[wv][l31]      = f2bf(pooled0);
        pool[wv][32 + l31] = f2bf(pooled1);
    }

    // epilogue: out = W_conv@pooled + W_out@feat (biases cancel in BN)
    f32x16 oa;
#pragma unroll
    for (int i = 0; i < 16; ++i) oa[i] = 0.f;
#pragma unroll
    for (int kt = 0; kt < 4; ++kt) {
        short8 bb = *(const short8*)&pool[wv][kt * 16 + 8 * hi];
        oa = __builtin_amdgcn_mfma_f32_32x32x16_bf16(wconvF[kt * 64 + lane], bb, oa, 0, 0, 0);
    }
#pragma unroll
    for (int kt = 0; kt < 2; ++kt) {
        short8 bb = *(const short8*)(fb + (size_t)nb * INC + kt * 16 + 8 * hi);
        oa = __builtin_amdgcn_mfma_f32_32x32x16_bf16(woutF[kt * 64 + lane], bb, oa, 0, 0, 0);
    }
#pragma unroll
    for (int r = 0; r < 16; ++r) {
        int o = (r & 3) + 8 * (r >> 2) + 4 * hi;
        if (l31 == 0) out[((size_t)(b * OUTC + o)) * NPTS + nb] = oa[r];
    }
}

// ---------------- kernel 3a: per-channel batch stats ----------------
__global__ __launch_bounds__(256) void k_stats(const float* __restrict__ of,
                                               float* __restrict__ stats) {
    int c = blockIdx.x;
    int tid = threadIdx.x;
    float s = 0.f, s2 = 0.f;
    for (int i = tid; i < BATCH * NPTS; i += 256) {
        int b = i >> 12, n = i & (NPTS - 1);
        float v = of[((size_t)b * OUTC + c) * NPTS + n];
        s += v; s2 = fmaf(v, v, s2);
    }
#pragma unroll
    for (int off = 32; off >= 1; off >>= 1) {
        s += __shfl_xor(s, off, 64);
        s2 += __shfl_xor(s2, off, 64);
    }
    __shared__ float rs[4], rs2[4];
    if ((tid & 63) == 0) { rs[tid >> 6] = s; rs2[tid >> 6] = s2; }
    __syncthreads();
    if (tid == 0) {
        float S = (rs[0] + rs[1]) + (rs[2] + rs[3]);
        float S2 = (rs2[0] + rs2[1]) + (rs2[2] + rs2[3]);
        const float invn = 1.0f / (BATCH * NPTS);
        float mean = S * invn;
        float var = S2 * invn - mean * mean;
        stats[c] = mean;
        stats[32 + c] = rsqrtf(var + EPSBN);
    }
}

// ---------------- kernel 3b: normalize in place ----------------
__global__ __launch_bounds__(256) void k_norm(float* __restrict__ of,
                                              const float* __restrict__ stats,
                                              const float* __restrict__ gamma,
                                              const float* __restrict__ beta) {
    int i = blockIdx.x * 256 + threadIdx.x;
    if (i >= BATCH * OUTC * NPTS) return;
    int c = (i >> 12) & (OUTC - 1);
    float v = of[i];
    of[i] = (v - stats[c]) * stats[32 + c] * gamma[c] + beta[c];
}

// ---------------- launch ----------------
extern "C" void kernel_launch(void* const* d_in, const int* in_sizes, int n_in,
                              void* d_out, int out_size, void* d_ws, size_t ws_size,
                              hipStream_t stream) {
    const float* x      = (const float*)d_in[0];
    const float* feat   = (const float*)d_in[1];
    const float* w_mlp  = (const float*)d_in[2];
    const float* b_mlp  = (const float*)d_in[3];
    const float* w_att  = (const float*)d_in[4];
    const float* w_conv = (const float*)d_in[5];
    const float* w_out  = (const float*)d_in[7];
    const float* gamma  = (const float*)d_in[9];
    const float* beta   = (const float*)d_in[10];
    float* out = (float*)d_out;

    char* ws = (char*)d_ws;
    float4* xT4    = (float4*)ws;                          // 262144 B
    ushort* fbT    = (ushort*)(ws + 262144);               // 1048576 B
    float*  stats  = (float*)(ws + 1310720);               // 256 B
    short8* wattF  = (short8*)(ws + 1310976);              // 8192 B
    short8* wconvF = (short8*)(ws + 1319168);              // 4096 B
    short8* woutF  = (short8*)(ws + 1323264);              // 2048 B
    float*  wmlp8  = (float*)(ws + 1325312);               // 2048 B

    k_prep<<<(BATCH * INC * NPTS + 255) / 256 + 1, 256, 0, stream>>>(
        x, feat, xT4, fbT, w_att, w_conv, w_out, w_mlp, b_mlp,
        wattF, wconvF, woutF, wmlp8);
    k_fused<<<(BATCH * NPTS) / PPBK, 512, 0, stream>>>(xT4, fbT, wmlp8,
                                                       wattF, wconvF, woutF, out);
    k_stats<<<OUTC, 256, 0, stream>>>(out, stats);
    k_norm<<<(BATCH * OUTC * NPTS + 255) / 256, 256, 0, stream>>>(out, stats, gamma, beta);
}

// Round 9
// 112.301 us; speedup vs baseline: 5.5452x; 1.0772x over previous
//
#include <hip/hip_runtime.h>
#include <hip/hip_bf16.h>

#define BATCH 4
#define NPTS  4096
#define KNBR  20
#define INC   32
#define TWC   64   // 2*INC
#define OUTC  32
#define EPSBN 1e-5f

typedef short short8 __attribute__((ext_vector_type(8)));
typedef float f32x16 __attribute__((ext_vector_type(16)));

// ---------------- helpers ----------------
__device__ __forceinline__ float rlf(float v, int l) {
    return __uint_as_float((unsigned)__builtin_amdgcn_readlane((int)__float_as_uint(v), l));
}
__device__ __forceinline__ ushort f2bf(float x) {        // fp32 -> bf16 bits (RNE)
    unsigned u = __float_as_uint(x);
    unsigned r = u + 0x7FFFu + ((u >> 16) & 1u);
    return (ushort)(r >> 16);
}
__device__ __forceinline__ float bf2f(ushort h) {
    return __uint_as_float(((unsigned)h) << 16);
}
__device__ __forceinline__ void gll16(const float4* g, float4* l) {
    __builtin_amdgcn_global_load_lds((const __attribute__((address_space(1))) void*)g,
                                     (__attribute__((address_space(3))) void*)l, 16, 0, 0);
}

// ---------------- kernel 0: fused transposes + weight prepack ----------------
__global__ __launch_bounds__(256) void k_prep(const float* __restrict__ x,
                                              const float* __restrict__ f,
                                              float4* __restrict__ xT4,
                                              ushort* __restrict__ fT,
                                              const float* __restrict__ w_att,
                                              const float* __restrict__ w_conv,
                                              const float* __restrict__ w_out,
                                              const float* __restrict__ w_mlp,
                                              const float* __restrict__ b_mlp,
                                              short8* __restrict__ wattF,
                                              short8* __restrict__ wconvF,
                                              short8* __restrict__ woutF,
                                              float* __restrict__ wmlp8) {
    int i = blockIdx.x * 256 + threadIdx.x;
    if (i < BATCH * NPTS) {
        int b = i / NPTS, n = i % NPTS;
        const float* xb = x + (size_t)b * 3 * NPTS;
        float x0 = xb[n], x1 = xb[NPTS + n], x2 = xb[2 * NPTS + n];
        float sq = fmaf(x2, x2, fmaf(x1, x1, x0 * x0));
        xT4[i] = make_float4(x0, x1, x2, sq);
    }
    if (i < BATCH * INC * NPTS) {
        int n = i % NPTS; int t = i / NPTS; int c = t % INC; int b = t / INC;
        fT[((size_t)(b * NPTS + n)) * INC + c] = f2bf(f[i]);
    }
    if (blockIdx.x == gridDim.x - 1) {
        int t = threadIdx.x;
        for (int idx = t; idx < 14 * 64; idx += 256) {
            int fr = idx >> 6, ln = idx & 63, l31 = ln & 31, h8 = (ln >> 5) * 8;
            short8 v;
            if (fr < 8) {
                int nt = fr >> 2, kt = fr & 3;
                const float* s = w_att + (nt * 32 + l31) * 64 + kt * 16 + h8;
#pragma unroll
                for (int j = 0; j < 8; ++j) v[j] = (short)f2bf(s[j]);
                wattF[fr * 64 + ln] = v;
            } else if (fr < 12) {
                int kt = fr - 8;
                const float* s = w_conv + l31 * 64 + kt * 16 + h8;
#pragma unroll
                for (int j = 0; j < 8; ++j) v[j] = (short)f2bf(s[j]);
                wconvF[kt * 64 + ln] = v;
            } else {
                int kt = fr - 12;
                const float* s = w_out + l31 * 32 + kt * 16 + h8;
#pragma unroll
                for (int j = 0; j < 8; ++j) v[j] = (short)f2bf(s[j]);
                woutF[kt * 64 + ln] = v;
            }
        }
        for (int idx = t; idx < 512; idx += 256) {
            int e = idx >> 3, j = idx & 7;
            wmlp8[idx] = (j < 7) ? w_mlp[e * 7 + j] : b_mlp[e];
        }
    }
}

// ---------------- kernel 1: FUSED knn + attention ----------------
// 512 threads = 8 waves = 8 points. Phase A: filter+exact-set KNN with
// results in LDS. Phase B: dual-orientation MFMA attention per wave.
// Fb (32 KB) aliases cand(16K)+surv(16K). launch_bounds(512,6): 85-reg
// budget (the (512,8)=64-reg bound caused 180 MB/dispatch scratch spills).
#define CAP   256
#define PPBK  8
__global__ __launch_bounds__(512, 6) void k_fused(const float4* __restrict__ xT4,
                                                  const ushort* __restrict__ fbT,
                                                  const float* __restrict__ wmlp8,
                                                  const short8* __restrict__ wattF,
                                                  const short8* __restrict__ wconvF,
                                                  const short8* __restrict__ woutF,
                                                  float* __restrict__ out) {
    __shared__ __align__(16) char smA[32768];       // cand[2][512]f4 + surv[8][256]u64 / Fb[8][2048]u16
    float4*             candB = (float4*)smA;
    unsigned long long* survB = (unsigned long long*)(smA + 16384);
    ushort*             FbB   = (ushort*)smA;
    __shared__ int scnt[PPBK], slot[PPBK];
    __shared__ int neighL[PPBK][KNBR];              // 640 B
    __shared__ __align__(16) ushort pool[PPBK][64]; // 1024 B

    const int tid  = threadIdx.x;
    const int lane = tid & 63;
    const int wv   = tid >> 6;
    const int hi   = lane >> 5;
    const int l31  = lane & 31;
    const int gp   = blockIdx.x * PPBK + wv;
    const int b    = gp >> 12;
    const int nb   = gp & (NPTS - 1);
    const float4* base = xT4 + (size_t)b * NPTS;

    if (lane == 0) { scnt[wv] = 0; slot[wv] = 1; }

    float4 me = xT4[gp];

    auto stage = [&](int c) {
        const float4* src = base + c * 512 + wv * 64 + lane;
        float4* dst = candB + (c & 1) * 512 + wv * 64;   // wave-uniform base; HW adds lane*16
        gll16(src, dst);
    };

    stage(0); stage(1);
    __syncthreads();

    // ---- phase A1: subset distances (candidates 0..1023) in regs ----
    unsigned bits[16];
#pragma unroll
    for (int j = 0; j < 8; ++j) {
        float4 o = candB[lane + 64 * j];
        float dot = fmaf(o.z, me.z, fmaf(o.y, me.y, o.x * me.x));
        bits[j] = __float_as_uint(fmaxf((me.w + o.w) - 2.0f * dot, 0.0f));
    }
#pragma unroll
    for (int j = 0; j < 8; ++j) {
        float4 o = candB[512 + lane + 64 * j];
        float dot = fmaf(o.z, me.z, fmaf(o.y, me.y, o.x * me.x));
        bits[8 + j] = __float_as_uint(fmaxf((me.w + o.w) - 2.0f * dot, 0.0f));
    }
    __syncthreads();
    stage(2);

    unsigned lo = 0u, hi2 = 0xFF000000u;
    for (int it = 0; it < 16; ++it) {
        unsigned mid = lo + ((hi2 - lo) >> 1);
        int c = 0;
#pragma unroll
        for (int j = 0; j < 16; ++j) c += __popcll(__ballot(bits[j] <= mid));
        if (c >= KNBR) hi2 = mid; else lo = mid + 1;
    }
    const unsigned tau = hi2;

    // ---- phase A2: append survivors ----
#pragma unroll
    for (int j = 0; j < 16; ++j) {
        if (bits[j] <= tau) {
            int pos = atomicAdd(&scnt[wv], 1);
            if (pos < CAP)
                survB[wv * CAP + pos] = ((unsigned long long)bits[j] << 32) | (unsigned)(lane + 64 * j);
        }
    }
    __syncthreads();

    for (int ch = 2; ch < 8; ++ch) {
        if (ch < 7) stage(ch + 1);
        const float4* cb = candB + (ch & 1) * 512;
        const int ib = ch * 512 + lane;
#pragma unroll
        for (int j = 0; j < 8; ++j) {
            float4 o = cb[lane + 64 * j];
            float dot = fmaf(o.z, me.z, fmaf(o.y, me.y, o.x * me.x));
            unsigned bb = __float_as_uint(fmaxf((me.w + o.w) - 2.0f * dot, 0.0f));
            if (bb <= tau) {
                int pos = atomicAdd(&scnt[wv], 1);
                if (pos < CAP)
                    survB[wv * CAP + pos] = ((unsigned long long)bb << 32) | (unsigned)(ib + 64 * j);
            }
        }
        __syncthreads();
    }

    // ---- phase A3: exact top-20 set (2-key fast path when cnt<=128) ----
    int cnt = scnt[wv]; if (cnt > CAP) cnt = CAP;
    const unsigned long long* sv = survB + wv * CAP;

    if (cnt <= 128) {
        unsigned long long k0 = (lane      < cnt) ? sv[lane     ] : ~0ull;
        unsigned long long k1 = (lane + 64 < cnt) ? sv[lane + 64] : ~0ull;
        unsigned d0 = (unsigned)(k0 >> 32), d1 = (unsigned)(k1 >> 32);
        unsigned i0 = (unsigned)k0, i1 = (unsigned)k1;

        unsigned l2 = 0u, h2 = tau;
        for (int it = 0; it < 32; ++it) {
            unsigned mid = l2 + ((h2 - l2) >> 1);
            int c = __popcll(__ballot(d0 <= mid)) + __popcll(__ballot(d1 <= mid));
            if (c >= KNBR) h2 = mid; else l2 = mid + 1;
        }
        const unsigned th = h2;
        int cless = __popcll(__ballot(d0 < th)) + __popcll(__ballot(d1 < th));
        int need = KNBR - cless;
        bool t0 = (d0 == th), t1 = (d1 == th);
        int tcnt = __popcll(__ballot(t0)) + __popcll(__ballot(t1));
        unsigned idxthr = 0xFFFFFFFFu;
        if (tcnt != need) {
            unsigned la = 0u, ha = 0xFFFFFFFFu;
            for (int it = 0; it < 32; ++it) {
                unsigned mid = la + ((ha - la) >> 1);
                int c = __popcll(__ballot(t0 && i0 <= mid)) + __popcll(__ballot(t1 && i1 <= mid));
                if (c >= need) ha = mid; else la = mid + 1;
            }
            idxthr = ha;
        }
        bool s0 = (d0 < th) || (t0 && i0 <= idxthr);
        bool s1 = (d1 < th) || (t1 && i1 <= idxthr);

        unsigned long long mk = k0 < k1 ? k0 : k1;
#pragma unroll
        for (int off = 32; off >= 1; off >>= 1) {
            unsigned long long o = __shfl_xor(mk, off, 64);
            mk = o < mk ? o : mk;
        }
        if (s0) { if (k0 == mk) neighL[wv][0] = (int)i0; else { int p = atomicAdd(&slot[wv], 1); neighL[wv][p] = (int)i0; } }
        if (s1) { if (k1 == mk) neighL[wv][0] = (int)i1; else { int p = atomicAdd(&slot[wv], 1); neighL[wv][p] = (int)i1; } }
    } else {
        unsigned long long k0 = (lane       < cnt) ? sv[lane      ] : ~0ull;
        unsigned long long k1 = (lane +  64 < cnt) ? sv[lane +  64] : ~0ull;
        unsigned long long k2 = (lane + 128 < cnt) ? sv[lane + 128] : ~0ull;
        unsigned long long k3 = (lane + 192 < cnt) ? sv[lane + 192] : ~0ull;
        unsigned d0 = (unsigned)(k0 >> 32), d1 = (unsigned)(k1 >> 32);
        unsigned d2 = (unsigned)(k2 >> 32), d3 = (unsigned)(k3 >> 32);
        unsigned i0 = (unsigned)k0, i1 = (unsigned)k1, i2 = (unsigned)k2, i3 = (unsigned)k3;

        unsigned l2 = 0u, h2 = tau;
        for (int it = 0; it < 32; ++it) {
            unsigned mid = l2 + ((h2 - l2) >> 1);
            int c = __popcll(__ballot(d0 <= mid)) + __popcll(__ballot(d1 <= mid))
                  + __popcll(__ballot(d2 <= mid)) + __popcll(__ballot(d3 <= mid));
            if (c >= KNBR) h2 = mid; else l2 = mid + 1;
        }
        const unsigned th = h2;
        int cless = __popcll(__ballot(d0 < th)) + __popcll(__ballot(d1 < th))
                  + __popcll(__ballot(d2 < th)) + __popcll(__ballot(d3 < th));
        int need = KNBR - cless;
        bool t0 = (d0 == th), t1 = (d1 == th), t2 = (d2 == th), t3 = (d3 == th);
        int tcnt = __popcll(__ballot(t0)) + __popcll(__ballot(t1))
                 + __popcll(__ballot(t2)) + __popcll(__ballot(t3));
        unsigned idxthr = 0xFFFFFFFFu;
        if (tcnt != need) {
            unsigned la = 0u, ha = 0xFFFFFFFFu;
            for (int it = 0; it < 32; ++it) {
                unsigned mid = la + ((ha - la) >> 1);
                int c = __popcll(__ballot(t0 && i0 <= mid)) + __popcll(__ballot(t1 && i1 <= mid))
                      + __popcll(__ballot(t2 && i2 <= mid)) + __popcll(__ballot(t3 && i3 <= mid));
                if (c >= need) ha = mid; else la = mid + 1;
            }
            idxthr = ha;
        }
        bool s0 = (d0 < th) || (t0 && i0 <= idxthr);
        bool s1 = (d1 < th) || (t1 && i1 <= idxthr);
        bool s2 = (d2 < th) || (t2 && i2 <= idxthr);
        bool s3 = (d3 < th) || (t3 && i3 <= idxthr);

        unsigned long long m01 = k0 < k1 ? k0 : k1;
        unsigned long long m23 = k2 < k3 ? k2 : k3;
        unsigned long long mk  = m01 < m23 ? m01 : m23;
#pragma unroll
        for (int off = 32; off >= 1; off >>= 1) {
            unsigned long long o = __shfl_xor(mk, off, 64);
            mk = o < mk ? o : mk;
        }
        if (s0) { if (k0 == mk) neighL[wv][0] = (int)i0; else { int p = atomicAdd(&slot[wv], 1); neighL[wv][p] = (int)i0; } }
        if (s1) { if (k1 == mk) neighL[wv][0] = (int)i1; else { int p = atomicAdd(&slot[wv], 1); neighL[wv][p] = (int)i1; } }
        if (s2) { if (k2 == mk) neighL[wv][0] = (int)i2; else { int p = atomicAdd(&slot[wv], 1); neighL[wv][p] = (int)i2; } }
        if (s3) { if (k3 == mk) neighL[wv][0] = (int)i3; else { int p = atomicAdd(&slot[wv], 1); neighL[wv][p] = (int)i3; } }
    }

    __syncthreads();   // last surv/cand use above; Fb (aliased) written below

    // ================= phase B: attention =================
    const ushort* fb = fbT + (size_t)b * NPTS * INC;
    ushort* Fw = FbB + wv * 2048;

    int nv = 0;
    if (l31 < KNBR) nv = neighL[wv][l31];
    float4 ncl = base[nv];

    float wm[8];
    {
        const float4* w8 = (const float4*)(wmlp8 + l31 * 8);
        float4 a = w8[0], bq = w8[1];
        wm[0] = a.x; wm[1] = a.y; wm[2] = a.z; wm[3] = a.w;
        wm[4] = bq.x; wm[5] = bq.y; wm[6] = bq.z; wm[7] = bq.w;
    }
    const float c0x = rlf(ncl.x, 0), c0y = rlf(ncl.y, 0), c0z = rlf(ncl.z, 0);

    // batched gather prefetch: all 20 feature loads issued before any use
    ushort fr[KNBR];
#pragma unroll
    for (int k = 0; k < KNBR; ++k) {
        int snk = __builtin_amdgcn_readlane(nv, k);
        fr[k] = fb[(size_t)snk * INC + l31];
    }

#pragma unroll
    for (int k = 0; k < KNBR; ++k) {
        float rx = rlf(ncl.x, k) - c0x;
        float ry = rlf(ncl.y, k) - c0y;
        float rz = rlf(ncl.z, k) - c0z;
        float dis = sqrtf(fmaf(rz, rz, fmaf(ry, ry, rx * rx)));
        float fm = wm[7];
        fm = fmaf(wm[0], c0x, fm); fm = fmaf(wm[1], c0y, fm); fm = fmaf(wm[2], c0z, fm);
        fm = fmaf(wm[3], rx, fm);  fm = fmaf(wm[4], ry, fm);  fm = fmaf(wm[5], rz, fm);
        fm = fmaf(wm[6], dis, fm);
        ushort fbits = hi ? f2bf(fm) : fr[k];
        Fw[k * 64 + (lane ^ ((k & 7) << 3))] = fbits;
    }

    short8 Af[4];
#pragma unroll
    for (int kt = 0; kt < 4; ++kt) {
        int c0 = kt * 16 + 8 * hi;
        Af[kt] = *(const short8*)&Fw[l31 * 64 + (c0 ^ ((l31 & 7) << 3))];
    }

    // flipped orientation: lane k holds d-column -> lane-local softmax stats
    float mloc, zloc;
    {
        f32x16 af;
#pragma unroll
        for (int i = 0; i < 16; ++i) af[i] = 0.f;
        __builtin_amdgcn_s_setprio(1);
#pragma unroll
        for (int kt = 0; kt < 4; ++kt)
            af = __builtin_amdgcn_mfma_f32_32x32x16_bf16(wattF[kt * 64 + lane], Af[kt], af, 0, 0, 0);
        __builtin_amdgcn_s_setprio(0);
        float m0 = af[0];
#pragma unroll
        for (int i = 1; i < 16; ++i) m0 = fmaxf(m0, af[i]);
        float z0 = 0.f;
#pragma unroll
        for (int i = 0; i < 16; ++i) z0 += __expf(af[i] - m0);
        mloc = m0; zloc = z0;
    }
    {
        f32x16 af;
#pragma unroll
        for (int i = 0; i < 16; ++i) af[i] = 0.f;
        __builtin_amdgcn_s_setprio(1);
#pragma unroll
        for (int kt = 0; kt < 4; ++kt)
            af = __builtin_amdgcn_mfma_f32_32x32x16_bf16(wattF[(4 + kt) * 64 + lane], Af[kt], af, 0, 0, 0);
        __builtin_amdgcn_s_setprio(0);
        float m1 = af[0];
#pragma unroll
        for (int i = 1; i < 16; ++i) m1 = fmaxf(m1, af[i]);
        float z1 = 0.f;
#pragma unroll
        for (int i = 0; i < 16; ++i) z1 += __expf(af[i] - m1);
        float mn = fmaxf(mloc, m1);
        zloc = zloc * __expf(mloc - mn) + z1 * __expf(m1 - mn);
        mloc = mn;
    }
    float mo = fmaxf(mloc, __shfl_xor(mloc, 32, 64));
    float zs = zloc * __expf(mloc - mo);
    float Zk = zs + __shfl_xor(zs, 32, 64);
    float invZ = 1.0f / Zk;
    // stats for neighbor j live in lane j (and j+32): broadcast via readlane

    // original orientation + pooling, half at a time
    float pooled0 = 0.f, pooled1 = 0.f;
    {
        f32x16 acc;
#pragma unroll
        for (int i = 0; i < 16; ++i) acc[i] = 0.f;
        __builtin_amdgcn_s_setprio(1);
#pragma unroll
        for (int kt = 0; kt < 4; ++kt)
            acc = __builtin_amdgcn_mfma_f32_32x32x16_bf16(Af[kt], wattF[kt * 64 + lane], acc, 0, 0, 0);
        __builtin_amdgcn_s_setprio(0);
#pragma unroll
        for (int r = 0; r < 12; ++r) {
            int j = (r & 3) + 8 * (r >> 2) + 4 * hi;
            float mzm = rlf(mo, j);
            float mzi = rlf(invZ, j);
            float a0 = __expf(acc[r] - mzm) * mzi;
            float f0 = bf2f(Fw[j * 64 + (l31 ^ ((j & 7) << 3))]);
            float p0 = a0 * f0;
            if (r >= 8) p0 = hi ? 0.f : p0;           // j>=20 rows invalid (garbage stats selected away)
            pooled0 += p0;
        }
    }
    {
        f32x16 acc;
#pragma unroll
        for (int i = 0; i < 16; ++i) acc[i] = 0.f;
        __builtin_amdgcn_s_setprio(1);
#pragma unroll
        for (int kt = 0; kt < 4; ++kt)
            acc = __builtin_amdgcn_mfma_f32_32x32x16_bf16(Af[kt], wattF[(4 + kt) * 64 + lane], acc, 0, 0, 0);
        __builtin_amdgcn_s_setprio(0);
#pragma unroll
        for (int r = 0; r < 12; ++r) {
            int j = (r & 3) + 8 * (r >> 2) + 4 * hi;
            float mzm = rlf(mo, j);
            float mzi = rlf(invZ, j);
            float a1 = __expf(acc[r] - mzm) * mzi;
            float f1 = bf2f(Fw[j * 64 + ((32 + l31) ^ ((j & 7) << 3))]);
            float p1 = a1 * f1;
            if (r >= 8) p1 = hi ? 0.f : p1;
            pooled1 += p1;
        }
    }
    pooled0 += __shfl_xor(pooled0, 32, 64);
    pooled1 += __shfl_xor(pooled1, 32, 64);
    if (!hi) {
        pool[wv][l31]      = f2bf(pooled0);
        pool[wv][32 + l31] = f2bf(pooled1);
    }

    // epilogue: out = W_conv@pooled + W_out@feat (biases cancel in BN)
    f32x16 oa;
#pragma unroll
    for (int i = 0; i < 16; ++i) oa[i] = 0.f;
    __builtin_amdgcn_s_setprio(1);
#pragma unroll
    for (int kt = 0; kt < 4; ++kt) {
        short8 bb = *(const short8*)&pool[wv][kt * 16 + 8 * hi];
        oa = __builtin_amdgcn_mfma_f32_32x32x16_bf16(wconvF[kt * 64 + lane], bb, oa, 0, 0, 0);
    }
#pragma unroll
    for (int kt = 0; kt < 2; ++kt) {
        short8 bb = *(const short8*)(fb + (size_t)nb * INC + kt * 16 + 8 * hi);
        oa = __builtin_amdgcn_mfma_f32_32x32x16_bf16(woutF[kt * 64 + lane], bb, oa, 0, 0, 0);
    }
    __builtin_amdgcn_s_setprio(0);
#pragma unroll
    for (int r = 0; r < 16; ++r) {
        int o = (r & 3) + 8 * (r >> 2) + 4 * hi;
        if (l31 == 0) out[((size_t)(b * OUTC + o)) * NPTS + nb] = oa[r];
    }
}

// ---------------- kernel 3a: per-channel batch stats ----------------
__global__ __launch_bounds__(256) void k_stats(const float* __restrict__ of,
                                               float* __restrict__ stats) {
    int c = blockIdx.x;
    int tid = threadIdx.x;
    float s = 0.f, s2 = 0.f;
    for (int i = tid; i < BATCH * NPTS; i += 256) {
        int b = i >> 12, n = i & (NPTS - 1);
        float v = of[((size_t)b * OUTC + c) * NPTS + n];
        s += v; s2 = fmaf(v, v, s2);
    }
#pragma unroll
    for (int off = 32; off >= 1; off >>= 1) {
        s += __shfl_xor(s, off, 64);
        s2 += __shfl_xor(s2, off, 64);
    }
    __shared__ float rs[4], rs2[4];
    if ((tid & 63) == 0) { rs[tid >> 6] = s; rs2[tid >> 6] = s2; }
    __syncthreads();
    if (tid == 0) {
        float S = (rs[0] + rs[1]) + (rs[2] + rs[3]);
        float S2 = (rs2[0] + rs2[1]) + (rs2[2] + rs2[3]);
        const float invn = 1.0f / (BATCH * NPTS);
        float mean = S * invn;
        float var = S2 * invn - mean * mean;
        stats[c] = mean;
        stats[32 + c] = rsqrtf(var + EPSBN);
    }
}

// ---------------- kernel 3b: normalize in place ----------------
__global__ __launch_bounds__(256) void k_norm(float* __restrict__ of,
                                              const float* __restrict__ stats,
                                              const float* __restrict__ gamma,
                                              const float* __restrict__ beta) {
    int i = blockIdx.x * 256 + threadIdx.x;
    if (i >= BATCH * OUTC * NPTS) return;
    int c = (i >> 12) & (OUTC - 1);
    float v = of[i];
    of[i] = (v - stats[c]) * stats[32 + c] * gamma[c] + beta[c];
}

// ---------------- launch ----------------
extern "C" void kernel_launch(void* const* d_in, const int* in_sizes, int n_in,
                              void* d_out, int out_size, void* d_ws, size_t ws_size,
                              hipStream_t stream) {
    const float* x      = (const float*)d_in[0];
    const float* feat   = (const float*)d_in[1];
    const float* w_mlp  = (const float*)d_in[2];
    const float* b_mlp  = (const float*)d_in[3];
    const float* w_att  = (const float*)d_in[4];
    const float* w_conv = (const float*)d_in[5];
    const float* w_out  = (const float*)d_in[7];
    const float* gamma  = (const float*)d_in[9];
    const float* beta   = (const float*)d_in[10];
    float* out = (float*)d_out;

    char* ws = (char*)d_ws;
    float4* xT4    = (float4*)ws;                          // 262144 B
    ushort* fbT    = (ushort*)(ws + 262144);               // 1048576 B
    float*  stats  = (float*)(ws + 1310720);               // 256 B
    short8* wattF  = (short8*)(ws + 1310976);              // 8192 B
    short8* wconvF = (short8*)(ws + 1319168);              // 4096 B
    short8* woutF  = (short8*)(ws + 1323264);              // 2048 B
    float*  wmlp8  = (float*)(ws + 1325312);               // 2048 B

    k_prep<<<(BATCH * INC * NPTS + 255) / 256 + 1, 256, 0, stream>>>(
        x, feat, xT4, fbT, w_att, w_conv, w_out, w_mlp, b_mlp,
        wattF, wconvF, woutF, wmlp8);
    k_fused<<<(BATCH * NPTS) / PPBK, 512, 0, stream>>>(xT4, fbT, wmlp8,
                                                       wattF, wconvF, woutF, out);
    k_stats<<<OUTC, 256, 0, stream>>>(out, stats);
    k_norm<<<(BATCH * OUTC * NPTS + 255) / 256, 256, 0, stream>>>(out, stats, gamma, beta);
}

// Round 10
// 91.998 us; speedup vs baseline: 6.7690x; 1.2207x over previous
//
#include <hip/hip_runtime.h>
#include <hip/hip_bf16.h>

#define BATCH 4
#define NPTS  4096
#define KNBR  20
#define INC   32
#define TWC   64   // 2*INC
#define OUTC  32
#define EPSBN 1e-5f

typedef short short8 __attribute__((ext_vector_type(8)));
typedef float f32x16 __attribute__((ext_vector_type(16)));

// ---------------- helpers ----------------
__device__ __forceinline__ float rlf(float v, int l) {
    return __uint_as_float((unsigned)__builtin_amdgcn_readlane((int)__float_as_uint(v), l));
}
__device__ __forceinline__ ushort f2bf(float x) {        // fp32 -> bf16 bits (RNE)
    unsigned u = __float_as_uint(x);
    unsigned r = u + 0x7FFFu + ((u >> 16) & 1u);
    return (ushort)(r >> 16);
}
__device__ __forceinline__ float bf2f(ushort h) {
    return __uint_as_float(((unsigned)h) << 16);
}
__device__ __forceinline__ void gll16(const float4* g, float4* l) {
    __builtin_amdgcn_global_load_lds((const __attribute__((address_space(1))) void*)g,
                                     (__attribute__((address_space(3))) void*)l, 16, 0, 0);
}

// ---------------- kernel 0: fused transposes + weight prepack ----------------
__global__ __launch_bounds__(256) void k_prep(const float* __restrict__ x,
                                              const float* __restrict__ f,
                                              float4* __restrict__ xT4,
                                              ushort* __restrict__ fT,
                                              const float* __restrict__ w_att,
                                              const float* __restrict__ w_conv,
                                              const float* __restrict__ w_out,
                                              const float* __restrict__ w_mlp,
                                              const float* __restrict__ b_mlp,
                                              short8* __restrict__ wattF,
                                              short8* __restrict__ wconvF,
                                              short8* __restrict__ woutF,
                                              float* __restrict__ wmlp8) {
    int i = blockIdx.x * 256 + threadIdx.x;
    if (i < BATCH * NPTS) {
        int b = i / NPTS, n = i % NPTS;
        const float* xb = x + (size_t)b * 3 * NPTS;
        float x0 = xb[n], x1 = xb[NPTS + n], x2 = xb[2 * NPTS + n];
        float sq = fmaf(x2, x2, fmaf(x1, x1, x0 * x0));
        xT4[i] = make_float4(x0, x1, x2, sq);
    }
    if (i < BATCH * INC * NPTS) {
        int n = i % NPTS; int t = i / NPTS; int c = t % INC; int b = t / INC;
        fT[((size_t)(b * NPTS + n)) * INC + c] = f2bf(f[i]);
    }
    if (blockIdx.x == gridDim.x - 1) {
        int t = threadIdx.x;
        for (int idx = t; idx < 14 * 64; idx += 256) {
            int fr = idx >> 6, ln = idx & 63, l31 = ln & 31, h8 = (ln >> 5) * 8;
            short8 v;
            if (fr < 8) {
                int nt = fr >> 2, kt = fr & 3;
                const float* s = w_att + (nt * 32 + l31) * 64 + kt * 16 + h8;
#pragma unroll
                for (int j = 0; j < 8; ++j) v[j] = (short)f2bf(s[j]);
                wattF[fr * 64 + ln] = v;
            } else if (fr < 12) {
                int kt = fr - 8;
                const float* s = w_conv + l31 * 64 + kt * 16 + h8;
#pragma unroll
                for (int j = 0; j < 8; ++j) v[j] = (short)f2bf(s[j]);
                wconvF[kt * 64 + ln] = v;
            } else {
                int kt = fr - 12;
                const float* s = w_out + l31 * 32 + kt * 16 + h8;
#pragma unroll
                for (int j = 0; j < 8; ++j) v[j] = (short)f2bf(s[j]);
                woutF[kt * 64 + ln] = v;
            }
        }
        for (int idx = t; idx < 512; idx += 256) {
            int e = idx >> 3, j = idx & 7;
            wmlp8[idx] = (j < 7) ? w_mlp[e * 7 + j] : b_mlp[e];
        }
    }
}

// ---------------- kernel 1: FUSED knn + attention ----------------
// 512 threads = 8 waves = 8 points. Phase A: filter+exact-set KNN with
// results in LDS. Phase B: dual-orientation MFMA attention per wave.
// Fb (32 KB) aliases cand(16K)+surv(16K). launch_bounds(512,6): 85-reg
// budget (the (512,8)=64-reg bound caused 180 MB/dispatch scratch spills).
// tau via min/2nd-min capped-count bisect (2 ballots/iter, still a valid
// upper bound on the 20th distance); A3 bisect early-exits when the count
// hits exactly 20 (20th value = wave-max of keys <= mid).
#define CAP   256
#define PPBK  8
__global__ __launch_bounds__(512, 6) void k_fused(const float4* __restrict__ xT4,
                                                  const ushort* __restrict__ fbT,
                                                  const float* __restrict__ wmlp8,
                                                  const short8* __restrict__ wattF,
                                                  const short8* __restrict__ wconvF,
                                                  const short8* __restrict__ woutF,
                                                  float* __restrict__ out) {
    __shared__ __align__(16) char smA[32768];       // cand[2][512]f4 + surv[8][256]u64 / Fb[8][2048]u16
    float4*             candB = (float4*)smA;
    unsigned long long* survB = (unsigned long long*)(smA + 16384);
    ushort*             FbB   = (ushort*)smA;
    __shared__ int scnt[PPBK], slot[PPBK];
    __shared__ int neighL[PPBK][KNBR];              // 640 B
    __shared__ __align__(16) ushort pool[PPBK][64]; // 1024 B

    const int tid  = threadIdx.x;
    const int lane = tid & 63;
    const int wv   = tid >> 6;
    const int hi   = lane >> 5;
    const int l31  = lane & 31;
    const int gp   = blockIdx.x * PPBK + wv;
    const int b    = gp >> 12;
    const int nb   = gp & (NPTS - 1);
    const float4* base = xT4 + (size_t)b * NPTS;

    if (lane == 0) { scnt[wv] = 0; slot[wv] = 1; }

    float4 me = xT4[gp];

    auto stage = [&](int c) {
        const float4* src = base + c * 512 + wv * 64 + lane;
        float4* dst = candB + (c & 1) * 512 + wv * 64;   // wave-uniform base; HW adds lane*16
        gll16(src, dst);
    };

    stage(0); stage(1);
    __syncthreads();

    // ---- phase A1: subset distances + per-lane min/2nd-min ----
    unsigned bits[16];
    unsigned lmin = 0xFFFFFFFFu, lmin2 = 0xFFFFFFFFu;
#pragma unroll
    for (int j = 0; j < 8; ++j) {
        float4 o = candB[lane + 64 * j];
        float dot = fmaf(o.z, me.z, fmaf(o.y, me.y, o.x * me.x));
        unsigned bb = __float_as_uint(fmaxf((me.w + o.w) - 2.0f * dot, 0.0f));
        bits[j] = bb;
        unsigned lo_ = bb < lmin ? bb : lmin;
        unsigned hi_ = bb < lmin ? lmin : bb;
        lmin = lo_;
        lmin2 = hi_ < lmin2 ? hi_ : lmin2;
    }
#pragma unroll
    for (int j = 0; j < 8; ++j) {
        float4 o = candB[512 + lane + 64 * j];
        float dot = fmaf(o.z, me.z, fmaf(o.y, me.y, o.x * me.x));
        unsigned bb = __float_as_uint(fmaxf((me.w + o.w) - 2.0f * dot, 0.0f));
        bits[8 + j] = bb;
        unsigned lo_ = bb < lmin ? bb : lmin;
        unsigned hi_ = bb < lmin ? lmin : bb;
        lmin = lo_;
        lmin2 = hi_ < lmin2 ? hi_ : lmin2;
    }
    __syncthreads();
    stage(2);

    // tau bisect: count candidates capped at 2/lane (valid upper bound)
    unsigned lo = 0u, hi2 = 0xFF000000u;
    for (int it = 0; it < 16 && lo < hi2; ++it) {
        unsigned mid = lo + ((hi2 - lo) >> 1);
        int c = __popcll(__ballot(lmin <= mid)) + __popcll(__ballot(lmin2 <= mid));
        if (c >= KNBR) hi2 = mid; else lo = mid + 1;
    }
    const unsigned tau = hi2;

    // ---- phase A2: append survivors ----
#pragma unroll
    for (int j = 0; j < 16; ++j) {
        if (bits[j] <= tau) {
            int pos = atomicAdd(&scnt[wv], 1);
            if (pos < CAP)
                survB[wv * CAP + pos] = ((unsigned long long)bits[j] << 32) | (unsigned)(lane + 64 * j);
        }
    }
    __syncthreads();

    for (int ch = 2; ch < 8; ++ch) {
        if (ch < 7) stage(ch + 1);
        const float4* cb = candB + (ch & 1) * 512;
        const int ib = ch * 512 + lane;
#pragma unroll
        for (int j = 0; j < 8; ++j) {
            float4 o = cb[lane + 64 * j];
            float dot = fmaf(o.z, me.z, fmaf(o.y, me.y, o.x * me.x));
            unsigned bb = __float_as_uint(fmaxf((me.w + o.w) - 2.0f * dot, 0.0f));
            if (bb <= tau) {
                int pos = atomicAdd(&scnt[wv], 1);
                if (pos < CAP)
                    survB[wv * CAP + pos] = ((unsigned long long)bb << 32) | (unsigned)(ib + 64 * j);
            }
        }
        __syncthreads();
    }

    // ---- phase A3: exact top-20 set (2-key fast path when cnt<=128) ----
    int cnt = scnt[wv]; if (cnt > CAP) cnt = CAP;
    const unsigned long long* sv = survB + wv * CAP;

    if (cnt <= 128) {
        unsigned long long k0 = (lane      < cnt) ? sv[lane     ] : ~0ull;
        unsigned long long k1 = (lane + 64 < cnt) ? sv[lane + 64] : ~0ull;
        unsigned d0 = (unsigned)(k0 >> 32), d1 = (unsigned)(k1 >> 32);
        unsigned i0 = (unsigned)k0, i1 = (unsigned)k1;

        unsigned th;
        {
            unsigned l2 = 0u, h2 = tau;
            bool found = false;
            for (int it = 0; it < 32; ++it) {
                unsigned mid = l2 + ((h2 - l2) >> 1);
                int c = __popcll(__ballot(d0 <= mid)) + __popcll(__ballot(d1 <= mid));
                if (c >= KNBR) h2 = mid; else l2 = mid + 1;
                if (c == KNBR) {              // exact: 20th = max key <= mid
                    unsigned mm = (d0 <= mid) ? d0 : 0u;
                    unsigned m2_ = (d1 <= mid) ? d1 : 0u;
                    mm = mm > m2_ ? mm : m2_;
#pragma unroll
                    for (int off = 32; off >= 1; off >>= 1) {
                        unsigned o = __shfl_xor(mm, off, 64);
                        mm = o > mm ? o : mm;
                    }
                    th = mm; found = true; break;
                }
                if (l2 >= h2) break;
            }
            if (!found) th = h2;
        }
        int cless = __popcll(__ballot(d0 < th)) + __popcll(__ballot(d1 < th));
        int need = KNBR - cless;
        bool t0 = (d0 == th), t1 = (d1 == th);
        int tcnt = __popcll(__ballot(t0)) + __popcll(__ballot(t1));
        unsigned idxthr = 0xFFFFFFFFu;
        if (tcnt != need) {
            unsigned la = 0u, ha = 0xFFFFFFFFu;
            for (int it = 0; it < 32; ++it) {
                unsigned mid = la + ((ha - la) >> 1);
                int c = __popcll(__ballot(t0 && i0 <= mid)) + __popcll(__ballot(t1 && i1 <= mid));
                if (c >= need) ha = mid; else la = mid + 1;
            }
            idxthr = ha;
        }
        bool s0 = (d0 < th) || (t0 && i0 <= idxthr);
        bool s1 = (d1 < th) || (t1 && i1 <= idxthr);

        unsigned long long mk = k0 < k1 ? k0 : k1;
#pragma unroll
        for (int off = 32; off >= 1; off >>= 1) {
            unsigned long long o = __shfl_xor(mk, off, 64);
            mk = o < mk ? o : mk;
        }
        if (s0) { if (k0 == mk) neighL[wv][0] = (int)i0; else { int p = atomicAdd(&slot[wv], 1); neighL[wv][p] = (int)i0; } }
        if (s1) { if (k1 == mk) neighL[wv][0] = (int)i1; else { int p = atomicAdd(&slot[wv], 1); neighL[wv][p] = (int)i1; } }
    } else {
        unsigned long long k0 = (lane       < cnt) ? sv[lane      ] : ~0ull;
        unsigned long long k1 = (lane +  64 < cnt) ? sv[lane +  64] : ~0ull;
        unsigned long long k2 = (lane + 128 < cnt) ? sv[lane + 128] : ~0ull;
        unsigned long long k3 = (lane + 192 < cnt) ? sv[lane + 192] : ~0ull;
        unsigned d0 = (unsigned)(k0 >> 32), d1 = (unsigned)(k1 >> 32);
        unsigned d2 = (unsigned)(k2 >> 32), d3 = (unsigned)(k3 >> 32);
        unsigned i0 = (unsigned)k0, i1 = (unsigned)k1, i2 = (unsigned)k2, i3 = (unsigned)k3;

        unsigned l2 = 0u, h2 = tau;
        for (int it = 0; it < 32 && l2 < h2; ++it) {
            unsigned mid = l2 + ((h2 - l2) >> 1);
            int c = __popcll(__ballot(d0 <= mid)) + __popcll(__ballot(d1 <= mid))
                  + __popcll(__ballot(d2 <= mid)) + __popcll(__ballot(d3 <= mid));
            if (c >= KNBR) h2 = mid; else l2 = mid + 1;
        }
        const unsigned th = h2;
        int cless = __popcll(__ballot(d0 < th)) + __popcll(__ballot(d1 < th))
                  + __popcll(__ballot(d2 < th)) + __popcll(__ballot(d3 < th));
        int need = KNBR - cless;
        bool t0 = (d0 == th), t1 = (d1 == th), t2 = (d2 == th), t3 = (d3 == th);
        int tcnt = __popcll(__ballot(t0)) + __popcll(__ballot(t1))
                 + __popcll(__ballot(t2)) + __popcll(__ballot(t3));
        unsigned idxthr = 0xFFFFFFFFu;
        if (tcnt != need) {
            unsigned la = 0u, ha = 0xFFFFFFFFu;
            for (int it = 0; it < 32; ++it) {
                unsigned mid = la + ((ha - la) >> 1);
                int c = __popcll(__ballot(t0 && i0 <= mid)) + __popcll(__ballot(t1 && i1 <= mid))
                      + __popcll(__ballot(t2 && i2 <= mid)) + __popcll(__ballot(t3 && i3 <= mid));
                if (c >= need) ha = mid; else la = mid + 1;
            }
            idxthr = ha;
        }
        bool s0 = (d0 < th) || (t0 && i0 <= idxthr);
        bool s1 = (d1 < th) || (t1 && i1 <= idxthr);
        bool s2 = (d2 < th) || (t2 && i2 <= idxthr);
        bool s3 = (d3 < th) || (t3 && i3 <= idxthr);

        unsigned long long m01 = k0 < k1 ? k0 : k1;
        unsigned long long m23 = k2 < k3 ? k2 : k3;
        unsigned long long mk  = m01 < m23 ? m01 : m23;
#pragma unroll
        for (int off = 32; off >= 1; off >>= 1) {
            unsigned long long o = __shfl_xor(mk, off, 64);
            mk = o < mk ? o : mk;
        }
        if (s0) { if (k0 == mk) neighL[wv][0] = (int)i0; else { int p = atomicAdd(&slot[wv], 1); neighL[wv][p] = (int)i0; } }
        if (s1) { if (k1 == mk) neighL[wv][0] = (int)i1; else { int p = atomicAdd(&slot[wv], 1); neighL[wv][p] = (int)i1; } }
        if (s2) { if (k2 == mk) neighL[wv][0] = (int)i2; else { int p = atomicAdd(&slot[wv], 1); neighL[wv][p] = (int)i2; } }
        if (s3) { if (k3 == mk) neighL[wv][0] = (int)i3; else { int p = atomicAdd(&slot[wv], 1); neighL[wv][p] = (int)i3; } }
    }

    __syncthreads();   // last surv/cand use above; Fb (aliased) written below

    // ================= phase B: attention =================
    const ushort* fb = fbT + (size_t)b * NPTS * INC;
    ushort* Fw = FbB + wv * 2048;

    int nv = 0;
    if (l31 < KNBR) nv = neighL[wv][l31];
    float4 ncl = base[nv];

    float wm[8];
    {
        const float4* w8 = (const float4*)(wmlp8 + l31 * 8);
        float4 a = w8[0], bq = w8[1];
        wm[0] = a.x; wm[1] = a.y; wm[2] = a.z; wm[3] = a.w;
        wm[4] = bq.x; wm[5] = bq.y; wm[6] = bq.z; wm[7] = bq.w;
    }
    const float c0x = rlf(ncl.x, 0), c0y = rlf(ncl.y, 0), c0z = rlf(ncl.z, 0);

    // batched gather prefetch: all 20 feature loads issued before any use
    ushort fr[KNBR];
#pragma unroll
    for (int k = 0; k < KNBR; ++k) {
        int snk = __builtin_amdgcn_readlane(nv, k);
        fr[k] = fb[(size_t)snk * INC + l31];
    }

    float fmbase = wm[7];
    fmbase = fmaf(wm[0], c0x, fmbase); fmbase = fmaf(wm[1], c0y, fmbase);
    fmbase = fmaf(wm[2], c0z, fmbase);
#pragma unroll
    for (int k = 0; k < KNBR; ++k) {
        float rx = rlf(ncl.x, k) - c0x;
        float ry = rlf(ncl.y, k) - c0y;
        float rz = rlf(ncl.z, k) - c0z;
        float dis = sqrtf(fmaf(rz, rz, fmaf(ry, ry, rx * rx)));
        float fm = fmbase;
        fm = fmaf(wm[3], rx, fm);  fm = fmaf(wm[4], ry, fm);  fm = fmaf(wm[5], rz, fm);
        fm = fmaf(wm[6], dis, fm);
        ushort fbits = hi ? f2bf(fm) : fr[k];
        Fw[k * 64 + (lane ^ ((k & 7) << 3))] = fbits;
    }

    short8 Af[4];
#pragma unroll
    for (int kt = 0; kt < 4; ++kt) {
        int c0 = kt * 16 + 8 * hi;
        Af[kt] = *(const short8*)&Fw[l31 * 64 + (c0 ^ ((l31 & 7) << 3))];
    }

    // flipped orientation: lane k holds d-column -> lane-local softmax stats
    float mloc, zloc;
    {
        f32x16 af;
#pragma unroll
        for (int i = 0; i < 16; ++i) af[i] = 0.f;
        __builtin_amdgcn_s_setprio(1);
#pragma unroll
        for (int kt = 0; kt < 4; ++kt)
            af = __builtin_amdgcn_mfma_f32_32x32x16_bf16(wattF[kt * 64 + lane], Af[kt], af, 0, 0, 0);
        __builtin_amdgcn_s_setprio(0);
        float m0 = af[0];
#pragma unroll
        for (int i = 1; i < 16; ++i) m0 = fmaxf(m0, af[i]);
        float z0 = 0.f;
#pragma unroll
        for (int i = 0; i < 16; ++i) z0 += __expf(af[i] - m0);
        mloc = m0; zloc = z0;
    }
    {
        f32x16 af;
#pragma unroll
        for (int i = 0; i < 16; ++i) af[i] = 0.f;
        __builtin_amdgcn_s_setprio(1);
#pragma unroll
        for (int kt = 0; kt < 4; ++kt)
            af = __builtin_amdgcn_mfma_f32_32x32x16_bf16(wattF[(4 + kt) * 64 + lane], Af[kt], af, 0, 0, 0);
        __builtin_amdgcn_s_setprio(0);
        float m1 = af[0];
#pragma unroll
        for (int i = 1; i < 16; ++i) m1 = fmaxf(m1, af[i]);
        float z1 = 0.f;
#pragma unroll
        for (int i = 0; i < 16; ++i) z1 += __expf(af[i] - m1);
        float mn = fmaxf(mloc, m1);
        zloc = zloc * __expf(mloc - mn) + z1 * __expf(m1 - mn);
        mloc = mn;
    }
    float mo = fmaxf(mloc, __shfl_xor(mloc, 32, 64));
    float zs = zloc * __expf(mloc - mo);
    float Zk = zs + __shfl_xor(zs, 32, 64);
    float invZ = 1.0f / Zk;
    // stats for neighbor j live in lane j (and j+32): broadcast via readlane

    // original orientation + pooling, half at a time
    float pooled0 = 0.f, pooled1 = 0.f;
    {
        f32x16 acc;
#pragma unroll
        for (int i = 0; i < 16; ++i) acc[i] = 0.f;
        __builtin_amdgcn_s_setprio(1);
#pragma unroll
        for (int kt = 0; kt < 4; ++kt)
            acc = __builtin_amdgcn_mfma_f32_32x32x16_bf16(Af[kt], wattF[kt * 64 + lane], acc, 0, 0, 0);
        __builtin_amdgcn_s_setprio(0);
#pragma unroll
        for (int r = 0; r < 12; ++r) {
            int j = (r & 3) + 8 * (r >> 2) + 4 * hi;
            float mzm = rlf(mo, j);
            float mzi = rlf(invZ, j);
            float a0 = __expf(acc[r] - mzm) * mzi;
            float f0 = bf2f(Fw[j * 64 + (l31 ^ ((j & 7) << 3))]);
            float p0 = a0 * f0;
            if (r >= 8) p0 = hi ? 0.f : p0;           // j>=20 rows invalid (garbage stats selected away)
            pooled0 += p0;
        }
    }
    {
        f32x16 acc;
#pragma unroll
        for (int i = 0; i < 16; ++i) acc[i] = 0.f;
        __builtin_amdgcn_s_setprio(1);
#pragma unroll
        for (int kt = 0; kt < 4; ++kt)
            acc = __builtin_amdgcn_mfma_f32_32x32x16_bf16(Af[kt], wattF[(4 + kt) * 64 + lane], acc, 0, 0, 0);
        __builtin_amdgcn_s_setprio(0);
#pragma unroll
        for (int r = 0; r < 12; ++r) {
            int j = (r & 3) + 8 * (r >> 2) + 4 * hi;
            float mzm = rlf(mo, j);
            float mzi = rlf(invZ, j);
            float a1 = __expf(acc[r] - mzm) * mzi;
            float f1 = bf2f(Fw[j * 64 + ((32 + l31) ^ ((j & 7) << 3))]);
            float p1 = a1 * f1;
            if (r >= 8) p1 = hi ? 0.f : p1;
            pooled1 += p1;
        }
    }
    pooled0 += __shfl_xor(pooled0, 32, 64);
    pooled1 += __shfl_xor(pooled1, 32, 64);
    if (!hi) {
        pool[wv][l31]      = f2bf(pooled0);
        pool[wv][32 + l31] = f2bf(pooled1);
    }

    // epilogue: out = W_conv@pooled + W_out@feat (biases cancel in BN)
    f32x16 oa;
#pragma unroll
    for (int i = 0; i < 16; ++i) oa[i] = 0.f;
    __builtin_amdgcn_s_setprio(1);
#pragma unroll
    for (int kt = 0; kt < 4; ++kt) {
        short8 bb = *(const short8*)&pool[wv][kt * 16 + 8 * hi];
        oa = __builtin_amdgcn_mfma_f32_32x32x16_bf16(wconvF[kt * 64 + lane], bb, oa, 0, 0, 0);
    }
#pragma unroll
    for (int kt = 0; kt < 2; ++kt) {
        short8 bb = *(const short8*)(fb + (size_t)nb * INC + kt * 16 + 8 * hi);
        oa = __builtin_amdgcn_mfma_f32_32x32x16_bf16(woutF[kt * 64 + lane], bb, oa, 0, 0, 0);
    }
    __builtin_amdgcn_s_setprio(0);
#pragma unroll
    for (int r = 0; r < 16; ++r) {
        int o = (r & 3) + 8 * (r >> 2) + 4 * hi;
        if (l31 == 0) out[((size_t)(b * OUTC + o)) * NPTS + nb] = oa[r];
    }
}

// ---------------- kernel 2: fused BatchNorm (stats + normalize) ----------------
// 32 blocks, one per channel. Channel data = 4 contiguous 16KB runs (L2-hot).
__global__ __launch_bounds__(256) void k_bn(float* __restrict__ of,
                                            const float* __restrict__ gamma,
                                            const float* __restrict__ beta) {
    const int c = blockIdx.x;
    const int tid = threadIdx.x;
    float s = 0.f, s2 = 0.f;
#pragma unroll
    for (int b = 0; b < BATCH; ++b) {
        const float4* p = (const float4*)(of + ((size_t)b * OUTC + c) * NPTS);
        for (int i = tid; i < NPTS / 4; i += 256) {
            float4 v = p[i];
            s += (v.x + v.y) + (v.z + v.w);
            s2 = fmaf(v.x, v.x, s2); s2 = fmaf(v.y, v.y, s2);
            s2 = fmaf(v.z, v.z, s2); s2 = fmaf(v.w, v.w, s2);
        }
    }
#pragma unroll
    for (int off = 32; off >= 1; off >>= 1) {
        s += __shfl_xor(s, off, 64);
        s2 += __shfl_xor(s2, off, 64);
    }
    __shared__ float rs[4], rs2[4];
    __shared__ float sc[2];
    if ((tid & 63) == 0) { rs[tid >> 6] = s; rs2[tid >> 6] = s2; }
    __syncthreads();
    if (tid == 0) {
        float S = (rs[0] + rs[1]) + (rs[2] + rs[3]);
        float S2 = (rs2[0] + rs2[1]) + (rs2[2] + rs2[3]);
        const float invn = 1.0f / (BATCH * NPTS);
        float mean = S * invn;
        float var = S2 * invn - mean * mean;
        float rstd = rsqrtf(var + EPSBN);
        float scale = rstd * gamma[c];
        sc[0] = scale;
        sc[1] = beta[c] - mean * scale;
    }
    __syncthreads();
    const float scale = sc[0], shift = sc[1];
#pragma unroll
    for (int b = 0; b < BATCH; ++b) {
        float4* p = (float4*)(of + ((size_t)b * OUTC + c) * NPTS);
        for (int i = tid; i < NPTS / 4; i += 256) {
            float4 v = p[i];
            v.x = fmaf(v.x, scale, shift);
            v.y = fmaf(v.y, scale, shift);
            v.z = fmaf(v.z, scale, shift);
            v.w = fmaf(v.w, scale, shift);
            p[i] = v;
        }
    }
}

// ---------------- launch ----------------
extern "C" void kernel_launch(void* const* d_in, const int* in_sizes, int n_in,
                              void* d_out, int out_size, void* d_ws, size_t ws_size,
                              hipStream_t stream) {
    const float* x      = (const float*)d_in[0];
    const float* feat   = (const float*)d_in[1];
    const float* w_mlp  = (const float*)d_in[2];
    const float* b_mlp  = (const float*)d_in[3];
    const float* w_att  = (const float*)d_in[4];
    const float* w_conv = (const float*)d_in[5];
    const float* w_out  = (const float*)d_in[7];
    const float* gamma  = (const float*)d_in[9];
    const float* beta   = (const float*)d_in[10];
    float* out = (float*)d_out;

    char* ws = (char*)d_ws;
    float4* xT4    = (float4*)ws;                          // 262144 B
    ushort* fbT    = (ushort*)(ws + 262144);               // 1048576 B
    short8* wattF  = (short8*)(ws + 1310976);              // 8192 B
    short8* wconvF = (short8*)(ws + 1319168);              // 4096 B
    short8* woutF  = (short8*)(ws + 1323264);              // 2048 B
    float*  wmlp8  = (float*)(ws + 1325312);               // 2048 B

    k_prep<<<(BATCH * INC * NPTS + 255) / 256 + 1, 256, 0, stream>>>(
        x, feat, xT4, fbT, w_att, w_conv, w_out, w_mlp, b_mlp,
        wattF, wconvF, woutF, wmlp8);
    k_fused<<<(BATCH * NPTS) / PPBK, 512, 0, stream>>>(xT4, fbT, wmlp8,
                                                       wattF, wconvF, woutF, out);
    k_bn<<<OUTC, 256, 0, stream>>>(out, gamma, beta);
}

// Round 12
// 84.917 us; speedup vs baseline: 7.3334x; 1.0834x over previous
//
#include <hip/hip_runtime.h>
#include <hip/hip_bf16.h>

#define BATCH 4
#define NPTS  4096
#define KNBR  20
#define INC   32
#define TWC   64   // 2*INC
#define OUTC  32
#define EPSBN 1e-5f

typedef short short8 __attribute__((ext_vector_type(8)));
typedef float f32x16 __attribute__((ext_vector_type(16)));

// ---------------- helpers ----------------
__device__ __forceinline__ float rlf(float v, int l) {
    return __uint_as_float((unsigned)__builtin_amdgcn_readlane((int)__float_as_uint(v), l));
}
__device__ __forceinline__ ushort f2bf(float x) {        // fp32 -> bf16 bits (RNE)
    unsigned u = __float_as_uint(x);
    unsigned r = u + 0x7FFFu + ((u >> 16) & 1u);
    return (ushort)(r >> 16);
}
__device__ __forceinline__ float bf2f(ushort h) {
    return __uint_as_float(((unsigned)h) << 16);
}
__device__ __forceinline__ void gll16(const float4* g, float4* l) {
    __builtin_amdgcn_global_load_lds((const __attribute__((address_space(1))) void*)g,
                                     (__attribute__((address_space(3))) void*)l, 16, 0, 0);
}

// ---------------- kernel 0: fused transposes + weight prepack ----------------
__global__ __launch_bounds__(256) void k_prep(const float* __restrict__ x,
                                              const float* __restrict__ f,
                                              float4* __restrict__ xT4,
                                              ushort* __restrict__ fT,
                                              const float* __restrict__ w_att,
                                              const float* __restrict__ w_conv,
                                              const float* __restrict__ w_out,
                                              const float* __restrict__ w_mlp,
                                              const float* __restrict__ b_mlp,
                                              short8* __restrict__ wattF,
                                              short8* __restrict__ wconvF,
                                              short8* __restrict__ woutF,
                                              float* __restrict__ wmlp8) {
    int i = blockIdx.x * 256 + threadIdx.x;
    if (i < BATCH * NPTS) {
        int b = i / NPTS, n = i % NPTS;
        const float* xb = x + (size_t)b * 3 * NPTS;
        float x0 = xb[n], x1 = xb[NPTS + n], x2 = xb[2 * NPTS + n];
        float sq = fmaf(x2, x2, fmaf(x1, x1, x0 * x0));
        xT4[i] = make_float4(x0, x1, x2, sq);
    }
    if (i < BATCH * INC * NPTS) {
        int n = i % NPTS; int t = i / NPTS; int c = t % INC; int b = t / INC;
        fT[((size_t)(b * NPTS + n)) * INC + c] = f2bf(f[i]);
    }
    if (blockIdx.x == gridDim.x - 1) {
        int t = threadIdx.x;
        for (int idx = t; idx < 14 * 64; idx += 256) {
            int fr = idx >> 6, ln = idx & 63, l31 = ln & 31, h8 = (ln >> 5) * 8;
            short8 v;
            if (fr < 8) {
                int nt = fr >> 2, kt = fr & 3;
                const float* s = w_att + (nt * 32 + l31) * 64 + kt * 16 + h8;
#pragma unroll
                for (int j = 0; j < 8; ++j) v[j] = (short)f2bf(s[j]);
                wattF[fr * 64 + ln] = v;
            } else if (fr < 12) {
                int kt = fr - 8;
                const float* s = w_conv + l31 * 64 + kt * 16 + h8;
#pragma unroll
                for (int j = 0; j < 8; ++j) v[j] = (short)f2bf(s[j]);
                wconvF[kt * 64 + ln] = v;
            } else {
                int kt = fr - 12;
                const float* s = w_out + l31 * 32 + kt * 16 + h8;
#pragma unroll
                for (int j = 0; j < 8; ++j) v[j] = (short)f2bf(s[j]);
                woutF[kt * 64 + ln] = v;
            }
        }
        for (int idx = t; idx < 512; idx += 256) {
            int e = idx >> 3, j = idx & 7;
            wmlp8[idx] = (j < 7) ? w_mlp[e * 7 + j] : b_mlp[e];
        }
    }
}

// ---------------- kernel 1: FUSED knn + attention ----------------
// 512 threads = 8 waves = 8 points. Phase A: filter+exact-set KNN.
// Phase B: dual-orientation MFMA attention.
// CAP=192 (R11's CAP=128 overflowed: capped-count tau is LARGER than the
// exact-subset tau, survivor mean ~90-100, P(>128)~1e-3/point -> silent
// drops -> absmax 0.125. 192 is ~10sigma safe). Fb = 20 rows/wave.
// smA = max(16K cand + 12K surv, 20K Fb) = 28K; total ~30.4KB ->
// 4 blocks/CU guaranteed = 32 waves/CU HW cap.
#define CAP   192
#define PPBK  8
#define FWSZ  (KNBR * 64)   // 1280 ushorts per wave
__global__ __launch_bounds__(512, 6) void k_fused(const float4* __restrict__ xT4,
                                                  const ushort* __restrict__ fbT,
                                                  const float* __restrict__ wmlp8,
                                                  const short8* __restrict__ wattF,
                                                  const short8* __restrict__ wconvF,
                                                  const short8* __restrict__ woutF,
                                                  float* __restrict__ out) {
    __shared__ __align__(16) char smA[28672];       // cand[2][512]f4(16K)+surv[8][192]u64(12K) / Fb 8x1280u16(20K)
    float4*             candB = (float4*)smA;
    unsigned long long* survB = (unsigned long long*)(smA + 16384);
    ushort*             FbB   = (ushort*)smA;
    __shared__ int scnt[PPBK], slot[PPBK];
    __shared__ int neighL[PPBK][KNBR];              // 640 B
    __shared__ __align__(16) ushort pool[PPBK][64]; // 1024 B

    const int tid  = threadIdx.x;
    const int lane = tid & 63;
    const int wv   = tid >> 6;
    const int hi   = lane >> 5;
    const int l31  = lane & 31;
    const int gp   = blockIdx.x * PPBK + wv;
    const int b    = gp >> 12;
    const int nb   = gp & (NPTS - 1);
    const float4* base = xT4 + (size_t)b * NPTS;

    if (lane == 0) { scnt[wv] = 0; slot[wv] = 1; }

    float4 me = xT4[gp];

    auto stage = [&](int c) {
        const float4* src = base + c * 512 + wv * 64 + lane;
        float4* dst = candB + (c & 1) * 512 + wv * 64;   // wave-uniform base; HW adds lane*16
        gll16(src, dst);
    };

    stage(0); stage(1);
    __syncthreads();

    // ---- phase A1: subset distances + per-lane min/2nd-min ----
    unsigned bits[16];
    unsigned lmin = 0xFFFFFFFFu, lmin2 = 0xFFFFFFFFu;
#pragma unroll
    for (int j = 0; j < 8; ++j) {
        float4 o = candB[lane + 64 * j];
        float dot = fmaf(o.z, me.z, fmaf(o.y, me.y, o.x * me.x));
        unsigned bb = __float_as_uint(fmaxf((me.w + o.w) - 2.0f * dot, 0.0f));
        bits[j] = bb;
        unsigned lo_ = bb < lmin ? bb : lmin;
        unsigned hi_ = bb < lmin ? lmin : bb;
        lmin = lo_;
        lmin2 = hi_ < lmin2 ? hi_ : lmin2;
    }
#pragma unroll
    for (int j = 0; j < 8; ++j) {
        float4 o = candB[512 + lane + 64 * j];
        float dot = fmaf(o.z, me.z, fmaf(o.y, me.y, o.x * me.x));
        unsigned bb = __float_as_uint(fmaxf((me.w + o.w) - 2.0f * dot, 0.0f));
        bits[8 + j] = bb;
        unsigned lo_ = bb < lmin ? bb : lmin;
        unsigned hi_ = bb < lmin ? lmin : bb;
        lmin = lo_;
        lmin2 = hi_ < lmin2 ? hi_ : lmin2;
    }
    __syncthreads();
    stage(2);

    // tau bisect: count candidates capped at 2/lane (valid upper bound)
    unsigned lo = 0u, hi2 = 0xFF000000u;
    for (int it = 0; it < 16 && lo < hi2; ++it) {
        unsigned mid = lo + ((hi2 - lo) >> 1);
        int c = __popcll(__ballot(lmin <= mid)) + __popcll(__ballot(lmin2 <= mid));
        if (c >= KNBR) hi2 = mid; else lo = mid + 1;
    }
    const unsigned tau = hi2;

    // ---- phase A2: append survivors ----
#pragma unroll
    for (int j = 0; j < 16; ++j) {
        if (bits[j] <= tau) {
            int pos = atomicAdd(&scnt[wv], 1);
            if (pos < CAP)
                survB[wv * CAP + pos] = ((unsigned long long)bits[j] << 32) | (unsigned)(lane + 64 * j);
        }
    }
    __syncthreads();

    for (int ch = 2; ch < 8; ++ch) {
        if (ch < 7) stage(ch + 1);
        const float4* cb = candB + (ch & 1) * 512;
        const int ib = ch * 512 + lane;
#pragma unroll
        for (int j = 0; j < 8; ++j) {
            float4 o = cb[lane + 64 * j];
            float dot = fmaf(o.z, me.z, fmaf(o.y, me.y, o.x * me.x));
            unsigned bb = __float_as_uint(fmaxf((me.w + o.w) - 2.0f * dot, 0.0f));
            if (bb <= tau) {
                int pos = atomicAdd(&scnt[wv], 1);
                if (pos < CAP)
                    survB[wv * CAP + pos] = ((unsigned long long)bb << 32) | (unsigned)(ib + 64 * j);
            }
        }
        __syncthreads();
    }

    // ---- phase A3: exact top-20 set ----
    int cnt = scnt[wv]; if (cnt > CAP) cnt = CAP;
    const unsigned long long* sv = survB + wv * CAP;

    if (cnt <= 128) {   // common path: 2 keys/lane
        unsigned long long k0 = (lane      < cnt) ? sv[lane     ] : ~0ull;
        unsigned long long k1 = (lane + 64 < cnt) ? sv[lane + 64] : ~0ull;
        unsigned d0 = (unsigned)(k0 >> 32), d1 = (unsigned)(k1 >> 32);
        unsigned i0 = (unsigned)k0, i1 = (unsigned)k1;

        unsigned th;
        {
            unsigned l2 = 0u, h2 = tau;
            bool found = false;
            for (int it = 0; it < 32; ++it) {
                unsigned mid = l2 + ((h2 - l2) >> 1);
                int c = __popcll(__ballot(d0 <= mid)) + __popcll(__ballot(d1 <= mid));
                if (c >= KNBR) h2 = mid; else l2 = mid + 1;
                if (c == KNBR) {              // exact: 20th = max key <= mid
                    unsigned mm = (d0 <= mid) ? d0 : 0u;
                    unsigned m2_ = (d1 <= mid) ? d1 : 0u;
                    mm = mm > m2_ ? mm : m2_;
#pragma unroll
                    for (int off = 32; off >= 1; off >>= 1) {
                        unsigned o = __shfl_xor(mm, off, 64);
                        mm = o > mm ? o : mm;
                    }
                    th = mm; found = true; break;
                }
                if (l2 >= h2) break;
            }
            if (!found) th = h2;
        }
        int cless = __popcll(__ballot(d0 < th)) + __popcll(__ballot(d1 < th));
        int need = KNBR - cless;
        bool t0 = (d0 == th), t1 = (d1 == th);
        int tcnt = __popcll(__ballot(t0)) + __popcll(__ballot(t1));
        unsigned idxthr = 0xFFFFFFFFu;
        if (tcnt != need) {       // rare exact-d2-tie path (uniform branch)
            unsigned la = 0u, ha = 0xFFFFFFFFu;
            for (int it = 0; it < 32; ++it) {
                unsigned mid = la + ((ha - la) >> 1);
                int c = __popcll(__ballot(t0 && i0 <= mid)) + __popcll(__ballot(t1 && i1 <= mid));
                if (c >= need) ha = mid; else la = mid + 1;
            }
            idxthr = ha;
        }
        bool s0 = (d0 < th) || (t0 && i0 <= idxthr);
        bool s1 = (d1 < th) || (t1 && i1 <= idxthr);

        unsigned long long mk = k0 < k1 ? k0 : k1;
#pragma unroll
        for (int off = 32; off >= 1; off >>= 1) {
            unsigned long long o = __shfl_xor(mk, off, 64);
            mk = o < mk ? o : mk;
        }
        if (s0) { if (k0 == mk) neighL[wv][0] = (int)i0; else { int p = atomicAdd(&slot[wv], 1); neighL[wv][p] = (int)i0; } }
        if (s1) { if (k1 == mk) neighL[wv][0] = (int)i1; else { int p = atomicAdd(&slot[wv], 1); neighL[wv][p] = (int)i1; } }
    } else {            // rare fallback: 3 keys/lane (cnt <= 192 by CAP)
        unsigned long long k0 = (lane       < cnt) ? sv[lane      ] : ~0ull;
        unsigned long long k1 = (lane +  64 < cnt) ? sv[lane +  64] : ~0ull;
        unsigned long long k2 = (lane + 128 < cnt) ? sv[lane + 128] : ~0ull;
        unsigned d0 = (unsigned)(k0 >> 32), d1 = (unsigned)(k1 >> 32), d2 = (unsigned)(k2 >> 32);
        unsigned i0 = (unsigned)k0, i1 = (unsigned)k1, i2 = (unsigned)k2;

        unsigned l2 = 0u, h2 = tau;
        for (int it = 0; it < 32 && l2 < h2; ++it) {
            unsigned mid = l2 + ((h2 - l2) >> 1);
            int c = __popcll(__ballot(d0 <= mid)) + __popcll(__ballot(d1 <= mid))
                  + __popcll(__ballot(d2 <= mid));
            if (c >= KNBR) h2 = mid; else l2 = mid + 1;
        }
        const unsigned th = h2;
        int cless = __popcll(__ballot(d0 < th)) + __popcll(__ballot(d1 < th))
                  + __popcll(__ballot(d2 < th));
        int need = KNBR - cless;
        bool t0 = (d0 == th), t1 = (d1 == th), t2 = (d2 == th);
        int tcnt = __popcll(__ballot(t0)) + __popcll(__ballot(t1)) + __popcll(__ballot(t2));
        unsigned idxthr = 0xFFFFFFFFu;
        if (tcnt != need) {
            unsigned la = 0u, ha = 0xFFFFFFFFu;
            for (int it = 0; it < 32; ++it) {
                unsigned mid = la + ((ha - la) >> 1);
                int c = __popcll(__ballot(t0 && i0 <= mid)) + __popcll(__ballot(t1 && i1 <= mid))
                      + __popcll(__ballot(t2 && i2 <= mid));
                if (c >= need) ha = mid; else la = mid + 1;
            }
            idxthr = ha;
        }
        bool s0 = (d0 < th) || (t0 && i0 <= idxthr);
        bool s1 = (d1 < th) || (t1 && i1 <= idxthr);
        bool s2 = (d2 < th) || (t2 && i2 <= idxthr);

        unsigned long long m01 = k0 < k1 ? k0 : k1;
        unsigned long long mk  = m01 < k2 ? m01 : k2;
#pragma unroll
        for (int off = 32; off >= 1; off >>= 1) {
            unsigned long long o = __shfl_xor(mk, off, 64);
            mk = o < mk ? o : mk;
        }
        if (s0) { if (k0 == mk) neighL[wv][0] = (int)i0; else { int p = atomicAdd(&slot[wv], 1); neighL[wv][p] = (int)i0; } }
        if (s1) { if (k1 == mk) neighL[wv][0] = (int)i1; else { int p = atomicAdd(&slot[wv], 1); neighL[wv][p] = (int)i1; } }
        if (s2) { if (k2 == mk) neighL[wv][0] = (int)i2; else { int p = atomicAdd(&slot[wv], 1); neighL[wv][p] = (int)i2; } }
    }

    __syncthreads();   // last surv/cand use above; Fb (aliased) written below

    // ================= phase B: attention =================
    const ushort* fb = fbT + (size_t)b * NPTS * INC;
    ushort* Fw = FbB + wv * FWSZ;

    int nv = 0;
    if (l31 < KNBR) nv = neighL[wv][l31];
    float4 ncl = base[nv];

    float wm[8];
    {
        const float4* w8 = (const float4*)(wmlp8 + l31 * 8);
        float4 a = w8[0], bq = w8[1];
        wm[0] = a.x; wm[1] = a.y; wm[2] = a.z; wm[3] = a.w;
        wm[4] = bq.x; wm[5] = bq.y; wm[6] = bq.z; wm[7] = bq.w;
    }
    const float c0x = rlf(ncl.x, 0), c0y = rlf(ncl.y, 0), c0z = rlf(ncl.z, 0);

    // batched gather prefetch: all 20 feature loads issued before any use
    ushort fr[KNBR];
#pragma unroll
    for (int k = 0; k < KNBR; ++k) {
        int snk = __builtin_amdgcn_readlane(nv, k);
        fr[k] = fb[(size_t)snk * INC + l31];
    }

    // per-lane relative coords (lane k owns neighbor k); consumed via readlane
    float rxl = ncl.x - c0x, ryl = ncl.y - c0y, rzl = ncl.z - c0z;
    float disl = sqrtf(fmaf(rzl, rzl, fmaf(ryl, ryl, rxl * rxl)));

    float fmbase = wm[7];
    fmbase = fmaf(wm[0], c0x, fmbase); fmbase = fmaf(wm[1], c0y, fmbase);
    fmbase = fmaf(wm[2], c0z, fmbase);
#pragma unroll
    for (int k = 0; k < KNBR; ++k) {
        float fm = fmbase;
        fm = fmaf(wm[3], rlf(rxl, k), fm);
        fm = fmaf(wm[4], rlf(ryl, k), fm);
        fm = fmaf(wm[5], rlf(rzl, k), fm);
        fm = fmaf(wm[6], rlf(disl, k), fm);
        ushort fbits = hi ? f2bf(fm) : fr[k];
        Fw[k * 64 + (lane ^ ((k & 7) << 3))] = fbits;
    }

    const int rowA = (l31 < KNBR) ? l31 : (KNBR - 1);   // rows 20..31 = row-19 copies
    short8 Af[4];
#pragma unroll
    for (int kt = 0; kt < 4; ++kt) {
        int c0 = kt * 16 + 8 * hi;
        Af[kt] = *(const short8*)&Fw[rowA * 64 + (c0 ^ ((rowA & 7) << 3))];
    }

    // flipped orientation: lane k holds d-column -> lane-local softmax stats
    float mloc, zloc;
    {
        f32x16 af;
#pragma unroll
        for (int i = 0; i < 16; ++i) af[i] = 0.f;
        __builtin_amdgcn_s_setprio(1);
#pragma unroll
        for (int kt = 0; kt < 4; ++kt)
            af = __builtin_amdgcn_mfma_f32_32x32x16_bf16(wattF[kt * 64 + lane], Af[kt], af, 0, 0, 0);
        __builtin_amdgcn_s_setprio(0);
        float m0 = af[0];
#pragma unroll
        for (int i = 1; i < 16; ++i) m0 = fmaxf(m0, af[i]);
        float z0 = 0.f;
#pragma unroll
        for (int i = 0; i < 16; ++i) z0 += __expf(af[i] - m0);
        mloc = m0; zloc = z0;
    }
    {
        f32x16 af;
#pragma unroll
        for (int i = 0; i < 16; ++i) af[i] = 0.f;
        __builtin_amdgcn_s_setprio(1);
#pragma unroll
        for (int kt = 0; kt < 4; ++kt)
            af = __builtin_amdgcn_mfma_f32_32x32x16_bf16(wattF[(4 + kt) * 64 + lane], Af[kt], af, 0, 0, 0);
        __builtin_amdgcn_s_setprio(0);
        float m1 = af[0];
#pragma unroll
        for (int i = 1; i < 16; ++i) m1 = fmaxf(m1, af[i]);
        float z1 = 0.f;
#pragma unroll
        for (int i = 0; i < 16; ++i) z1 += __expf(af[i] - m1);
        float mn = fmaxf(mloc, m1);
        zloc = zloc * __expf(mloc - mn) + z1 * __expf(m1 - mn);
        mloc = mn;
    }
    float mo = fmaxf(mloc, __shfl_xor(mloc, 32, 64));
    float zs = zloc * __expf(mloc - mo);
    float Zk = zs + __shfl_xor(zs, 32, 64);
    float mzl = mo + __logf(Zk);      // log-fold: attn = exp(s - mzl)
    // stats for neighbor j live in lane j (and j+32): broadcast via readlane

    // original orientation + pooling, half at a time
    float pooled0 = 0.f, pooled1 = 0.f;
    {
        f32x16 acc;
#pragma unroll
        for (int i = 0; i < 16; ++i) acc[i] = 0.f;
        __builtin_amdgcn_s_setprio(1);
#pragma unroll
        for (int kt = 0; kt < 4; ++kt)
            acc = __builtin_amdgcn_mfma_f32_32x32x16_bf16(Af[kt], wattF[kt * 64 + lane], acc, 0, 0, 0);
        __builtin_amdgcn_s_setprio(0);
#pragma unroll
        for (int r = 0; r < 12; ++r) {
            int j = (r & 3) + 8 * (r >> 2) + 4 * hi;
            float a0 = __expf(acc[r] - rlf(mzl, j));
            float f0 = bf2f(Fw[j * 64 + (l31 ^ ((j & 7) << 3))]);
            float p0 = a0 * f0;
            if (r >= 8) p0 = hi ? 0.f : p0;           // j>=20 rows invalid
            pooled0 += p0;
        }
    }
    {
        f32x16 acc;
#pragma unroll
        for (int i = 0; i < 16; ++i) acc[i] = 0.f;
        __builtin_amdgcn_s_setprio(1);
#pragma unroll
        for (int kt = 0; kt < 4; ++kt)
            acc = __builtin_amdgcn_mfma_f32_32x32x16_bf16(Af[kt], wattF[(4 + kt) * 64 + lane], acc, 0, 0, 0);
        __builtin_amdgcn_s_setprio(0);
#pragma unroll
        for (int r = 0; r < 12; ++r) {
            int j = (r & 3) + 8 * (r >> 2) + 4 * hi;
            float a1 = __expf(acc[r] - rlf(mzl, j));
            float f1 = bf2f(Fw[j * 64 + ((32 + l31) ^ ((j & 7) << 3))]);
            float p1 = a1 * f1;
            if (r >= 8) p1 = hi ? 0.f : p1;
            pooled1 += p1;
        }
    }
    pooled0 += __shfl_xor(pooled0, 32, 64);
    pooled1 += __shfl_xor(pooled1, 32, 64);
    if (!hi) {
        pool[wv][l31]      = f2bf(pooled0);
        pool[wv][32 + l31] = f2bf(pooled1);
    }

    // epilogue: out = W_conv@pooled + W_out@feat (biases cancel in BN)
    f32x16 oa;
#pragma unroll
    for (int i = 0; i < 16; ++i) oa[i] = 0.f;
    __builtin_amdgcn_s_setprio(1);
#pragma unroll
    for (int kt = 0; kt < 4; ++kt) {
        short8 bb = *(const short8*)&pool[wv][kt * 16 + 8 * hi];
        oa = __builtin_amdgcn_mfma_f32_32x32x16_bf16(wconvF[kt * 64 + lane], bb, oa, 0, 0, 0);
    }
#pragma unroll
    for (int kt = 0; kt < 2; ++kt) {
        short8 bb = *(const short8*)(fb + (size_t)nb * INC + kt * 16 + 8 * hi);
        oa = __builtin_amdgcn_mfma_f32_32x32x16_bf16(woutF[kt * 64 + lane], bb, oa, 0, 0, 0);
    }
    __builtin_amdgcn_s_setprio(0);
#pragma unroll
    for (int r = 0; r < 16; ++r) {
        int o = (r & 3) + 8 * (r >> 2) + 4 * hi;
        if (l31 == 0) out[((size_t)(b * OUTC + o)) * NPTS + nb] = oa[r];
    }
}

// ---------------- kernel 2: fused BatchNorm (stats + normalize) ----------------
__global__ __launch_bounds__(256) void k_bn(float* __restrict__ of,
                                            const float* __restrict__ gamma,
                                            const float* __restrict__ beta) {
    const int c = blockIdx.x;
    const int tid = threadIdx.x;
    float s = 0.f, s2 = 0.f;
#pragma unroll
    for (int b = 0; b < BATCH; ++b) {
        const float4* p = (const float4*)(of + ((size_t)b * OUTC + c) * NPTS);
        for (int i = tid; i < NPTS / 4; i += 256) {
            float4 v = p[i];
            s += (v.x + v.y) + (v.z + v.w);
            s2 = fmaf(v.x, v.x, s2); s2 = fmaf(v.y, v.y, s2);
            s2 = fmaf(v.z, v.z, s2); s2 = fmaf(v.w, v.w, s2);
        }
    }
#pragma unroll
    for (int off = 32; off >= 1; off >>= 1) {
        s += __shfl_xor(s, off, 64);
        s2 += __shfl_xor(s2, off, 64);
    }
    __shared__ float rs[4], rs2[4];
    __shared__ float sc[2];
    if ((tid & 63) == 0) { rs[tid >> 6] = s; rs2[tid >> 6] = s2; }
    __syncthreads();
    if (tid == 0) {
        float S = (rs[0] + rs[1]) + (rs[2] + rs[3]);
        float S2 = (rs2[0] + rs2[1]) + (rs2[2] + rs2[3]);
        const float invn = 1.0f / (BATCH * NPTS);
        float mean = S * invn;
        float var = S2 * invn - mean * mean;
        float rstd = rsqrtf(var + EPSBN);
        float scale = rstd * gamma[c];
        sc[0] = scale;
        sc[1] = beta[c] - mean * scale;
    }
    __syncthreads();
    const float scale = sc[0], shift = sc[1];
#pragma unroll
    for (int b = 0; b < BATCH; ++b) {
        float4* p = (float4*)(of + ((size_t)b * OUTC + c) * NPTS);
        for (int i = tid; i < NPTS / 4; i += 256) {
            float4 v = p[i];
            v.x = fmaf(v.x, scale, shift);
            v.y = fmaf(v.y, scale, shift);
            v.z = fmaf(v.z, scale, shift);
            v.w = fmaf(v.w, scale, shift);
            p[i] = v;
        }
    }
}

// ---------------- launch ----------------
extern "C" void kernel_launch(void* const* d_in, const int* in_sizes, int n_in,
                              void* d_out, int out_size, void* d_ws, size_t ws_size,
                              hipStream_t stream) {
    const float* x      = (const float*)d_in[0];
    const float* feat   = (const float*)d_in[1];
    const float* w_mlp  = (const float*)d_in[2];
    const float* b_mlp  = (const float*)d_in[3];
    const float* w_att  = (const float*)d_in[4];
    const float* w_conv = (const float*)d_in[5];
    const float* w_out  = (const float*)d_in[7];
    const float* gamma  = (const float*)d_in[9];
    const float* beta   = (const float*)d_in[10];
    float* out = (float*)d_out;

    char* ws = (char*)d_ws;
    float4* xT4    = (float4*)ws;                          // 262144 B
    ushort* fbT    = (ushort*)(ws + 262144);               // 1048576 B
    short8* wattF  = (short8*)(ws + 1310976);              // 8192 B
    short8* wconvF = (short8*)(ws + 1319168);              // 4096 B
    short8* woutF  = (short8*)(ws + 1323264);              // 2048 B
    float*  wmlp8  = (float*)(ws + 1325312);               // 2048 B

    k_prep<<<(BATCH * INC * NPTS + 255) / 256 + 1, 256, 0, stream>>>(
        x, feat, xT4, fbT, w_att, w_conv, w_out, w_mlp, b_mlp,
        wattF, wconvF, woutF, wmlp8);
    k_fused<<<(BATCH * NPTS) / PPBK, 512, 0, stream>>>(xT4, fbT, wmlp8,
                                                       wattF, wconvF, woutF, out);
    k_bn<<<OUTC, 256, 0, stream>>>(out, gamma, beta);
}

// Round 13
// 84.482 us; speedup vs baseline: 7.3711x; 1.0051x over previous
//
#include <hip/hip_runtime.h>
#include <hip/hip_bf16.h>

#define BATCH 4
#define NPTS  4096
#define KNBR  20
#define INC   32
#define TWC   64   // 2*INC
#define OUTC  32
#define EPSBN 1e-5f

typedef short short8 __attribute__((ext_vector_type(8)));
typedef float f32x16 __attribute__((ext_vector_type(16)));

// ---------------- helpers ----------------
__device__ __forceinline__ float rlf(float v, int l) {
    return __uint_as_float((unsigned)__builtin_amdgcn_readlane((int)__float_as_uint(v), l));
}
__device__ __forceinline__ ushort f2bf(float x) {        // fp32 -> bf16 bits (RNE)
    unsigned u = __float_as_uint(x);
    unsigned r = u + 0x7FFFu + ((u >> 16) & 1u);
    return (ushort)(r >> 16);
}
__device__ __forceinline__ float bf2f(ushort h) {
    return __uint_as_float(((unsigned)h) << 16);
}
__device__ __forceinline__ void gll16(const float4* g, float4* l) {
    __builtin_amdgcn_global_load_lds((const __attribute__((address_space(1))) void*)g,
                                     (__attribute__((address_space(3))) void*)l, 16, 0, 0);
}
// raw barrier (no vmcnt drain) with compiler memory fences on both sides
__device__ __forceinline__ void barrier_nd() {
    asm volatile("" ::: "memory");
    __builtin_amdgcn_s_barrier();
    asm volatile("" ::: "memory");
}
template <int N> __device__ __forceinline__ void waitVm() {
    if constexpr (N == 0) asm volatile("s_waitcnt vmcnt(0)" ::: "memory");
    else if constexpr (N == 1) asm volatile("s_waitcnt vmcnt(1)" ::: "memory");
    else asm volatile("s_waitcnt vmcnt(2)" ::: "memory");
}

// ---------------- kernel 0: fused transposes + weight prepack ----------------
__global__ __launch_bounds__(256) void k_prep(const float* __restrict__ x,
                                              const float* __restrict__ f,
                                              float4* __restrict__ xT4,
                                              ushort* __restrict__ fT,
                                              const float* __restrict__ w_att,
                                              const float* __restrict__ w_conv,
                                              const float* __restrict__ w_out,
                                              const float* __restrict__ w_mlp,
                                              const float* __restrict__ b_mlp,
                                              short8* __restrict__ wattF,
                                              short8* __restrict__ wconvF,
                                              short8* __restrict__ woutF,
                                              float* __restrict__ wmlp8) {
    int i = blockIdx.x * 256 + threadIdx.x;
    if (i < BATCH * NPTS) {
        int b = i / NPTS, n = i % NPTS;
        const float* xb = x + (size_t)b * 3 * NPTS;
        float x0 = xb[n], x1 = xb[NPTS + n], x2 = xb[2 * NPTS + n];
        float sq = fmaf(x2, x2, fmaf(x1, x1, x0 * x0));
        xT4[i] = make_float4(x0, x1, x2, sq);
    }
    if (i < BATCH * INC * NPTS) {
        int n = i % NPTS; int t = i / NPTS; int c = t % INC; int b = t / INC;
        fT[((size_t)(b * NPTS + n)) * INC + c] = f2bf(f[i]);
    }
    if (blockIdx.x == gridDim.x - 1) {
        int t = threadIdx.x;
        for (int idx = t; idx < 14 * 64; idx += 256) {
            int fr = idx >> 6, ln = idx & 63, l31 = ln & 31, h8 = (ln >> 5) * 8;
            short8 v;
            if (fr < 8) {
                int nt = fr >> 2, kt = fr & 3;
                const float* s = w_att + (nt * 32 + l31) * 64 + kt * 16 + h8;
#pragma unroll
                for (int j = 0; j < 8; ++j) v[j] = (short)f2bf(s[j]);
                wattF[fr * 64 + ln] = v;
            } else if (fr < 12) {
                int kt = fr - 8;
                const float* s = w_conv + l31 * 64 + kt * 16 + h8;
#pragma unroll
                for (int j = 0; j < 8; ++j) v[j] = (short)f2bf(s[j]);
                wconvF[kt * 64 + ln] = v;
            } else {
                int kt = fr - 12;
                const float* s = w_out + l31 * 32 + kt * 16 + h8;
#pragma unroll
                for (int j = 0; j < 8; ++j) v[j] = (short)f2bf(s[j]);
                woutF[kt * 64 + ln] = v;
            }
        }
        for (int idx = t; idx < 512; idx += 256) {
            int e = idx >> 3, j = idx & 7;
            wmlp8[idx] = (j < 7) ? w_mlp[e * 7 + j] : b_mlp[e];
        }
    }
}

// ---------------- kernel 1: FUSED knn + attention ----------------
// 512 threads = 8 waves = 8 points. Phase A: filter+exact-set KNN with a
// TRIPLE-BUFFERED staging pipeline (counted vmcnt + raw s_barrier; never
// vmcnt(0) in the chunk loop -- the __syncthreads drain was ~13us of stall).
// Issue ledger per wave: 3 prologue stages + stage(ch+3) at end of iters
// 0..4 = 8 total; before reading chunk ch, outstanding = issued-(ch+1) = 2
// (ch<=5), 1 (ch=6), 0 (ch=7). stage(ch+3) overwrites buf ch%3 only after
// the barrier retiring its reads. surv/scnt are per-wave (no cross-wave
// hazard); cand is the only shared buffer.
// Phase B: dual-orientation MFMA attention (unchanged from R12).
// LDS: cand 24K + surv 12K = 36K, Fb(20K) aliases; total ~38.6K -> 4
// blocks/CU (154KB<160KB) = 32 waves/CU cap. CAP=192 (R11's 128 overflowed).
#define CAP   192
#define PPBK  8
#define FWSZ  (KNBR * 64)   // 1280 ushorts per wave
__global__ __launch_bounds__(512, 6) void k_fused(const float4* __restrict__ xT4,
                                                  const ushort* __restrict__ fbT,
                                                  const float* __restrict__ wmlp8,
                                                  const short8* __restrict__ wattF,
                                                  const short8* __restrict__ wconvF,
                                                  const short8* __restrict__ woutF,
                                                  float* __restrict__ out) {
    __shared__ __align__(16) char smA[36864];       // cand[3][512]f4(24K)+surv[8][192]u64(12K) / Fb 8x1280u16(20K)
    float4*             candB = (float4*)smA;
    unsigned long long* survB = (unsigned long long*)(smA + 24576);
    ushort*             FbB   = (ushort*)smA;
    __shared__ int scnt[PPBK], slot[PPBK];
    __shared__ int neighL[PPBK][KNBR];              // 640 B
    __shared__ __align__(16) ushort pool[PPBK][64]; // 1024 B

    const int tid  = threadIdx.x;
    const int lane = tid & 63;
    const int wv   = tid >> 6;
    const int hi   = lane >> 5;
    const int l31  = lane & 31;
    const int gp   = blockIdx.x * PPBK + wv;
    const int b    = gp >> 12;
    const int nb   = gp & (NPTS - 1);
    const float4* base = xT4 + (size_t)b * NPTS;

    if (lane == 0) { scnt[wv] = 0; slot[wv] = 1; }

    float4 me = xT4[gp];
    asm volatile("s_waitcnt vmcnt(0)" ::: "memory");   // me landed; vmcnt now counts only gll16s

    auto stage = [&](int c) {
        const float4* src = base + c * 512 + wv * 64 + lane;
        float4* dst = candB + (c % 3) * 512 + wv * 64;   // wave-uniform base; HW adds lane*16
        gll16(src, dst);
    };
    auto dist = [&](const float4& o) -> unsigned {
        float dot = fmaf(o.z, me.z, fmaf(o.y, me.y, o.x * me.x));
        return __float_as_uint(fmaxf((me.w + o.w) - 2.0f * dot, 0.0f));
    };

    stage(0); stage(1); stage(2);

    // ---- phase A1: chunks 0,1 -> bits[16] + per-lane min/2nd-min ----
    unsigned bits[16];
    unsigned lmin = 0xFFFFFFFFu, lmin2 = 0xFFFFFFFFu;

    waitVm<2>(); barrier_nd();                 // chunk 0 resident everywhere
#pragma unroll
    for (int j = 0; j < 8; ++j) {
        unsigned bb = dist(candB[lane + 64 * j]);
        bits[j] = bb;
        unsigned lo_ = bb < lmin ? bb : lmin;
        unsigned hi_ = bb < lmin ? lmin : bb;
        lmin = lo_;
        lmin2 = hi_ < lmin2 ? hi_ : lmin2;
    }
    barrier_nd(); stage(3);                    // buf0 reads retired -> chunk 3 may land

    waitVm<2>(); barrier_nd();                 // chunk 1 resident
#pragma unroll
    for (int j = 0; j < 8; ++j) {
        unsigned bb = dist(candB[512 + lane + 64 * j]);
        bits[8 + j] = bb;
        unsigned lo_ = bb < lmin ? bb : lmin;
        unsigned hi_ = bb < lmin ? lmin : bb;
        lmin = lo_;
        lmin2 = hi_ < lmin2 ? hi_ : lmin2;
    }
    barrier_nd(); stage(4);                    // buf1 retired -> chunk 4

    // tau bisect: count candidates capped at 2/lane (valid upper bound).
    // Runs while chunks 2..4 are in flight.
    unsigned lo = 0u, hi2 = 0xFF000000u;
    for (int it = 0; it < 16 && lo < hi2; ++it) {
        unsigned mid = lo + ((hi2 - lo) >> 1);
        int c = __popcll(__ballot(lmin <= mid)) + __popcll(__ballot(lmin2 <= mid));
        if (c >= KNBR) hi2 = mid; else lo = mid + 1;
    }
    const unsigned tau = hi2;

    // subset append (surv/scnt per-wave: no cross-wave hazard)
#pragma unroll
    for (int j = 0; j < 16; ++j) {
        if (bits[j] <= tau) {
            int pos = atomicAdd(&scnt[wv], 1);
            if (pos < CAP)
                survB[wv * CAP + pos] = ((unsigned long long)bits[j] << 32) | (unsigned)(lane + 64 * j);
        }
    }

    // ---- phase A2: chunks 2..7, pipelined ----
#pragma unroll
    for (int ch = 2; ch < 8; ++ch) {
        if (ch <= 5) waitVm<2>(); else if (ch == 6) waitVm<1>(); else waitVm<0>();
        barrier_nd();                          // chunk ch resident everywhere
        const float4* cb = candB + (ch % 3) * 512;
        const int ib = ch * 512 + lane;
#pragma unroll
        for (int j = 0; j < 8; ++j) {
            unsigned bb = dist(cb[lane + 64 * j]);
            if (bb <= tau) {
                int pos = atomicAdd(&scnt[wv], 1);
                if (pos < CAP)
                    survB[wv * CAP + pos] = ((unsigned long long)bb << 32) | (unsigned)(ib + 64 * j);
            }
        }
        barrier_nd();                          // buf ch%3 reads retired
        if (ch < 5) stage(ch + 3);             // chunk ch+3 -> buf ch%3
    }

    // ---- phase A3: exact top-20 set ----
    int cnt = scnt[wv]; if (cnt > CAP) cnt = CAP;
    const unsigned long long* sv = survB + wv * CAP;

    if (cnt <= 128) {   // common path: 2 keys/lane
        unsigned long long k0 = (lane      < cnt) ? sv[lane     ] : ~0ull;
        unsigned long long k1 = (lane + 64 < cnt) ? sv[lane + 64] : ~0ull;
        unsigned d0 = (unsigned)(k0 >> 32), d1 = (unsigned)(k1 >> 32);
        unsigned i0 = (unsigned)k0, i1 = (unsigned)k1;

        unsigned th;
        {
            unsigned l2 = 0u, h2 = tau;
            bool found = false;
            for (int it = 0; it < 32; ++it) {
                unsigned mid = l2 + ((h2 - l2) >> 1);
                int c = __popcll(__ballot(d0 <= mid)) + __popcll(__ballot(d1 <= mid));
                if (c >= KNBR) h2 = mid; else l2 = mid + 1;
                if (c == KNBR) {              // exact: 20th = max key <= mid
                    unsigned mm = (d0 <= mid) ? d0 : 0u;
                    unsigned m2_ = (d1 <= mid) ? d1 : 0u;
                    mm = mm > m2_ ? mm : m2_;
#pragma unroll
                    for (int off = 32; off >= 1; off >>= 1) {
                        unsigned o = __shfl_xor(mm, off, 64);
                        mm = o > mm ? o : mm;
                    }
                    th = mm; found = true; break;
                }
                if (l2 >= h2) break;
            }
            if (!found) th = h2;
        }
        int cless = __popcll(__ballot(d0 < th)) + __popcll(__ballot(d1 < th));
        int need = KNBR - cless;
        bool t0 = (d0 == th), t1 = (d1 == th);
        int tcnt = __popcll(__ballot(t0)) + __popcll(__ballot(t1));
        unsigned idxthr = 0xFFFFFFFFu;
        if (tcnt != need) {       // rare exact-d2-tie path (uniform branch)
            unsigned la = 0u, ha = 0xFFFFFFFFu;
            for (int it = 0; it < 32; ++it) {
                unsigned mid = la + ((ha - la) >> 1);
                int c = __popcll(__ballot(t0 && i0 <= mid)) + __popcll(__ballot(t1 && i1 <= mid));
                if (c >= need) ha = mid; else la = mid + 1;
            }
            idxthr = ha;
        }
        bool s0 = (d0 < th) || (t0 && i0 <= idxthr);
        bool s1 = (d1 < th) || (t1 && i1 <= idxthr);

        unsigned long long mk = k0 < k1 ? k0 : k1;
#pragma unroll
        for (int off = 32; off >= 1; off >>= 1) {
            unsigned long long o = __shfl_xor(mk, off, 64);
            mk = o < mk ? o : mk;
        }
        if (s0) { if (k0 == mk) neighL[wv][0] = (int)i0; else { int p = atomicAdd(&slot[wv], 1); neighL[wv][p] = (int)i0; } }
        if (s1) { if (k1 == mk) neighL[wv][0] = (int)i1; else { int p = atomicAdd(&slot[wv], 1); neighL[wv][p] = (int)i1; } }
    } else {            // rare fallback: 3 keys/lane (cnt <= 192 by CAP)
        unsigned long long k0 = (lane       < cnt) ? sv[lane      ] : ~0ull;
        unsigned long long k1 = (lane +  64 < cnt) ? sv[lane +  64] : ~0ull;
        unsigned long long k2 = (lane + 128 < cnt) ? sv[lane + 128] : ~0ull;
        unsigned d0 = (unsigned)(k0 >> 32), d1 = (unsigned)(k1 >> 32), d2 = (unsigned)(k2 >> 32);
        unsigned i0 = (unsigned)k0, i1 = (unsigned)k1, i2 = (unsigned)k2;

        unsigned l2 = 0u, h2 = tau;
        for (int it = 0; it < 32 && l2 < h2; ++it) {
            unsigned mid = l2 + ((h2 - l2) >> 1);
            int c = __popcll(__ballot(d0 <= mid)) + __popcll(__ballot(d1 <= mid))
                  + __popcll(__ballot(d2 <= mid));
            if (c >= KNBR) h2 = mid; else l2 = mid + 1;
        }
        const unsigned th = h2;
        int cless = __popcll(__ballot(d0 < th)) + __popcll(__ballot(d1 < th))
                  + __popcll(__ballot(d2 < th));
        int need = KNBR - cless;
        bool t0 = (d0 == th), t1 = (d1 == th), t2 = (d2 == th);
        int tcnt = __popcll(__ballot(t0)) + __popcll(__ballot(t1)) + __popcll(__ballot(t2));
        unsigned idxthr = 0xFFFFFFFFu;
        if (tcnt != need) {
            unsigned la = 0u, ha = 0xFFFFFFFFu;
            for (int it = 0; it < 32; ++it) {
                unsigned mid = la + ((ha - la) >> 1);
                int c = __popcll(__ballot(t0 && i0 <= mid)) + __popcll(__ballot(t1 && i1 <= mid))
                      + __popcll(__ballot(t2 && i2 <= mid));
                if (c >= need) ha = mid; else la = mid + 1;
            }
            idxthr = ha;
        }
        bool s0 = (d0 < th) || (t0 && i0 <= idxthr);
        bool s1 = (d1 < th) || (t1 && i1 <= idxthr);
        bool s2 = (d2 < th) || (t2 && i2 <= idxthr);

        unsigned long long m01 = k0 < k1 ? k0 : k1;
        unsigned long long mk  = m01 < k2 ? m01 : k2;
#pragma unroll
        for (int off = 32; off >= 1; off >>= 1) {
            unsigned long long o = __shfl_xor(mk, off, 64);
            mk = o < mk ? o : mk;
        }
        if (s0) { if (k0 == mk) neighL[wv][0] = (int)i0; else { int p = atomicAdd(&slot[wv], 1); neighL[wv][p] = (int)i0; } }
        if (s1) { if (k1 == mk) neighL[wv][0] = (int)i1; else { int p = atomicAdd(&slot[wv], 1); neighL[wv][p] = (int)i1; } }
        if (s2) { if (k2 == mk) neighL[wv][0] = (int)i2; else { int p = atomicAdd(&slot[wv], 1); neighL[wv][p] = (int)i2; } }
    }

    __syncthreads();   // Fb (aliased over cand+surv) written below; full drain OK here

    // ================= phase B: attention =================
    const ushort* fb = fbT + (size_t)b * NPTS * INC;
    ushort* Fw = FbB + wv * FWSZ;

    int nv = 0;
    if (l31 < KNBR) nv = neighL[wv][l31];
    float4 ncl = base[nv];

    float wm[8];
    {
        const float4* w8 = (const float4*)(wmlp8 + l31 * 8);
        float4 a = w8[0], bq = w8[1];
        wm[0] = a.x; wm[1] = a.y; wm[2] = a.z; wm[3] = a.w;
        wm[4] = bq.x; wm[5] = bq.y; wm[6] = bq.z; wm[7] = bq.w;
    }
    const float c0x = rlf(ncl.x, 0), c0y = rlf(ncl.y, 0), c0z = rlf(ncl.z, 0);

    // batched gather prefetch: all 20 feature loads issued before any use
    ushort fr[KNBR];
#pragma unroll
    for (int k = 0; k < KNBR; ++k) {
        int snk = __builtin_amdgcn_readlane(nv, k);
        fr[k] = fb[(size_t)snk * INC + l31];
    }

    // per-lane relative coords (lane k owns neighbor k); consumed via readlane
    float rxl = ncl.x - c0x, ryl = ncl.y - c0y, rzl = ncl.z - c0z;
    float disl = sqrtf(fmaf(rzl, rzl, fmaf(ryl, ryl, rxl * rxl)));

    float fmbase = wm[7];
    fmbase = fmaf(wm[0], c0x, fmbase); fmbase = fmaf(wm[1], c0y, fmbase);
    fmbase = fmaf(wm[2], c0z, fmbase);
#pragma unroll
    for (int k = 0; k < KNBR; ++k) {
        float fm = fmbase;
        fm = fmaf(wm[3], rlf(rxl, k), fm);
        fm = fmaf(wm[4], rlf(ryl, k), fm);
        fm = fmaf(wm[5], rlf(rzl, k), fm);
        fm = fmaf(wm[6], rlf(disl, k), fm);
        ushort fbits = hi ? f2bf(fm) : fr[k];
        Fw[k * 64 + (lane ^ ((k & 7) << 3))] = fbits;
    }

    const int rowA = (l31 < KNBR) ? l31 : (KNBR - 1);   // rows 20..31 = row-19 copies
    short8 Af[4];
#pragma unroll
    for (int kt = 0; kt < 4; ++kt) {
        int c0 = kt * 16 + 8 * hi;
        Af[kt] = *(const short8*)&Fw[rowA * 64 + (c0 ^ ((rowA & 7) << 3))];
    }

    // flipped orientation: lane k holds d-column -> lane-local softmax stats
    float mloc, zloc;
    {
        f32x16 af;
#pragma unroll
        for (int i = 0; i < 16; ++i) af[i] = 0.f;
        __builtin_amdgcn_s_setprio(1);
#pragma unroll
        for (int kt = 0; kt < 4; ++kt)
            af = __builtin_amdgcn_mfma_f32_32x32x16_bf16(wattF[kt * 64 + lane], Af[kt], af, 0, 0, 0);
        __builtin_amdgcn_s_setprio(0);
        float m0 = af[0];
#pragma unroll
        for (int i = 1; i < 16; ++i) m0 = fmaxf(m0, af[i]);
        float z0 = 0.f;
#pragma unroll
        for (int i = 0; i < 16; ++i) z0 += __expf(af[i] - m0);
        mloc = m0; zloc = z0;
    }
    {
        f32x16 af;
#pragma unroll
        for (int i = 0; i < 16; ++i) af[i] = 0.f;
        __builtin_amdgcn_s_setprio(1);
#pragma unroll
        for (int kt = 0; kt < 4; ++kt)
            af = __builtin_amdgcn_mfma_f32_32x32x16_bf16(wattF[(4 + kt) * 64 + lane], Af[kt], af, 0, 0, 0);
        __builtin_amdgcn_s_setprio(0);
        float m1 = af[0];
#pragma unroll
        for (int i = 1; i < 16; ++i) m1 = fmaxf(m1, af[i]);
        float z1 = 0.f;
#pragma unroll
        for (int i = 0; i < 16; ++i) z1 += __expf(af[i] - m1);
        float mn = fmaxf(mloc, m1);
        zloc = zloc * __expf(mloc - mn) + z1 * __expf(m1 - mn);
        mloc = mn;
    }
    float mo = fmaxf(mloc, __shfl_xor(mloc, 32, 64));
    float zs = zloc * __expf(mloc - mo);
    float Zk = zs + __shfl_xor(zs, 32, 64);
    float mzl = mo + __logf(Zk);      // log-fold: attn = exp(s - mzl)
    // stats for neighbor j live in lane j (and j+32): broadcast via readlane

    // original orientation + pooling, half at a time
    float pooled0 = 0.f, pooled1 = 0.f;
    {
        f32x16 acc;
#pragma unroll
        for (int i = 0; i < 16; ++i) acc[i] = 0.f;
        __builtin_amdgcn_s_setprio(1);
#pragma unroll
        for (int kt = 0; kt < 4; ++kt)
            acc = __builtin_amdgcn_mfma_f32_32x32x16_bf16(Af[kt], wattF[kt * 64 + lane], acc, 0, 0, 0);
        __builtin_amdgcn_s_setprio(0);
#pragma unroll
        for (int r = 0; r < 12; ++r) {
            int j = (r & 3) + 8 * (r >> 2) + 4 * hi;
            float a0 = __expf(acc[r] - rlf(mzl, j));
            float f0 = bf2f(Fw[j * 64 + (l31 ^ ((j & 7) << 3))]);
            float p0 = a0 * f0;
            if (r >= 8) p0 = hi ? 0.f : p0;           // j>=20 rows invalid
            pooled0 += p0;
        }
    }
    {
        f32x16 acc;
#pragma unroll
        for (int i = 0; i < 16; ++i) acc[i] = 0.f;
        __builtin_amdgcn_s_setprio(1);
#pragma unroll
        for (int kt = 0; kt < 4; ++kt)
            acc = __builtin_amdgcn_mfma_f32_32x32x16_bf16(Af[kt], wattF[(4 + kt) * 64 + lane], acc, 0, 0, 0);
        __builtin_amdgcn_s_setprio(0);
#pragma unroll
        for (int r = 0; r < 12; ++r) {
            int j = (r & 3) + 8 * (r >> 2) + 4 * hi;
            float a1 = __expf(acc[r] - rlf(mzl, j));
            float f1 = bf2f(Fw[j * 64 + ((32 + l31) ^ ((j & 7) << 3))]);
            float p1 = a1 * f1;
            if (r >= 8) p1 = hi ? 0.f : p1;
            pooled1 += p1;
        }
    }
    pooled0 += __shfl_xor(pooled0, 32, 64);
    pooled1 += __shfl_xor(pooled1, 32, 64);
    if (!hi) {
        pool[wv][l31]      = f2bf(pooled0);
        pool[wv][32 + l31] = f2bf(pooled1);
    }

    // epilogue: out = W_conv@pooled + W_out@feat (biases cancel in BN)
    f32x16 oa;
#pragma unroll
    for (int i = 0; i < 16; ++i) oa[i] = 0.f;
    __builtin_amdgcn_s_setprio(1);
#pragma unroll
    for (int kt = 0; kt < 4; ++kt) {
        short8 bb = *(const short8*)&pool[wv][kt * 16 + 8 * hi];
        oa = __builtin_amdgcn_mfma_f32_32x32x16_bf16(wconvF[kt * 64 + lane], bb, oa, 0, 0, 0);
    }
#pragma unroll
    for (int kt = 0; kt < 2; ++kt) {
        short8 bb = *(const short8*)(fb + (size_t)nb * INC + kt * 16 + 8 * hi);
        oa = __builtin_amdgcn_mfma_f32_32x32x16_bf16(woutF[kt * 64 + lane], bb, oa, 0, 0, 0);
    }
    __builtin_amdgcn_s_setprio(0);
#pragma unroll
    for (int r = 0; r < 16; ++r) {
        int o = (r & 3) + 8 * (r >> 2) + 4 * hi;
        if (l31 == 0) out[((size_t)(b * OUTC + o)) * NPTS + nb] = oa[r];
    }
}

// ---------------- kernel 2: fused BatchNorm (stats + normalize) ----------------
__global__ __launch_bounds__(256) void k_bn(float* __restrict__ of,
                                            const float* __restrict__ gamma,
                                            const float* __restrict__ beta) {
    const int c = blockIdx.x;
    const int tid = threadIdx.x;
    float s = 0.f, s2 = 0.f;
#pragma unroll
    for (int b = 0; b < BATCH; ++b) {
        const float4* p = (const float4*)(of + ((size_t)b * OUTC + c) * NPTS);
        for (int i = tid; i < NPTS / 4; i += 256) {
            float4 v = p[i];
            s += (v.x + v.y) + (v.z + v.w);
            s2 = fmaf(v.x, v.x, s2); s2 = fmaf(v.y, v.y, s2);
            s2 = fmaf(v.z, v.z, s2); s2 = fmaf(v.w, v.w, s2);
        }
    }
#pragma unroll
    for (int off = 32; off >= 1; off >>= 1) {
        s += __shfl_xor(s, off, 64);
        s2 += __shfl_xor(s2, off, 64);
    }
    __shared__ float rs[4], rs2[4];
    __shared__ float sc[2];
    if ((tid & 63) == 0) { rs[tid >> 6] = s; rs2[tid >> 6] = s2; }
    __syncthreads();
    if (tid == 0) {
        float S = (rs[0] + rs[1]) + (rs[2] + rs[3]);
        float S2 = (rs2[0] + rs2[1]) + (rs2[2] + rs2[3]);
        const float invn = 1.0f / (BATCH * NPTS);
        float mean = S * invn;
        float var = S2 * invn - mean * mean;
        float rstd = rsqrtf(var + EPSBN);
        float scale = rstd * gamma[c];
        sc[0] = scale;
        sc[1] = beta[c] - mean * scale;
    }
    __syncthreads();
    const float scale = sc[0], shift = sc[1];
#pragma unroll
    for (int b = 0; b < BATCH; ++b) {
        float4* p = (float4*)(of + ((size_t)b * OUTC + c) * NPTS);
        for (int i = tid; i < NPTS / 4; i += 256) {
            float4 v = p[i];
            v.x = fmaf(v.x, scale, shift);
            v.y = fmaf(v.y, scale, shift);
            v.z = fmaf(v.z, scale, shift);
            v.w = fmaf(v.w, scale, shift);
            p[i] = v;
        }
    }
}

// ---------------- launch ----------------
extern "C" void kernel_launch(void* const* d_in, const int* in_sizes, int n_in,
                              void* d_out, int out_size, void* d_ws, size_t ws_size,
                              hipStream_t stream) {
    const float* x      = (const float*)d_in[0];
    const float* feat   = (const float*)d_in[1];
    const float* w_mlp  = (const float*)d_in[2];
    const float* b_mlp  = (const float*)d_in[3];
    const float* w_att  = (const float*)d_in[4];
    const float* w_conv = (const float*)d_in[5];
    const float* w_out  = (const float*)d_in[7];
    const float* gamma  = (const float*)d_in[9];
    const float* beta   = (const float*)d_in[10];
    float* out = (float*)d_out;

    char* ws = (char*)d_ws;
    float4* xT4    = (float4*)ws;                          // 262144 B
    ushort* fbT    = (ushort*)(ws + 262144);               // 1048576 B
    short8* wattF  = (short8*)(ws + 1310976);              // 8192 B
    short8* wconvF = (short8*)(ws + 1319168);              // 4096 B
    short8* woutF  = (short8*)(ws + 1323264);              // 2048 B
    float*  wmlp8  = (float*)(ws + 1325312);               // 2048 B

    k_prep<<<(BATCH * INC * NPTS + 255) / 256 + 1, 256, 0, stream>>>(
        x, feat, xT4, fbT, w_att, w_conv, w_out, w_mlp, b_mlp,
        wattF, wconvF, woutF, wmlp8);
    k_fused<<<(BATCH * NPTS) / PPBK, 512, 0, stream>>>(xT4, fbT, wmlp8,
                                                       wattF, wconvF, woutF, out);
    k_bn<<<OUTC, 256, 0, stream>>>(out, gamma, beta);
}